// Round 12
// baseline (821.478 us; speedup 1.0000x reference)
//
#include <hip/hip_runtime.h>
#include <math.h>

#define N_NODES 50000
#define N_EDGES 300000
#define IN_DIM 64
#define H 256
#define LAYERS 4
#define NB 181
#define NGRAPH 64
#define EE (N_EDGES + N_NODES)
#define NEG_SLOPE 0.2f
#define LN_EPS 1e-5f

typedef unsigned short u16;
typedef __attribute__((ext_vector_type(8))) _Float16 half8;
typedef __attribute__((ext_vector_type(4))) float floatx4;

__device__ __forceinline__ u16 f2h(float f) {
  _Float16 h = (_Float16)f;
  return __builtin_bit_cast(u16, h);
}
__device__ __forceinline__ float h2f(u16 b) {
  return (float)__builtin_bit_cast(_Float16, b);
}

__device__ __forceinline__ float wave_reduce_sum(float v) {
  #pragma unroll
  for (int off = 32; off > 0; off >>= 1) v += __shfl_xor(v, off, 64);
  return v;
}

// ---------------- casts ----------------
__global__ void cast_f16_kernel(const float* __restrict__ in, u16* __restrict__ out, int n4) {
  int i = blockIdx.x * 256 + threadIdx.x;
  if (i < n4) {
    float4 f = ((const float4*)in)[i];
    ushort4 o;
    o.x = f2h(f.x); o.y = f2h(f.y); o.z = f2h(f.z); o.w = f2h(f.w);
    ((ushort4*)out)[i] = o;
  }
}

__global__ void cast_weights_kernel(
    const float* __restrict__ W_in, const float* __restrict__ Wg1,
    const float* __restrict__ Wl, const float* __restrict__ Wr,
    u16* __restrict__ win_h, u16* __restrict__ wg1_h,
    u16* __restrict__ wl_h, u16* __restrict__ wr_h)
{
  int i = blockIdx.x * 256 + threadIdx.x;
  int which = blockIdx.y;
  const float* s; u16* dd; int n4;
  if (which == 0)      { s = W_in; dd = win_h; n4 = H * IN_DIM / 4; }
  else if (which == 1) { s = Wg1;  dd = wg1_h; n4 = H * H / 4; }
  else if (which == 2) { s = Wl;   dd = wl_h;  n4 = LAYERS * H * H / 4; }
  else                 { s = Wr;   dd = wr_h;  n4 = LAYERS * H * H / 4; }
  if (i < n4) {
    float4 f = ((const float4*)s)[i];
    ushort4 o;
    o.x = f2h(f.x); o.y = f2h(f.y); o.z = f2h(f.z); o.w = f2h(f.w);
    ((ushort4*)dd)[i] = o;
  }
}

// ---------------- CSR build ----------------
__global__ void init_counts_kernel(int* __restrict__ cnt) {
  int i = blockIdx.x * 256 + threadIdx.x;
  if (i < N_NODES) cnt[i] = 1;  // self loop
}

__global__ void count_edges_kernel(const int* __restrict__ dst, int* __restrict__ cnt) {
  int e = blockIdx.x * 256 + threadIdx.x;
  if (e < N_EDGES) atomicAdd(&cnt[dst[e]], 1);
}

__global__ void scan_blocks_kernel(const int* __restrict__ cnt, int* __restrict__ partial,
                                   int* __restrict__ bsums, int n) {
  __shared__ int buf[256];
  int tid = threadIdx.x;
  int i = blockIdx.x * 256 + tid;
  buf[tid] = (i < n) ? cnt[i] : 0;
  __syncthreads();
  #pragma unroll
  for (int off = 1; off < 256; off <<= 1) {
    int t = (tid >= off) ? buf[tid - off] : 0;
    __syncthreads();
    buf[tid] += t;
    __syncthreads();
  }
  if (i < n) partial[i] = buf[tid];
  if (tid == 255) bsums[blockIdx.x] = buf[255];
}

__global__ void scan_sums_kernel(int* __restrict__ bsums, int nblk) {
  __shared__ int buf[256];
  int tid = threadIdx.x;
  buf[tid] = (tid < nblk) ? bsums[tid] : 0;
  __syncthreads();
  #pragma unroll
  for (int off = 1; off < 256; off <<= 1) {
    int t = (tid >= off) ? buf[tid - off] : 0;
    __syncthreads();
    buf[tid] += t;
    __syncthreads();
  }
  if (tid < nblk) bsums[tid] = buf[tid];
}

__global__ void scan_write_kernel(const int* __restrict__ partial, const int* __restrict__ bsums,
                                  int* __restrict__ rowp, int n) {
  int i = blockIdx.x * 256 + threadIdx.x;
  if (i < n) {
    int b = blockIdx.x;
    int off = (b > 0) ? bsums[b - 1] : 0;
    rowp[i + 1] = partial[i] + off;
    if (i == 0) rowp[0] = 0;
  }
}

__global__ void fill_self_kernel(const int* __restrict__ rowp, int* __restrict__ col,
                                 int* __restrict__ fillpos) {
  int i = blockIdx.x * 256 + threadIdx.x;
  if (i < N_NODES) {
    int p = rowp[i];
    col[p] = i;
    fillpos[i] = p + 1;
  }
}

__global__ void fill_edges_kernel(const int* __restrict__ src, const int* __restrict__ dst,
                                  int* __restrict__ fillpos, int* __restrict__ col) {
  int e = blockIdx.x * 256 + threadIdx.x;
  if (e < N_EDGES) {
    int d = dst[e];
    int p = atomicAdd(&fillpos[d], 1);
    col[p] = src[e];
  }
}

// ---------------- MFMA GEMM tiles ----------------
#define GTM 128
#define GTK 64
#define LDB 72
#define SSTR 132

__global__ __launch_bounds__(256) void gemm_proj_kernel(
    const u16* __restrict__ A, const u16* __restrict__ W,
    const float* __restrict__ bias, u16* __restrict__ outh, int M, int K)
{
  __shared__ u16 smem[2 * GTM * LDB];
  u16* As = smem;
  u16* Bs = smem + GTM * LDB;
  int tid = threadIdx.x;
  int lane = tid & 63;
  int wave = tid >> 6;
  int wm = (wave >> 1) * 64;
  int wn = (wave & 1) * 64;
  int bm = blockIdx.y * GTM;
  int n0 = blockIdx.x * 128;
  int lr = tid >> 3;
  int lc = (tid & 7) * 8;

  floatx4 zero4 = {0.f, 0.f, 0.f, 0.f};
  floatx4 acc[4][4];
  #pragma unroll
  for (int i = 0; i < 4; i++)
    #pragma unroll
    for (int j = 0; j < 4; j++) acc[i][j] = zero4;

  int q8 = (lane >> 4) * 8;
  int mrow = lane & 15;

  for (int k0 = 0; k0 < K; k0 += GTK) {
    __syncthreads();
    #pragma unroll
    for (int p = 0; p < 4; p++) {
      int row = lr + p * 32;
      int gr = bm + row;
      uint4 av = {0, 0, 0, 0};
      if (gr < M) av = *(const uint4*)&A[(size_t)gr * K + k0 + lc];
      *(uint4*)&As[row * LDB + lc] = av;
      uint4 bv = *(const uint4*)&W[(size_t)(n0 + row) * K + k0 + lc];
      *(uint4*)&Bs[row * LDB + lc] = bv;
    }
    __syncthreads();
    #pragma unroll
    for (int h = 0; h < 2; h++) {
      half8 af[4], bf[4];
      #pragma unroll
      for (int i = 0; i < 4; i++)
        af[i] = *(const half8*)&As[(wm + i * 16 + mrow) * LDB + h * 32 + q8];
      #pragma unroll
      for (int j = 0; j < 4; j++)
        bf[j] = *(const half8*)&Bs[(wn + j * 16 + mrow) * LDB + h * 32 + q8];
      #pragma unroll
      for (int i = 0; i < 4; i++)
        #pragma unroll
        for (int j = 0; j < 4; j++)
          acc[i][j] = __builtin_amdgcn_mfma_f32_16x16x32_f16(af[i], bf[j], acc[i][j], 0, 0, 0);
    }
  }

  __syncthreads();
  u16* stage = smem;
  int ccol = lane & 15;
  int crow4 = (lane >> 4) * 4;
  #pragma unroll
  for (int j = 0; j < 4; j++) {
    float bv = bias[n0 + wn + j * 16 + ccol];
    #pragma unroll
    for (int i = 0; i < 4; i++) {
      #pragma unroll
      for (int r = 0; r < 4; r++) {
        int row = wm + i * 16 + crow4 + r;
        stage[row * SSTR + wn + j * 16 + ccol] = f2h(acc[i][j][r] + bv);
      }
    }
  }
  __syncthreads();
  int rr = tid >> 1;
  int c0 = (tid & 1) * 64;
  int grow = bm + rr;
  if (grow < M) {
    const ushort4* sp = (const ushort4*)&stage[rr * SSTR + c0];
    ushort4* gp = (ushort4*)&outh[(size_t)grow * H + n0 + c0];
    #pragma unroll
    for (int q = 0; q < 16; q++) gp[q] = sp[q];
  }
}

// ---------------- dual GEMM v3: A-resident + register-prefetched B ----------------
#define DTM 64
#define AST 264
#define SSTR2 132

__global__ __launch_bounds__(256) void gemm_dual2_kernel(
    const u16* __restrict__ A, const u16* __restrict__ Wlb, const u16* __restrict__ Wrb,
    const float* __restrict__ biasL, const float* __restrict__ biasR,
    u16* __restrict__ outL, u16* __restrict__ outR, int M)
{
  __shared__ u16 As[DTM * AST];
  __shared__ u16 Bs[128 * LDB];
  int tid = threadIdx.x;
  int lane = tid & 63;
  int wave = tid >> 6;
  int wn = wave * 32;
  int bm = blockIdx.x * DTM;
  int mrow = lane & 15;
  int q8 = (lane >> 4) * 8;
  int ccol = lane & 15;
  int crow4 = (lane >> 4) * 4;
  int colB = (tid & 7) * 8;
  int r0B = tid >> 3;

  {
    int col = (tid & 31) * 8;
    int r0 = tid >> 5;
    #pragma unroll
    for (int it = 0; it < 8; it++) {
      int row = r0 + it * 8;
      int gr = bm + row;
      uint4 av = {0, 0, 0, 0};
      if (gr < M) av = *(const uint4*)&A[(size_t)gr * H + col];
      *(uint4*)&As[row * AST + col] = av;
    }
  }

  floatx4 zero4 = {0.f, 0.f, 0.f, 0.f};

  // initial register prefetch: nt=0, k0=0
  uint4 rB[4];
  #pragma unroll
  for (int p2 = 0; p2 < 4; p2++)
    rB[p2] = *(const uint4*)&Wlb[(size_t)(r0B + p2 * 32) * H + colB];

  for (int nt = 0; nt < 4; nt++) {
    const float* bias = (nt < 2) ? biasL : biasR;
    u16* outp = (nt < 2) ? outL : outR;
    const u16* W = (nt < 2) ? Wlb : Wrb;
    int n0 = (nt & 1) * 128;

    floatx4 acc[4][2];
    #pragma unroll
    for (int i = 0; i < 4; i++) {
      acc[i][0] = zero4;
      acc[i][1] = zero4;
    }

    for (int kk = 0; kk < 4; kk++) {
      __syncthreads();   // prior Bs readers (or A staging / epilogue store reads) done
      #pragma unroll
      for (int p2 = 0; p2 < 4; p2++)
        *(uint4*)&Bs[(r0B + p2 * 32) * LDB + colB] = rB[p2];
      // prefetch next chunk into registers (overlaps with MFMA below)
      if (kk < 3) {
        #pragma unroll
        for (int p2 = 0; p2 < 4; p2++)
          rB[p2] = *(const uint4*)&W[(size_t)(n0 + r0B + p2 * 32) * H + (kk + 1) * 64 + colB];
      } else if (nt < 3) {
        const u16* Wn = (nt + 1 < 2) ? Wlb : Wrb;
        int n0n = ((nt + 1) & 1) * 128;
        #pragma unroll
        for (int p2 = 0; p2 < 4; p2++)
          rB[p2] = *(const uint4*)&Wn[(size_t)(n0n + r0B + p2 * 32) * H + colB];
      }
      __syncthreads();   // Bs visible
      #pragma unroll
      for (int h = 0; h < 2; h++) {
        half8 af[4], bf[2];
        #pragma unroll
        for (int i = 0; i < 4; i++)
          af[i] = *(const half8*)&As[(i * 16 + mrow) * AST + kk * 64 + h * 32 + q8];
        #pragma unroll
        for (int j = 0; j < 2; j++)
          bf[j] = *(const half8*)&Bs[(wn + j * 16 + mrow) * LDB + h * 32 + q8];
        #pragma unroll
        for (int i = 0; i < 4; i++)
          #pragma unroll
          for (int j = 0; j < 2; j++)
            acc[i][j] = __builtin_amdgcn_mfma_f32_16x16x32_f16(af[i], bf[j], acc[i][j], 0, 0, 0);
      }
    }

    __syncthreads();
    u16* stage = Bs;
    #pragma unroll
    for (int j = 0; j < 2; j++) {
      float bv = bias[n0 + wn + j * 16 + ccol];
      #pragma unroll
      for (int i = 0; i < 4; i++) {
        #pragma unroll
        for (int r = 0; r < 4; r++) {
          int row = i * 16 + crow4 + r;
          stage[row * SSTR2 + wn + j * 16 + ccol] = f2h(acc[i][j][r] + bv);
        }
      }
    }
    __syncthreads();
    {
      int row = tid >> 2;
      int c0 = (tid & 3) * 32;
      int grow = bm + row;
      if (grow < M) {
        #pragma unroll
        for (int q = 0; q < 8; q++)
          *(ushort4*)&outp[(size_t)grow * H + n0 + c0 + q * 4] =
              *(const ushort4*)&stage[row * SSTR2 + c0 + q * 4];
      }
    }
    // next nt's kk=0 barrier covers store-read completion before Bs overwrite
  }
}

// gate GEMM: gate[row] += sum_col relu(x@Wg1 + bg1)[col] * Wg2[col]; gate pre-init to bg2
__global__ __launch_bounds__(256) void gemm_gate_kernel(
    const u16* __restrict__ A, const u16* __restrict__ W,
    const float* __restrict__ bias, const float* __restrict__ Wg2,
    float* __restrict__ gate, int M)
{
  __shared__ u16 smem[2 * GTM * LDB];
  u16* As = smem;
  u16* Bs = smem + GTM * LDB;
  int tid = threadIdx.x;
  int lane = tid & 63;
  int wave = tid >> 6;
  int wm = (wave >> 1) * 64;
  int wn = (wave & 1) * 64;
  int bm = blockIdx.y * GTM;
  int bn = blockIdx.x * 128;
  int lr = tid >> 3;
  int lc = (tid & 7) * 8;

  floatx4 zero4 = {0.f, 0.f, 0.f, 0.f};
  floatx4 acc[4][4];
  #pragma unroll
  for (int i = 0; i < 4; i++)
    #pragma unroll
    for (int j = 0; j < 4; j++) acc[i][j] = zero4;

  int q8 = (lane >> 4) * 8;
  int mrow = lane & 15;

  for (int k0 = 0; k0 < H; k0 += GTK) {
    __syncthreads();
    #pragma unroll
    for (int p = 0; p < 4; p++) {
      int row = lr + p * 32;
      int gr = bm + row;
      uint4 av = {0, 0, 0, 0};
      if (gr < M) av = *(const uint4*)&A[(size_t)gr * H + k0 + lc];
      *(uint4*)&As[row * LDB + lc] = av;
      uint4 bv = *(const uint4*)&W[(size_t)(bn + row) * H + k0 + lc];
      *(uint4*)&Bs[row * LDB + lc] = bv;
    }
    __syncthreads();
    #pragma unroll
    for (int h = 0; h < 2; h++) {
      half8 af[4], bf[4];
      #pragma unroll
      for (int i = 0; i < 4; i++)
        af[i] = *(const half8*)&As[(wm + i * 16 + mrow) * LDB + h * 32 + q8];
      #pragma unroll
      for (int j = 0; j < 4; j++)
        bf[j] = *(const half8*)&Bs[(wn + j * 16 + mrow) * LDB + h * 32 + q8];
      #pragma unroll
      for (int i = 0; i < 4; i++)
        #pragma unroll
        for (int j = 0; j < 4; j++)
          acc[i][j] = __builtin_amdgcn_mfma_f32_16x16x32_f16(af[i], bf[j], acc[i][j], 0, 0, 0);
    }
  }

  int ccol = lane & 15;
  float bv[4], wv[4];
  #pragma unroll
  for (int j = 0; j < 4; j++) {
    int col = bn + wn + j * 16 + ccol;
    bv[j] = bias[col];
    wv[j] = Wg2[col];
  }
  #pragma unroll
  for (int i = 0; i < 4; i++) {
    #pragma unroll
    for (int r = 0; r < 4; r++) {
      float p = 0.f;
      #pragma unroll
      for (int j = 0; j < 4; j++) {
        float hcol = fmaxf(acc[i][j][r] + bv[j], 0.f);
        p += hcol * wv[j];
      }
      p += __shfl_xor(p, 1, 64);
      p += __shfl_xor(p, 2, 64);
      p += __shfl_xor(p, 4, 64);
      p += __shfl_xor(p, 8, 64);
      int row = bm + wm + i * 16 + (lane >> 4) * 4 + r;
      if ((lane & 15) == 0 && row < M) atomicAdd(&gate[row], p);
    }
  }
}

// ---------------- fused edge softmax + aggregate + LN + residual ----------------
// Unroll-4 (masked tail): 4 independent shuffle chains, softmax bookkeeping per 4 edges.
__global__ __launch_bounds__(256) void layer_fused_kernel(
    const u16* __restrict__ xl, const u16* __restrict__ xr,
    u16* __restrict__ xst,
    const int* __restrict__ rowp, const int* __restrict__ col,
    const float* __restrict__ att, const float* __restrict__ bias_c,
    const float* __restrict__ ln_g, const float* __restrict__ ln_b)
{
  int lane = threadIdx.x & 63;
  int v = blockIdx.x * 4 + (threadIdx.x >> 6);
  if (v >= N_NODES) return;
  int f4 = lane << 2;
  size_t rowbase = (size_t)v * H;
  ushort4 xr4 = *(const ushort4*)&xr[rowbase + f4];
  float xrx = h2f(xr4.x), xry = h2f(xr4.y), xrz = h2f(xr4.z), xrw = h2f(xr4.w);
  float4 attv = *(const float4*)&att[f4];
  int beg = rowp[v], end = rowp[v + 1];
  float m = -INFINITY, d = 0.f;
  float ox = 0.f, oy = 0.f, oz = 0.f, ow = 0.f;

  for (int p = beg; p < end; p += 4) {
    int n = end - p;
    int u0 = col[p];
    int u1 = (n > 1) ? col[p + 1] : u0;
    int u2 = (n > 2) ? col[p + 2] : u0;
    int u3 = (n > 3) ? col[p + 3] : u0;
    ushort4 A0 = *(const ushort4*)&xl[(size_t)u0 * H + f4];
    ushort4 A1 = *(const ushort4*)&xl[(size_t)u1 * H + f4];
    ushort4 A2 = *(const ushort4*)&xl[(size_t)u2 * H + f4];
    ushort4 A3 = *(const ushort4*)&xl[(size_t)u3 * H + f4];
    float a0x = h2f(A0.x), a0y = h2f(A0.y), a0z = h2f(A0.z), a0w = h2f(A0.w);
    float a1x = h2f(A1.x), a1y = h2f(A1.y), a1z = h2f(A1.z), a1w = h2f(A1.w);
    float a2x = h2f(A2.x), a2y = h2f(A2.y), a2z = h2f(A2.z), a2w = h2f(A2.w);
    float a3x = h2f(A3.x), a3y = h2f(A3.y), a3z = h2f(A3.z), a3w = h2f(A3.w);
    float t;
    float pe0, pe1, pe2, pe3;
    t = a0x + xrx; t = t > 0.f ? t : NEG_SLOPE * t; pe0 = t * attv.x;
    t = a0y + xry; t = t > 0.f ? t : NEG_SLOPE * t; pe0 = fmaf(t, attv.y, pe0);
    t = a0z + xrz; t = t > 0.f ? t : NEG_SLOPE * t; pe0 = fmaf(t, attv.z, pe0);
    t = a0w + xrw; t = t > 0.f ? t : NEG_SLOPE * t; pe0 = fmaf(t, attv.w, pe0);
    t = a1x + xrx; t = t > 0.f ? t : NEG_SLOPE * t; pe1 = t * attv.x;
    t = a1y + xry; t = t > 0.f ? t : NEG_SLOPE * t; pe1 = fmaf(t, attv.y, pe1);
    t = a1z + xrz; t = t > 0.f ? t : NEG_SLOPE * t; pe1 = fmaf(t, attv.z, pe1);
    t = a1w + xrw; t = t > 0.f ? t : NEG_SLOPE * t; pe1 = fmaf(t, attv.w, pe1);
    t = a2x + xrx; t = t > 0.f ? t : NEG_SLOPE * t; pe2 = t * attv.x;
    t = a2y + xry; t = t > 0.f ? t : NEG_SLOPE * t; pe2 = fmaf(t, attv.y, pe2);
    t = a2z + xrz; t = t > 0.f ? t : NEG_SLOPE * t; pe2 = fmaf(t, attv.z, pe2);
    t = a2w + xrw; t = t > 0.f ? t : NEG_SLOPE * t; pe2 = fmaf(t, attv.w, pe2);
    t = a3x + xrx; t = t > 0.f ? t : NEG_SLOPE * t; pe3 = t * attv.x;
    t = a3y + xry; t = t > 0.f ? t : NEG_SLOPE * t; pe3 = fmaf(t, attv.y, pe3);
    t = a3z + xrz; t = t > 0.f ? t : NEG_SLOPE * t; pe3 = fmaf(t, attv.z, pe3);
    t = a3w + xrw; t = t > 0.f ? t : NEG_SLOPE * t; pe3 = fmaf(t, attv.w, pe3);
    #pragma unroll
    for (int off = 32; off > 0; off >>= 1) {
      pe0 += __shfl_xor(pe0, off, 64);
      pe1 += __shfl_xor(pe1, off, 64);
      pe2 += __shfl_xor(pe2, off, 64);
      pe3 += __shfl_xor(pe3, off, 64);
    }
    pe1 = (n > 1) ? pe1 : -INFINITY;
    pe2 = (n > 2) ? pe2 : -INFINITY;
    pe3 = (n > 3) ? pe3 : -INFINITY;
    float mn = fmaxf(fmaxf(fmaxf(pe0, pe1), fmaxf(pe2, pe3)), m);
    float sc = __expf(m - mn);    // exp(-inf)=0 first iteration
    float w0 = __expf(pe0 - mn);
    float w1 = __expf(pe1 - mn);
    float w2 = __expf(pe2 - mn);
    float w3 = __expf(pe3 - mn);
    d = fmaf(d, sc, (w0 + w1) + (w2 + w3));
    ox = fmaf(ox, sc, fmaf(w0, a0x, fmaf(w1, a1x, fmaf(w2, a2x, w3 * a3x))));
    oy = fmaf(oy, sc, fmaf(w0, a0y, fmaf(w1, a1y, fmaf(w2, a2y, w3 * a3y))));
    oz = fmaf(oz, sc, fmaf(w0, a0z, fmaf(w1, a1z, fmaf(w2, a2z, w3 * a3z))));
    ow = fmaf(ow, sc, fmaf(w0, a0w, fmaf(w1, a1w, fmaf(w2, a2w, w3 * a3w))));
    m = mn;
  }

  float invd = 1.0f / d;
  float4 bc4 = *(const float4*)&bias_c[f4];
  ox = ox * invd + bc4.x;
  oy = oy * invd + bc4.y;
  oz = oz * invd + bc4.z;
  ow = ow * invd + bc4.w;
  float s = wave_reduce_sum(ox + oy + oz + ow);
  float mean = s * (1.0f / H);
  float cx = ox - mean, cy = oy - mean, cz = oz - mean, cw = ow - mean;
  float sq = wave_reduce_sum(cx * cx + cy * cy + cz * cz + cw * cw);
  float rstd = rsqrtf(sq * (1.0f / H) + LN_EPS);
  float4 g4 = *(const float4*)&ln_g[f4];
  float4 b4 = *(const float4*)&ln_b[f4];
  ushort4 xres4 = *(const ushort4*)&xst[rowbase + f4];
  float yx = fmaxf(fmaf(cx * rstd, g4.x, b4.x), 0.f) + h2f(xres4.x);
  float yy = fmaxf(fmaf(cy * rstd, g4.y, b4.y), 0.f) + h2f(xres4.y);
  float yz = fmaxf(fmaf(cz * rstd, g4.z, b4.z), 0.f) + h2f(xres4.z);
  float yw = fmaxf(fmaf(cw * rstd, g4.w, b4.w), 0.f) + h2f(xres4.w);
  ushort4 yb;
  yb.x = f2h(yx); yb.y = f2h(yy); yb.z = f2h(yz); yb.w = f2h(yw);
  *(ushort4*)&xst[rowbase + f4] = yb;
}

// ---------------- gate init + graph bounds (merged; batch sorted) ----------------
__global__ void gate_init_kernel(float* __restrict__ gate, const float* __restrict__ bg2,
                                 const int* __restrict__ batch,
                                 int* __restrict__ gstart, int* __restrict__ gend) {
  int i = blockIdx.x * 256 + threadIdx.x;
  if (i < N_NODES) {
    gate[i] = bg2[0];
    int b = batch[i];
    if (i == 0 || batch[i - 1] != b) gstart[b] = i;
    if (i == N_NODES - 1 || batch[i + 1] != b) gend[b] = i + 1;
  }
}

// ---------------- pooling: per-graph softmax stats (+ pooled zero) ----------------
__global__ __launch_bounds__(256) void pool_prep_kernel(
    const float* __restrict__ gate, const int* __restrict__ gstart,
    const int* __restrict__ gend, float* __restrict__ gmax, float* __restrict__ gdinv,
    float* __restrict__ pooled)
{
  __shared__ float red[256];
  int g = blockIdx.x, tid = threadIdx.x;
  pooled[(size_t)g * H + tid] = 0.f;
  int s = gstart[g], e = gend[g];
  float lm = -INFINITY;
  for (int i = s + tid; i < e; i += 256) lm = fmaxf(lm, gate[i]);
  red[tid] = lm;
  __syncthreads();
  for (int off = 128; off; off >>= 1) {
    if (tid < off) red[tid] = fmaxf(red[tid], red[tid + off]);
    __syncthreads();
  }
  float m = red[0];
  __syncthreads();
  float lsum = 0.0f;
  for (int i = s + tid; i < e; i += 256) lsum += __expf(gate[i] - m);
  red[tid] = lsum;
  __syncthreads();
  for (int off = 128; off; off >>= 1) {
    if (tid < off) red[tid] += red[tid + off];
    __syncthreads();
  }
  if (tid == 0) {
    gmax[g] = m;
    gdinv[g] = (s < e) ? 1.0f / red[0] : 0.0f;
  }
}

// ---------------- pooling: weighted accumulate (128 nodes per block, fp16 x) ----------------
__global__ __launch_bounds__(256) void pool_accum_kernel(
    const float* __restrict__ gate, const u16* __restrict__ xh,
    const int* __restrict__ batch, const float* __restrict__ gmax,
    const float* __restrict__ gdinv, float* __restrict__ pooled)
{
  __shared__ float wl[128];
  __shared__ int gl[128];
  int b0 = blockIdx.x * 128;
  int tid = threadIdx.x;
  if (tid < 128) {
    int v = b0 + tid;
    if (v < N_NODES) {
      int g = batch[v];
      gl[tid] = g;
      wl[tid] = __expf(gate[v] - gmax[g]) * gdinv[g];
    } else {
      gl[tid] = -1;
      wl[tid] = 0.f;
    }
  }
  __syncthreads();
  int cnt = min(128, N_NODES - b0);
  float acc = 0.f;
  int cur = gl[0];
  for (int j = 0; j < cnt; j++) {
    int g = gl[j];
    if (g != cur) {
      atomicAdd(&pooled[(size_t)cur * H + tid], acc);
      acc = 0.f;
      cur = g;
    }
    acc += wl[j] * h2f(xh[(size_t)(b0 + j) * H + tid]);
  }
  if (cur >= 0) atomicAdd(&pooled[(size_t)cur * H + tid], acc);
}

// ---------------- fused head: pooled -> z -> {cls, r1} -> residual ----------------
__global__ __launch_bounds__(256) void head_kernel(
    const float* __restrict__ pooled,
    const float* __restrict__ Ws, const float* __restrict__ bs,
    const float* __restrict__ Wc, const float* __restrict__ bc,
    const float* __restrict__ Wr1, const float* __restrict__ br1,
    const float* __restrict__ Wr2, const float* __restrict__ br2,
    float* __restrict__ out)
{
  __shared__ float psh[256];
  __shared__ float zsh[256];
  __shared__ float r1sh[128];
  int g = blockIdx.x, tid = threadIdx.x;
  psh[tid] = pooled[(size_t)g * H + tid];
  __syncthreads();
  {
    float acc = bs[tid];
    const float4* wr = (const float4*)&Ws[(size_t)tid * H];
    for (int k4 = 0; k4 < H / 4; k4++) {
      float4 wv = wr[k4];
      float4 av = *(const float4*)&psh[k4 * 4];
      acc += av.x * wv.x + av.y * wv.y + av.z * wv.z + av.w * wv.w;
    }
    zsh[tid] = fmaxf(acc, 0.f);
  }
  __syncthreads();
  if (tid < NB) {
    float acc = bc[tid];
    const float4* wr = (const float4*)&Wc[(size_t)tid * H];
    for (int k4 = 0; k4 < H / 4; k4++) {
      float4 wv = wr[k4];
      float4 av = *(const float4*)&zsh[k4 * 4];
      acc += av.x * wv.x + av.y * wv.y + av.z * wv.z + av.w * wv.w;
    }
    out[(size_t)g * NB + tid] = acc;
  }
  if (tid < 128) {
    float acc = br1[tid];
    const float4* wr = (const float4*)&Wr1[(size_t)tid * H];
    for (int k4 = 0; k4 < H / 4; k4++) {
      float4 wv = wr[k4];
      float4 av = *(const float4*)&zsh[k4 * 4];
      acc += av.x * wv.x + av.y * wv.y + av.z * wv.z + av.w * wv.w;
    }
    r1sh[tid] = fmaxf(acc, 0.f);
  }
  __syncthreads();
  if (tid < 64) {
    float s2 = r1sh[tid] * Wr2[tid] + r1sh[tid + 64] * Wr2[tid + 64];
    s2 = wave_reduce_sum(s2);
    if (tid == 0) out[(size_t)NGRAPH * NB + g] = tanhf(s2 + br2[0]);
  }
}

// ---------------- launcher ----------------
extern "C" void kernel_launch(void* const* d_in, const int* in_sizes, int n_in,
                              void* d_out, int out_size, void* d_ws, size_t ws_size,
                              hipStream_t stream) {
  const float* x_in   = (const float*)d_in[0];
  const int*   eidx   = (const int*)d_in[1];
  const int*   batch  = (const int*)d_in[2];
  const float* W_in   = (const float*)d_in[3];
  const float* b_in   = (const float*)d_in[4];
  const float* Wl     = (const float*)d_in[5];
  const float* bl     = (const float*)d_in[6];
  const float* Wr     = (const float*)d_in[7];
  const float* br     = (const float*)d_in[8];
  const float* att    = (const float*)d_in[9];
  const float* bias_c = (const float*)d_in[10];
  const float* ln_g   = (const float*)d_in[11];
  const float* ln_b   = (const float*)d_in[12];
  const float* Wg1    = (const float*)d_in[13];
  const float* bg1    = (const float*)d_in[14];
  const float* Wg2    = (const float*)d_in[15];
  const float* bg2    = (const float*)d_in[16];
  const float* Ws     = (const float*)d_in[17];
  const float* bs     = (const float*)d_in[18];
  const float* Wc     = (const float*)d_in[19];
  const float* bc     = (const float*)d_in[20];
  const float* Wr1    = (const float*)d_in[21];
  const float* br1    = (const float*)d_in[22];
  const float* Wr2    = (const float*)d_in[23];
  const float* br2    = (const float*)d_in[24];
  float* out = (float*)d_out;

  char* w = (char*)d_ws;
  u16* x_h    = (u16*)w;    w += sizeof(u16) * (size_t)N_NODES * H;
  u16* xl_h   = (u16*)w;    w += sizeof(u16) * (size_t)N_NODES * H;
  u16* xr_h   = (u16*)w;    w += sizeof(u16) * (size_t)N_NODES * H;
  u16* xin_h  = (u16*)w;    w += sizeof(u16) * (size_t)N_NODES * IN_DIM;
  u16* win_h  = (u16*)w;    w += sizeof(u16) * (size_t)H * IN_DIM;
  u16* wl_h   = (u16*)w;    w += sizeof(u16) * (size_t)LAYERS * H * H;
  u16* wr_h   = (u16*)w;    w += sizeof(u16) * (size_t)LAYERS * H * H;
  u16* wg1_h  = (u16*)w;    w += sizeof(u16) * (size_t)H * H;
  float* pooled = (float*)w; w += sizeof(float) * NGRAPH * H;
  float* gate = (float*)w;  w += sizeof(float) * N_NODES;
  float* gmax = (float*)w;  w += sizeof(float) * NGRAPH;
  float* gdinv= (float*)w;  w += sizeof(float) * NGRAPH;
  int* cnt    = (int*)w;    w += sizeof(int) * N_NODES;
  int* rowp   = (int*)w;    w += sizeof(int) * (N_NODES + 1);
  int* col    = (int*)w;    w += sizeof(int) * EE;
  int* partial= (int*)w;    w += sizeof(int) * N_NODES;
  int* bsums  = (int*)w;    w += sizeof(int) * 256;
  int* gstart = (int*)w;    w += sizeof(int) * NGRAPH;
  int* gend   = (int*)w;    w += sizeof(int) * NGRAPH;
  (void)ws_size; (void)n_in; (void)in_sizes; (void)out_size;

  const int* src = eidx;
  const int* dst = eidx + N_EDGES;
  int nblkN = (N_NODES + 255) / 256;
  int nblkE = (N_EDGES + 255) / 256;
  int mtiles = (N_NODES + GTM - 1) / GTM;
  int mtiles2 = (N_NODES + DTM - 1) / DTM;

  // CSR build (by dst, self-loops included)
  init_counts_kernel<<<nblkN, 256, 0, stream>>>(cnt);
  count_edges_kernel<<<nblkE, 256, 0, stream>>>(dst, cnt);
  scan_blocks_kernel<<<nblkN, 256, 0, stream>>>(cnt, partial, bsums, N_NODES);
  scan_sums_kernel<<<1, 256, 0, stream>>>(bsums, nblkN);
  scan_write_kernel<<<nblkN, 256, 0, stream>>>(partial, bsums, rowp, N_NODES);
  fill_self_kernel<<<nblkN, 256, 0, stream>>>(rowp, col, cnt);
  fill_edges_kernel<<<nblkE, 256, 0, stream>>>(src, dst, cnt, col);

  // casts
  {
    int maxn4 = LAYERS * H * H / 4;
    dim3 gcast((maxn4 + 255) / 256, 4);
    cast_weights_kernel<<<gcast, 256, 0, stream>>>(W_in, Wg1, Wl, Wr,
                                                   win_h, wg1_h, wl_h, wr_h);
    int n4 = N_NODES * IN_DIM / 4;
    cast_f16_kernel<<<(n4 + 255) / 256, 256, 0, stream>>>(x_in, xin_h, n4);
  }

  // input projection -> x_h
  dim3 gproj(2, mtiles);
  gemm_proj_kernel<<<gproj, 256, 0, stream>>>(xin_h, win_h, b_in, x_h, N_NODES, IN_DIM);

  int nblkV = N_NODES / 4;
  for (int l = 0; l < LAYERS; l++) {
    gemm_dual2_kernel<<<mtiles2, 256, 0, stream>>>(x_h,
        wl_h + (size_t)l * H * H, wr_h + (size_t)l * H * H,
        bl + l * H, br + l * H, xl_h, xr_h, N_NODES);
    layer_fused_kernel<<<nblkV, 256, 0, stream>>>(xl_h, xr_h, x_h, rowp, col,
        att + l * H, bias_c + l * H, ln_g + l * H, ln_b + l * H);
  }

  // gate (fused GEMM + row-dot); gate_init also computes graph bounds
  gate_init_kernel<<<nblkN, 256, 0, stream>>>(gate, bg2, batch, gstart, gend);
  dim3 ggate(2, mtiles);
  gemm_gate_kernel<<<ggate, 256, 0, stream>>>(x_h, wg1_h, bg1, Wg2, gate, N_NODES);

  // pooling
  pool_prep_kernel<<<NGRAPH, 256, 0, stream>>>(gate, gstart, gend, gmax, gdinv, pooled);
  pool_accum_kernel<<<(N_NODES + 127) / 128, 256, 0, stream>>>(gate, x_h, batch, gmax, gdinv, pooled);

  // fused heads
  head_kernel<<<NGRAPH, 256, 0, stream>>>(pooled, Ws, bs, Wc, bc, Wr1, br1, Wr2, br2, out);
}

// Round 13
// 788.136 us; speedup vs baseline: 1.0423x; 1.0423x over previous
//
#include <hip/hip_runtime.h>
#include <math.h>

#define N_NODES 50000
#define N_EDGES 300000
#define IN_DIM 64
#define H 256
#define LAYERS 4
#define NB 181
#define NGRAPH 64
#define EE (N_EDGES + N_NODES)
#define NEG_SLOPE 0.2f
#define LN_EPS 1e-5f

typedef unsigned short u16;
typedef __attribute__((ext_vector_type(8))) _Float16 half8;
typedef __attribute__((ext_vector_type(4))) float floatx4;

__device__ __forceinline__ u16 f2h(float f) {
  _Float16 h = (_Float16)f;
  return __builtin_bit_cast(u16, h);
}
__device__ __forceinline__ float h2f(u16 b) {
  return (float)__builtin_bit_cast(_Float16, b);
}

__device__ __forceinline__ float wave_reduce_sum(float v) {
  #pragma unroll
  for (int off = 32; off > 0; off >>= 1) v += __shfl_xor(v, off, 64);
  return v;
}

// ---------------- casts ----------------
__global__ void cast_f16_kernel(const float* __restrict__ in, u16* __restrict__ out, int n4) {
  int i = blockIdx.x * 256 + threadIdx.x;
  if (i < n4) {
    float4 f = ((const float4*)in)[i];
    ushort4 o;
    o.x = f2h(f.x); o.y = f2h(f.y); o.z = f2h(f.z); o.w = f2h(f.w);
    ((ushort4*)out)[i] = o;
  }
}

__global__ void cast_weights_kernel(
    const float* __restrict__ W_in, const float* __restrict__ Wg1,
    const float* __restrict__ Wl, const float* __restrict__ Wr,
    u16* __restrict__ win_h, u16* __restrict__ wg1_h,
    u16* __restrict__ wl_h, u16* __restrict__ wr_h)
{
  int i = blockIdx.x * 256 + threadIdx.x;
  int which = blockIdx.y;
  const float* s; u16* dd; int n4;
  if (which == 0)      { s = W_in; dd = win_h; n4 = H * IN_DIM / 4; }
  else if (which == 1) { s = Wg1;  dd = wg1_h; n4 = H * H / 4; }
  else if (which == 2) { s = Wl;   dd = wl_h;  n4 = LAYERS * H * H / 4; }
  else                 { s = Wr;   dd = wr_h;  n4 = LAYERS * H * H / 4; }
  if (i < n4) {
    float4 f = ((const float4*)s)[i];
    ushort4 o;
    o.x = f2h(f.x); o.y = f2h(f.y); o.z = f2h(f.z); o.w = f2h(f.w);
    ((ushort4*)dd)[i] = o;
  }
}

// ---------------- CSR build ----------------
__global__ void init_counts_kernel(int* __restrict__ cnt) {
  int i = blockIdx.x * 256 + threadIdx.x;
  if (i < N_NODES) cnt[i] = 1;  // self loop
}

__global__ void count_edges_kernel(const int* __restrict__ dst, int* __restrict__ cnt) {
  int e = blockIdx.x * 256 + threadIdx.x;
  if (e < N_EDGES) atomicAdd(&cnt[dst[e]], 1);
}

__global__ void scan_blocks_kernel(const int* __restrict__ cnt, int* __restrict__ partial,
                                   int* __restrict__ bsums, int n) {
  __shared__ int buf[256];
  int tid = threadIdx.x;
  int i = blockIdx.x * 256 + tid;
  buf[tid] = (i < n) ? cnt[i] : 0;
  __syncthreads();
  #pragma unroll
  for (int off = 1; off < 256; off <<= 1) {
    int t = (tid >= off) ? buf[tid - off] : 0;
    __syncthreads();
    buf[tid] += t;
    __syncthreads();
  }
  if (i < n) partial[i] = buf[tid];
  if (tid == 255) bsums[blockIdx.x] = buf[255];
}

__global__ void scan_sums_kernel(int* __restrict__ bsums, int nblk) {
  __shared__ int buf[256];
  int tid = threadIdx.x;
  buf[tid] = (tid < nblk) ? bsums[tid] : 0;
  __syncthreads();
  #pragma unroll
  for (int off = 1; off < 256; off <<= 1) {
    int t = (tid >= off) ? buf[tid - off] : 0;
    __syncthreads();
    buf[tid] += t;
    __syncthreads();
  }
  if (tid < nblk) bsums[tid] = buf[tid];
}

__global__ void scan_write_kernel(const int* __restrict__ partial, const int* __restrict__ bsums,
                                  int* __restrict__ rowp, int n) {
  int i = blockIdx.x * 256 + threadIdx.x;
  if (i < n) {
    int b = blockIdx.x;
    int off = (b > 0) ? bsums[b - 1] : 0;
    rowp[i + 1] = partial[i] + off;
    if (i == 0) rowp[0] = 0;
  }
}

__global__ void fill_self_kernel(const int* __restrict__ rowp, int* __restrict__ col,
                                 int* __restrict__ fillpos) {
  int i = blockIdx.x * 256 + threadIdx.x;
  if (i < N_NODES) {
    int p = rowp[i];
    col[p] = i;
    fillpos[i] = p + 1;
  }
}

__global__ void fill_edges_kernel(const int* __restrict__ src, const int* __restrict__ dst,
                                  int* __restrict__ fillpos, int* __restrict__ col) {
  int e = blockIdx.x * 256 + threadIdx.x;
  if (e < N_EDGES) {
    int d = dst[e];
    int p = atomicAdd(&fillpos[d], 1);
    col[p] = src[e];
  }
}

// ---------------- MFMA GEMM tiles ----------------
#define GTM 128
#define GTK 64
#define LDB 72
#define SSTR 132

__global__ __launch_bounds__(256) void gemm_proj_kernel(
    const u16* __restrict__ A, const u16* __restrict__ W,
    const float* __restrict__ bias, u16* __restrict__ outh, int M, int K)
{
  __shared__ u16 smem[2 * GTM * LDB];
  u16* As = smem;
  u16* Bs = smem + GTM * LDB;
  int tid = threadIdx.x;
  int lane = tid & 63;
  int wave = tid >> 6;
  int wm = (wave >> 1) * 64;
  int wn = (wave & 1) * 64;
  int bm = blockIdx.y * GTM;
  int n0 = blockIdx.x * 128;
  int lr = tid >> 3;
  int lc = (tid & 7) * 8;

  floatx4 zero4 = {0.f, 0.f, 0.f, 0.f};
  floatx4 acc[4][4];
  #pragma unroll
  for (int i = 0; i < 4; i++)
    #pragma unroll
    for (int j = 0; j < 4; j++) acc[i][j] = zero4;

  int q8 = (lane >> 4) * 8;
  int mrow = lane & 15;

  for (int k0 = 0; k0 < K; k0 += GTK) {
    __syncthreads();
    #pragma unroll
    for (int p = 0; p < 4; p++) {
      int row = lr + p * 32;
      int gr = bm + row;
      uint4 av = {0, 0, 0, 0};
      if (gr < M) av = *(const uint4*)&A[(size_t)gr * K + k0 + lc];
      *(uint4*)&As[row * LDB + lc] = av;
      uint4 bv = *(const uint4*)&W[(size_t)(n0 + row) * K + k0 + lc];
      *(uint4*)&Bs[row * LDB + lc] = bv;
    }
    __syncthreads();
    #pragma unroll
    for (int h = 0; h < 2; h++) {
      half8 af[4], bf[4];
      #pragma unroll
      for (int i = 0; i < 4; i++)
        af[i] = *(const half8*)&As[(wm + i * 16 + mrow) * LDB + h * 32 + q8];
      #pragma unroll
      for (int j = 0; j < 4; j++)
        bf[j] = *(const half8*)&Bs[(wn + j * 16 + mrow) * LDB + h * 32 + q8];
      #pragma unroll
      for (int i = 0; i < 4; i++)
        #pragma unroll
        for (int j = 0; j < 4; j++)
          acc[i][j] = __builtin_amdgcn_mfma_f32_16x16x32_f16(af[i], bf[j], acc[i][j], 0, 0, 0);
    }
  }

  __syncthreads();
  u16* stage = smem;
  int ccol = lane & 15;
  int crow4 = (lane >> 4) * 4;
  #pragma unroll
  for (int j = 0; j < 4; j++) {
    float bv = bias[n0 + wn + j * 16 + ccol];
    #pragma unroll
    for (int i = 0; i < 4; i++) {
      #pragma unroll
      for (int r = 0; r < 4; r++) {
        int row = wm + i * 16 + crow4 + r;
        stage[row * SSTR + wn + j * 16 + ccol] = f2h(acc[i][j][r] + bv);
      }
    }
  }
  __syncthreads();
  int rr = tid >> 1;
  int c0 = (tid & 1) * 64;
  int grow = bm + rr;
  if (grow < M) {
    const ushort4* sp = (const ushort4*)&stage[rr * SSTR + c0];
    ushort4* gp = (ushort4*)&outh[(size_t)grow * H + n0 + c0];
    #pragma unroll
    for (int q = 0; q < 16; q++) gp[q] = sp[q];
  }
}

// ---------------- dual GEMM v4: A-resident + post-barrier register prefetch ----------------
#define DTM 64
#define AST 264
#define SSTR2 132

__global__ __launch_bounds__(256) void gemm_dual2_kernel(
    const u16* __restrict__ A, const u16* __restrict__ Wlb, const u16* __restrict__ Wrb,
    const float* __restrict__ biasL, const float* __restrict__ biasR,
    u16* __restrict__ outL, u16* __restrict__ outR, int M)
{
  __shared__ u16 As[DTM * AST];
  __shared__ u16 Bs[128 * LDB];
  int tid = threadIdx.x;
  int lane = tid & 63;
  int wave = tid >> 6;
  int wn = wave * 32;
  int bm = blockIdx.x * DTM;
  int mrow = lane & 15;
  int q8 = (lane >> 4) * 8;
  int ccol = lane & 15;
  int crow4 = (lane >> 4) * 4;
  int colB = (tid & 7) * 8;
  int r0B = tid >> 3;

  {
    int col = (tid & 31) * 8;
    int r0 = tid >> 5;
    #pragma unroll
    for (int it = 0; it < 8; it++) {
      int row = r0 + it * 8;
      int gr = bm + row;
      uint4 av = {0, 0, 0, 0};
      if (gr < M) av = *(const uint4*)&A[(size_t)gr * H + col];
      *(uint4*)&As[row * AST + col] = av;
    }
  }

  floatx4 zero4 = {0.f, 0.f, 0.f, 0.f};

  // initial register prefetch: nt=0, kk=0
  uint4 rB[4];
  #pragma unroll
  for (int p2 = 0; p2 < 4; p2++)
    rB[p2] = *(const uint4*)&Wlb[(size_t)(r0B + p2 * 32) * H + colB];

  for (int nt = 0; nt < 4; nt++) {
    const float* bias = (nt < 2) ? biasL : biasR;
    u16* outp = (nt < 2) ? outL : outR;
    const u16* W = (nt < 2) ? Wlb : Wrb;
    int n0 = (nt & 1) * 128;

    floatx4 acc[4][2];
    #pragma unroll
    for (int i = 0; i < 4; i++) {
      acc[i][0] = zero4;
      acc[i][1] = zero4;
    }

    for (int kk = 0; kk < 4; kk++) {
      __syncthreads();   // prior Bs readers done (MFMA / epilogue / A staging)
      #pragma unroll
      for (int p2 = 0; p2 < 4; p2++)
        *(uint4*)&Bs[(r0B + p2 * 32) * LDB + colB] = rB[p2];
      __syncthreads();   // Bs visible
      // prefetch next chunk NOW (after the barrier): loads stay in flight
      // through the MFMA section below and are waited at the NEXT store.
      if (kk < 3) {
        #pragma unroll
        for (int p2 = 0; p2 < 4; p2++)
          rB[p2] = *(const uint4*)&W[(size_t)(n0 + r0B + p2 * 32) * H + (kk + 1) * 64 + colB];
      } else if (nt < 3) {
        const u16* Wn = (nt + 1 < 2) ? Wlb : Wrb;
        int n0n = ((nt + 1) & 1) * 128;
        #pragma unroll
        for (int p2 = 0; p2 < 4; p2++)
          rB[p2] = *(const uint4*)&Wn[(size_t)(n0n + r0B + p2 * 32) * H + colB];
      }
      #pragma unroll
      for (int h = 0; h < 2; h++) {
        half8 af[4], bf[2];
        #pragma unroll
        for (int i = 0; i < 4; i++)
          af[i] = *(const half8*)&As[(i * 16 + mrow) * AST + kk * 64 + h * 32 + q8];
        #pragma unroll
        for (int j = 0; j < 2; j++)
          bf[j] = *(const half8*)&Bs[(wn + j * 16 + mrow) * LDB + h * 32 + q8];
        #pragma unroll
        for (int i = 0; i < 4; i++)
          #pragma unroll
          for (int j = 0; j < 2; j++)
            acc[i][j] = __builtin_amdgcn_mfma_f32_16x16x32_f16(af[i], bf[j], acc[i][j], 0, 0, 0);
      }
    }

    __syncthreads();
    u16* stage = Bs;
    #pragma unroll
    for (int j = 0; j < 2; j++) {
      float bv = bias[n0 + wn + j * 16 + ccol];
      #pragma unroll
      for (int i = 0; i < 4; i++) {
        #pragma unroll
        for (int r = 0; r < 4; r++) {
          int row = i * 16 + crow4 + r;
          stage[row * SSTR2 + wn + j * 16 + ccol] = f2h(acc[i][j][r] + bv);
        }
      }
    }
    __syncthreads();
    {
      // fully coalesced copy: 4 passes x (256 threads x 16B) = 16 KB tile
      #pragma unroll
      for (int pass = 0; pass < 4; pass++) {
        int row = pass * 16 + (tid >> 4);
        int cu = (tid & 15) * 8;
        int grow = bm + row;
        if (grow < M) {
          *(uint4*)&outp[(size_t)grow * H + n0 + cu] =
              *(const uint4*)&stage[row * SSTR2 + cu];
        }
      }
    }
  }
}

// gate GEMM: gate[row] += sum_col relu(x@Wg1 + bg1)[col] * Wg2[col]; gate pre-init to bg2
__global__ __launch_bounds__(256) void gemm_gate_kernel(
    const u16* __restrict__ A, const u16* __restrict__ W,
    const float* __restrict__ bias, const float* __restrict__ Wg2,
    float* __restrict__ gate, int M)
{
  __shared__ u16 smem[2 * GTM * LDB];
  u16* As = smem;
  u16* Bs = smem + GTM * LDB;
  int tid = threadIdx.x;
  int lane = tid & 63;
  int wave = tid >> 6;
  int wm = (wave >> 1) * 64;
  int wn = (wave & 1) * 64;
  int bm = blockIdx.y * GTM;
  int bn = blockIdx.x * 128;
  int lr = tid >> 3;
  int lc = (tid & 7) * 8;

  floatx4 zero4 = {0.f, 0.f, 0.f, 0.f};
  floatx4 acc[4][4];
  #pragma unroll
  for (int i = 0; i < 4; i++)
    #pragma unroll
    for (int j = 0; j < 4; j++) acc[i][j] = zero4;

  int q8 = (lane >> 4) * 8;
  int mrow = lane & 15;

  for (int k0 = 0; k0 < H; k0 += GTK) {
    __syncthreads();
    #pragma unroll
    for (int p = 0; p < 4; p++) {
      int row = lr + p * 32;
      int gr = bm + row;
      uint4 av = {0, 0, 0, 0};
      if (gr < M) av = *(const uint4*)&A[(size_t)gr * H + k0 + lc];
      *(uint4*)&As[row * LDB + lc] = av;
      uint4 bv = *(const uint4*)&W[(size_t)(bn + row) * H + k0 + lc];
      *(uint4*)&Bs[row * LDB + lc] = bv;
    }
    __syncthreads();
    #pragma unroll
    for (int h = 0; h < 2; h++) {
      half8 af[4], bf[4];
      #pragma unroll
      for (int i = 0; i < 4; i++)
        af[i] = *(const half8*)&As[(wm + i * 16 + mrow) * LDB + h * 32 + q8];
      #pragma unroll
      for (int j = 0; j < 4; j++)
        bf[j] = *(const half8*)&Bs[(wn + j * 16 + mrow) * LDB + h * 32 + q8];
      #pragma unroll
      for (int i = 0; i < 4; i++)
        #pragma unroll
        for (int j = 0; j < 4; j++)
          acc[i][j] = __builtin_amdgcn_mfma_f32_16x16x32_f16(af[i], bf[j], acc[i][j], 0, 0, 0);
    }
  }

  int ccol = lane & 15;
  float bv[4], wv[4];
  #pragma unroll
  for (int j = 0; j < 4; j++) {
    int col = bn + wn + j * 16 + ccol;
    bv[j] = bias[col];
    wv[j] = Wg2[col];
  }
  #pragma unroll
  for (int i = 0; i < 4; i++) {
    #pragma unroll
    for (int r = 0; r < 4; r++) {
      float p = 0.f;
      #pragma unroll
      for (int j = 0; j < 4; j++) {
        float hcol = fmaxf(acc[i][j][r] + bv[j], 0.f);
        p += hcol * wv[j];
      }
      p += __shfl_xor(p, 1, 64);
      p += __shfl_xor(p, 2, 64);
      p += __shfl_xor(p, 4, 64);
      p += __shfl_xor(p, 8, 64);
      int row = bm + wm + i * 16 + (lane >> 4) * 4 + r;
      if ((lane & 15) == 0 && row < M) atomicAdd(&gate[row], p);
    }
  }
}

// ---------------- fused edge softmax + aggregate + LN + residual (R11 unroll-2) ----------------
__global__ __launch_bounds__(256) void layer_fused_kernel(
    const u16* __restrict__ xl, const u16* __restrict__ xr,
    u16* __restrict__ xst,
    const int* __restrict__ rowp, const int* __restrict__ col,
    const float* __restrict__ att, const float* __restrict__ bias_c,
    const float* __restrict__ ln_g, const float* __restrict__ ln_b)
{
  int lane = threadIdx.x & 63;
  int v = blockIdx.x * 4 + (threadIdx.x >> 6);
  if (v >= N_NODES) return;
  int f4 = lane << 2;
  size_t rowbase = (size_t)v * H;
  ushort4 xr4 = *(const ushort4*)&xr[rowbase + f4];
  float xrx = h2f(xr4.x), xry = h2f(xr4.y), xrz = h2f(xr4.z), xrw = h2f(xr4.w);
  float4 attv = *(const float4*)&att[f4];
  int beg = rowp[v], end = rowp[v + 1];
  float m = -INFINITY, d = 0.f;
  float ox = 0.f, oy = 0.f, oz = 0.f, ow = 0.f;
  int p = beg;
  for (; p + 2 <= end; p += 2) {
    int u0 = col[p];
    int u1 = col[p + 1];
    ushort4 a04 = *(const ushort4*)&xl[(size_t)u0 * H + f4];
    ushort4 a14 = *(const ushort4*)&xl[(size_t)u1 * H + f4];
    float a0x = h2f(a04.x), a0y = h2f(a04.y), a0z = h2f(a04.z), a0w = h2f(a04.w);
    float a1x = h2f(a14.x), a1y = h2f(a14.y), a1z = h2f(a14.z), a1w = h2f(a14.w);
    float t0x = a0x + xrx; t0x = t0x > 0.f ? t0x : NEG_SLOPE * t0x;
    float t0y = a0y + xry; t0y = t0y > 0.f ? t0y : NEG_SLOPE * t0y;
    float t0z = a0z + xrz; t0z = t0z > 0.f ? t0z : NEG_SLOPE * t0z;
    float t0w = a0w + xrw; t0w = t0w > 0.f ? t0w : NEG_SLOPE * t0w;
    float t1x = a1x + xrx; t1x = t1x > 0.f ? t1x : NEG_SLOPE * t1x;
    float t1y = a1y + xry; t1y = t1y > 0.f ? t1y : NEG_SLOPE * t1y;
    float t1z = a1z + xrz; t1z = t1z > 0.f ? t1z : NEG_SLOPE * t1z;
    float t1w = a1w + xrw; t1w = t1w > 0.f ? t1w : NEG_SLOPE * t1w;
    float pe0 = t0x * attv.x + t0y * attv.y + t0z * attv.z + t0w * attv.w;
    float pe1 = t1x * attv.x + t1y * attv.y + t1z * attv.z + t1w * attv.w;
    #pragma unroll
    for (int off = 32; off > 0; off >>= 1) {
      pe0 += __shfl_xor(pe0, off, 64);
      pe1 += __shfl_xor(pe1, off, 64);
    }
    float mn = fmaxf(m, fmaxf(pe0, pe1));
    float sc = __expf(m - mn);
    float w0 = __expf(pe0 - mn);
    float w1 = __expf(pe1 - mn);
    d = fmaf(d, sc, w0 + w1);
    ox = fmaf(ox, sc, fmaf(w0, a0x, w1 * a1x));
    oy = fmaf(oy, sc, fmaf(w0, a0y, w1 * a1y));
    oz = fmaf(oz, sc, fmaf(w0, a0z, w1 * a1z));
    ow = fmaf(ow, sc, fmaf(w0, a0w, w1 * a1w));
    m = mn;
  }
  if (p < end) {
    int u0 = col[p];
    ushort4 a04 = *(const ushort4*)&xl[(size_t)u0 * H + f4];
    float a0x = h2f(a04.x), a0y = h2f(a04.y), a0z = h2f(a04.z), a0w = h2f(a04.w);
    float t0x = a0x + xrx; t0x = t0x > 0.f ? t0x : NEG_SLOPE * t0x;
    float t0y = a0y + xry; t0y = t0y > 0.f ? t0y : NEG_SLOPE * t0y;
    float t0z = a0z + xrz; t0z = t0z > 0.f ? t0z : NEG_SLOPE * t0z;
    float t0w = a0w + xrw; t0w = t0w > 0.f ? t0w : NEG_SLOPE * t0w;
    float pe0 = t0x * attv.x + t0y * attv.y + t0z * attv.z + t0w * attv.w;
    pe0 = wave_reduce_sum(pe0);
    float mn = fmaxf(m, pe0);
    float sc = __expf(m - mn);
    float w0 = __expf(pe0 - mn);
    d = fmaf(d, sc, w0);
    ox = fmaf(ox, sc, w0 * a0x);
    oy = fmaf(oy, sc, w0 * a0y);
    oz = fmaf(oz, sc, w0 * a0z);
    ow = fmaf(ow, sc, w0 * a0w);
    m = mn;
  }
  float invd = 1.0f / d;
  float4 bc4 = *(const float4*)&bias_c[f4];
  ox = ox * invd + bc4.x;
  oy = oy * invd + bc4.y;
  oz = oz * invd + bc4.z;
  ow = ow * invd + bc4.w;
  float s = wave_reduce_sum(ox + oy + oz + ow);
  float mean = s * (1.0f / H);
  float cx = ox - mean, cy = oy - mean, cz = oz - mean, cw = ow - mean;
  float sq = wave_reduce_sum(cx * cx + cy * cy + cz * cz + cw * cw);
  float rstd = rsqrtf(sq * (1.0f / H) + LN_EPS);
  float4 g4 = *(const float4*)&ln_g[f4];
  float4 b4 = *(const float4*)&ln_b[f4];
  ushort4 xres4 = *(const ushort4*)&xst[rowbase + f4];
  float yx = fmaxf(fmaf(cx * rstd, g4.x, b4.x), 0.f) + h2f(xres4.x);
  float yy = fmaxf(fmaf(cy * rstd, g4.y, b4.y), 0.f) + h2f(xres4.y);
  float yz = fmaxf(fmaf(cz * rstd, g4.z, b4.z), 0.f) + h2f(xres4.z);
  float yw = fmaxf(fmaf(cw * rstd, g4.w, b4.w), 0.f) + h2f(xres4.w);
  ushort4 yb;
  yb.x = f2h(yx); yb.y = f2h(yy); yb.z = f2h(yz); yb.w = f2h(yw);
  *(ushort4*)&xst[rowbase + f4] = yb;
}

// ---------------- gate init + graph bounds (merged; batch sorted) ----------------
__global__ void gate_init_kernel(float* __restrict__ gate, const float* __restrict__ bg2,
                                 const int* __restrict__ batch,
                                 int* __restrict__ gstart, int* __restrict__ gend) {
  int i = blockIdx.x * 256 + threadIdx.x;
  if (i < N_NODES) {
    gate[i] = bg2[0];
    int b = batch[i];
    if (i == 0 || batch[i - 1] != b) gstart[b] = i;
    if (i == N_NODES - 1 || batch[i + 1] != b) gend[b] = i + 1;
  }
}

// ---------------- pooling: per-graph softmax stats (+ pooled zero) ----------------
__global__ __launch_bounds__(256) void pool_prep_kernel(
    const float* __restrict__ gate, const int* __restrict__ gstart,
    const int* __restrict__ gend, float* __restrict__ gmax, float* __restrict__ gdinv,
    float* __restrict__ pooled)
{
  __shared__ float red[256];
  int g = blockIdx.x, tid = threadIdx.x;
  pooled[(size_t)g * H + tid] = 0.f;
  int s = gstart[g], e = gend[g];
  float lm = -INFINITY;
  for (int i = s + tid; i < e; i += 256) lm = fmaxf(lm, gate[i]);
  red[tid] = lm;
  __syncthreads();
  for (int off = 128; off; off >>= 1) {
    if (tid < off) red[tid] = fmaxf(red[tid], red[tid + off]);
    __syncthreads();
  }
  float m = red[0];
  __syncthreads();
  float lsum = 0.0f;
  for (int i = s + tid; i < e; i += 256) lsum += __expf(gate[i] - m);
  red[tid] = lsum;
  __syncthreads();
  for (int off = 128; off; off >>= 1) {
    if (tid < off) red[tid] += red[tid + off];
    __syncthreads();
  }
  if (tid == 0) {
    gmax[g] = m;
    gdinv[g] = (s < e) ? 1.0f / red[0] : 0.0f;
  }
}

// ---------------- pooling: weighted accumulate (128 nodes per block, fp16 x) ----------------
__global__ __launch_bounds__(256) void pool_accum_kernel(
    const float* __restrict__ gate, const u16* __restrict__ xh,
    const int* __restrict__ batch, const float* __restrict__ gmax,
    const float* __restrict__ gdinv, float* __restrict__ pooled)
{
  __shared__ float wl[128];
  __shared__ int gl[128];
  int b0 = blockIdx.x * 128;
  int tid = threadIdx.x;
  if (tid < 128) {
    int v = b0 + tid;
    if (v < N_NODES) {
      int g = batch[v];
      gl[tid] = g;
      wl[tid] = __expf(gate[v] - gmax[g]) * gdinv[g];
    } else {
      gl[tid] = -1;
      wl[tid] = 0.f;
    }
  }
  __syncthreads();
  int cnt = min(128, N_NODES - b0);
  float acc = 0.f;
  int cur = gl[0];
  for (int j = 0; j < cnt; j++) {
    int g = gl[j];
    if (g != cur) {
      atomicAdd(&pooled[(size_t)cur * H + tid], acc);
      acc = 0.f;
      cur = g;
    }
    acc += wl[j] * h2f(xh[(size_t)(b0 + j) * H + tid]);
  }
  if (cur >= 0) atomicAdd(&pooled[(size_t)cur * H + tid], acc);
}

// ---------------- fused head: pooled -> z -> {cls, r1} -> residual ----------------
__global__ __launch_bounds__(256) void head_kernel(
    const float* __restrict__ pooled,
    const float* __restrict__ Ws, const float* __restrict__ bs,
    const float* __restrict__ Wc, const float* __restrict__ bc,
    const float* __restrict__ Wr1, const float* __restrict__ br1,
    const float* __restrict__ Wr2, const float* __restrict__ br2,
    float* __restrict__ out)
{
  __shared__ float psh[256];
  __shared__ float zsh[256];
  __shared__ float r1sh[128];
  int g = blockIdx.x, tid = threadIdx.x;
  psh[tid] = pooled[(size_t)g * H + tid];
  __syncthreads();
  {
    float acc = bs[tid];
    const float4* wr = (const float4*)&Ws[(size_t)tid * H];
    for (int k4 = 0; k4 < H / 4; k4++) {
      float4 wv = wr[k4];
      float4 av = *(const float4*)&psh[k4 * 4];
      acc += av.x * wv.x + av.y * wv.y + av.z * wv.z + av.w * wv.w;
    }
    zsh[tid] = fmaxf(acc, 0.f);
  }
  __syncthreads();
  if (tid < NB) {
    float acc = bc[tid];
    const float4* wr = (const float4*)&Wc[(size_t)tid * H];
    for (int k4 = 0; k4 < H / 4; k4++) {
      float4 wv = wr[k4];
      float4 av = *(const float4*)&zsh[k4 * 4];
      acc += av.x * wv.x + av.y * wv.y + av.z * wv.z + av.w * wv.w;
    }
    out[(size_t)g * NB + tid] = acc;
  }
  if (tid < 128) {
    float acc = br1[tid];
    const float4* wr = (const float4*)&Wr1[(size_t)tid * H];
    for (int k4 = 0; k4 < H / 4; k4++) {
      float4 wv = wr[k4];
      float4 av = *(const float4*)&zsh[k4 * 4];
      acc += av.x * wv.x + av.y * wv.y + av.z * wv.z + av.w * wv.w;
    }
    r1sh[tid] = fmaxf(acc, 0.f);
  }
  __syncthreads();
  if (tid < 64) {
    float s2 = r1sh[tid] * Wr2[tid] + r1sh[tid + 64] * Wr2[tid + 64];
    s2 = wave_reduce_sum(s2);
    if (tid == 0) out[(size_t)NGRAPH * NB + g] = tanhf(s2 + br2[0]);
  }
}

// ---------------- launcher ----------------
extern "C" void kernel_launch(void* const* d_in, const int* in_sizes, int n_in,
                              void* d_out, int out_size, void* d_ws, size_t ws_size,
                              hipStream_t stream) {
  const float* x_in   = (const float*)d_in[0];
  const int*   eidx   = (const int*)d_in[1];
  const int*   batch  = (const int*)d_in[2];
  const float* W_in   = (const float*)d_in[3];
  const float* b_in   = (const float*)d_in[4];
  const float* Wl     = (const float*)d_in[5];
  const float* bl     = (const float*)d_in[6];
  const float* Wr     = (const float*)d_in[7];
  const float* br     = (const float*)d_in[8];
  const float* att    = (const float*)d_in[9];
  const float* bias_c = (const float*)d_in[10];
  const float* ln_g   = (const float*)d_in[11];
  const float* ln_b   = (const float*)d_in[12];
  const float* Wg1    = (const float*)d_in[13];
  const float* bg1    = (const float*)d_in[14];
  const float* Wg2    = (const float*)d_in[15];
  const float* bg2    = (const float*)d_in[16];
  const float* Ws     = (const float*)d_in[17];
  const float* bs     = (const float*)d_in[18];
  const float* Wc     = (const float*)d_in[19];
  const float* bc     = (const float*)d_in[20];
  const float* Wr1    = (const float*)d_in[21];
  const float* br1    = (const float*)d_in[22];
  const float* Wr2    = (const float*)d_in[23];
  const float* br2    = (const float*)d_in[24];
  float* out = (float*)d_out;

  char* w = (char*)d_ws;
  u16* x_h    = (u16*)w;    w += sizeof(u16) * (size_t)N_NODES * H;
  u16* xl_h   = (u16*)w;    w += sizeof(u16) * (size_t)N_NODES * H;
  u16* xr_h   = (u16*)w;    w += sizeof(u16) * (size_t)N_NODES * H;
  u16* xin_h  = (u16*)w;    w += sizeof(u16) * (size_t)N_NODES * IN_DIM;
  u16* win_h  = (u16*)w;    w += sizeof(u16) * (size_t)H * IN_DIM;
  u16* wl_h   = (u16*)w;    w += sizeof(u16) * (size_t)LAYERS * H * H;
  u16* wr_h   = (u16*)w;    w += sizeof(u16) * (size_t)LAYERS * H * H;
  u16* wg1_h  = (u16*)w;    w += sizeof(u16) * (size_t)H * H;
  float* pooled = (float*)w; w += sizeof(float) * NGRAPH * H;
  float* gate = (float*)w;  w += sizeof(float) * N_NODES;
  float* gmax = (float*)w;  w += sizeof(float) * NGRAPH;
  float* gdinv= (float*)w;  w += sizeof(float) * NGRAPH;
  int* cnt    = (int*)w;    w += sizeof(int) * N_NODES;
  int* rowp   = (int*)w;    w += sizeof(int) * (N_NODES + 1);
  int* col    = (int*)w;    w += sizeof(int) * EE;
  int* partial= (int*)w;    w += sizeof(int) * N_NODES;
  int* bsums  = (int*)w;    w += sizeof(int) * 256;
  int* gstart = (int*)w;    w += sizeof(int) * NGRAPH;
  int* gend   = (int*)w;    w += sizeof(int) * NGRAPH;
  (void)ws_size; (void)n_in; (void)in_sizes; (void)out_size;

  const int* src = eidx;
  const int* dst = eidx + N_EDGES;
  int nblkN = (N_NODES + 255) / 256;
  int nblkE = (N_EDGES + 255) / 256;
  int mtiles = (N_NODES + GTM - 1) / GTM;
  int mtiles2 = (N_NODES + DTM - 1) / DTM;

  // CSR build (by dst, self-loops included)
  init_counts_kernel<<<nblkN, 256, 0, stream>>>(cnt);
  count_edges_kernel<<<nblkE, 256, 0, stream>>>(dst, cnt);
  scan_blocks_kernel<<<nblkN, 256, 0, stream>>>(cnt, partial, bsums, N_NODES);
  scan_sums_kernel<<<1, 256, 0, stream>>>(bsums, nblkN);
  scan_write_kernel<<<nblkN, 256, 0, stream>>>(partial, bsums, rowp, N_NODES);
  fill_self_kernel<<<nblkN, 256, 0, stream>>>(rowp, col, cnt);
  fill_edges_kernel<<<nblkE, 256, 0, stream>>>(src, dst, cnt, col);

  // casts
  {
    int maxn4 = LAYERS * H * H / 4;
    dim3 gcast((maxn4 + 255) / 256, 4);
    cast_weights_kernel<<<gcast, 256, 0, stream>>>(W_in, Wg1, Wl, Wr,
                                                   win_h, wg1_h, wl_h, wr_h);
    int n4 = N_NODES * IN_DIM / 4;
    cast_f16_kernel<<<(n4 + 255) / 256, 256, 0, stream>>>(x_in, xin_h, n4);
  }

  // input projection -> x_h
  dim3 gproj(2, mtiles);
  gemm_proj_kernel<<<gproj, 256, 0, stream>>>(xin_h, win_h, b_in, x_h, N_NODES, IN_DIM);

  int nblkV = N_NODES / 4;
  for (int l = 0; l < LAYERS; l++) {
    gemm_dual2_kernel<<<mtiles2, 256, 0, stream>>>(x_h,
        wl_h + (size_t)l * H * H, wr_h + (size_t)l * H * H,
        bl + l * H, br + l * H, xl_h, xr_h, N_NODES);
    layer_fused_kernel<<<nblkV, 256, 0, stream>>>(xl_h, xr_h, x_h, rowp, col,
        att + l * H, bias_c + l * H, ln_g + l * H, ln_b + l * H);
  }

  // gate (fused GEMM + row-dot); gate_init also computes graph bounds
  gate_init_kernel<<<nblkN, 256, 0, stream>>>(gate, bg2, batch, gstart, gend);
  dim3 ggate(2, mtiles);
  gemm_gate_kernel<<<ggate, 256, 0, stream>>>(x_h, wg1_h, bg1, Wg2, gate, N_NODES);

  // pooling
  pool_prep_kernel<<<NGRAPH, 256, 0, stream>>>(gate, gstart, gend, gmax, gdinv, pooled);
  pool_accum_kernel<<<(N_NODES + 127) / 128, 256, 0, stream>>>(gate, x_h, batch, gmax, gdinv, pooled);

  // fused heads
  head_kernel<<<NGRAPH, 256, 0, stream>>>(pooled, Ws, bs, Wc, bc, Wr1, br1, Wr2, br2, out);
}

// Round 14
// 600.333 us; speedup vs baseline: 1.3684x; 1.3128x over previous
//
#include <hip/hip_runtime.h>
#include <math.h>

#define N_NODES 50000
#define N_EDGES 300000
#define IN_DIM 64
#define H 256
#define LAYERS 4
#define NB 181
#define NGRAPH 64
#define EE (N_EDGES + N_NODES)
#define NEG_SLOPE 0.2f
#define LN_EPS 1e-5f

typedef unsigned short u16;
typedef __attribute__((ext_vector_type(8))) _Float16 half8;
typedef __attribute__((ext_vector_type(4))) float floatx4;

__device__ __forceinline__ u16 f2h(float f) {
  _Float16 h = (_Float16)f;
  return __builtin_bit_cast(u16, h);
}
__device__ __forceinline__ float h2f(u16 b) {
  return (float)__builtin_bit_cast(_Float16, b);
}

__device__ __forceinline__ float wave_reduce_sum(float v) {
  #pragma unroll
  for (int off = 32; off > 0; off >>= 1) v += __shfl_xor(v, off, 64);
  return v;
}

// ---------------- casts ----------------
__global__ void cast_f16_kernel(const float* __restrict__ in, u16* __restrict__ out, int n4) {
  int i = blockIdx.x * 256 + threadIdx.x;
  if (i < n4) {
    float4 f = ((const float4*)in)[i];
    ushort4 o;
    o.x = f2h(f.x); o.y = f2h(f.y); o.z = f2h(f.z); o.w = f2h(f.w);
    ((ushort4*)out)[i] = o;
  }
}

__global__ void cast_weights_kernel(
    const float* __restrict__ W_in, const float* __restrict__ Wg1,
    const float* __restrict__ Wl, const float* __restrict__ Wr,
    u16* __restrict__ win_h, u16* __restrict__ wg1_h,
    u16* __restrict__ wl_h, u16* __restrict__ wr_h)
{
  int i = blockIdx.x * 256 + threadIdx.x;
  int which = blockIdx.y;
  const float* s; u16* dd; int n4;
  if (which == 0)      { s = W_in; dd = win_h; n4 = H * IN_DIM / 4; }
  else if (which == 1) { s = Wg1;  dd = wg1_h; n4 = H * H / 4; }
  else if (which == 2) { s = Wl;   dd = wl_h;  n4 = LAYERS * H * H / 4; }
  else                 { s = Wr;   dd = wr_h;  n4 = LAYERS * H * H / 4; }
  if (i < n4) {
    float4 f = ((const float4*)s)[i];
    ushort4 o;
    o.x = f2h(f.x); o.y = f2h(f.y); o.z = f2h(f.z); o.w = f2h(f.w);
    ((ushort4*)dd)[i] = o;
  }
}

// ---------------- CSR build ----------------
__global__ void init_counts_kernel(int* __restrict__ cnt) {
  int i = blockIdx.x * 256 + threadIdx.x;
  if (i < N_NODES) cnt[i] = 1;  // self loop
}

__global__ void count_edges_kernel(const int* __restrict__ dst, int* __restrict__ cnt) {
  int e = blockIdx.x * 256 + threadIdx.x;
  if (e < N_EDGES) atomicAdd(&cnt[dst[e]], 1);
}

__global__ void scan_blocks_kernel(const int* __restrict__ cnt, int* __restrict__ partial,
                                   int* __restrict__ bsums, int n) {
  __shared__ int buf[256];
  int tid = threadIdx.x;
  int i = blockIdx.x * 256 + tid;
  buf[tid] = (i < n) ? cnt[i] : 0;
  __syncthreads();
  #pragma unroll
  for (int off = 1; off < 256; off <<= 1) {
    int t = (tid >= off) ? buf[tid - off] : 0;
    __syncthreads();
    buf[tid] += t;
    __syncthreads();
  }
  if (i < n) partial[i] = buf[tid];
  if (tid == 255) bsums[blockIdx.x] = buf[255];
}

__global__ void scan_sums_kernel(int* __restrict__ bsums, int nblk) {
  __shared__ int buf[256];
  int tid = threadIdx.x;
  buf[tid] = (tid < nblk) ? bsums[tid] : 0;
  __syncthreads();
  #pragma unroll
  for (int off = 1; off < 256; off <<= 1) {
    int t = (tid >= off) ? buf[tid - off] : 0;
    __syncthreads();
    buf[tid] += t;
    __syncthreads();
  }
  if (tid < nblk) bsums[tid] = buf[tid];
}

__global__ void scan_write_kernel(const int* __restrict__ partial, const int* __restrict__ bsums,
                                  int* __restrict__ rowp, int n) {
  int i = blockIdx.x * 256 + threadIdx.x;
  if (i < n) {
    int b = blockIdx.x;
    int off = (b > 0) ? bsums[b - 1] : 0;
    rowp[i + 1] = partial[i] + off;
    if (i == 0) rowp[0] = 0;
  }
}

__global__ void fill_self_kernel(const int* __restrict__ rowp, int* __restrict__ col,
                                 int* __restrict__ fillpos) {
  int i = blockIdx.x * 256 + threadIdx.x;
  if (i < N_NODES) {
    int p = rowp[i];
    col[p] = i;
    fillpos[i] = p + 1;
  }
}

__global__ void fill_edges_kernel(const int* __restrict__ src, const int* __restrict__ dst,
                                  int* __restrict__ fillpos, int* __restrict__ col) {
  int e = blockIdx.x * 256 + threadIdx.x;
  if (e < N_EDGES) {
    int d = dst[e];
    int p = atomicAdd(&fillpos[d], 1);
    col[p] = src[e];
  }
}

// ---------------- MFMA GEMM tiles ----------------
#define GTM 128
#define GTK 64
#define LDB 72
#define SSTR 132

__global__ __launch_bounds__(256) void gemm_proj_kernel(
    const u16* __restrict__ A, const u16* __restrict__ W,
    const float* __restrict__ bias, u16* __restrict__ outh, int M, int K)
{
  __shared__ u16 smem[2 * GTM * LDB];
  u16* As = smem;
  u16* Bs = smem + GTM * LDB;
  int tid = threadIdx.x;
  int lane = tid & 63;
  int wave = tid >> 6;
  int wm = (wave >> 1) * 64;
  int wn = (wave & 1) * 64;
  int bm = blockIdx.y * GTM;
  int n0 = blockIdx.x * 128;
  int lr = tid >> 3;
  int lc = (tid & 7) * 8;

  floatx4 zero4 = {0.f, 0.f, 0.f, 0.f};
  floatx4 acc[4][4];
  #pragma unroll
  for (int i = 0; i < 4; i++)
    #pragma unroll
    for (int j = 0; j < 4; j++) acc[i][j] = zero4;

  int q8 = (lane >> 4) * 8;
  int mrow = lane & 15;

  for (int k0 = 0; k0 < K; k0 += GTK) {
    __syncthreads();
    #pragma unroll
    for (int p = 0; p < 4; p++) {
      int row = lr + p * 32;
      int gr = bm + row;
      uint4 av = {0, 0, 0, 0};
      if (gr < M) av = *(const uint4*)&A[(size_t)gr * K + k0 + lc];
      *(uint4*)&As[row * LDB + lc] = av;
      uint4 bv = *(const uint4*)&W[(size_t)(n0 + row) * K + k0 + lc];
      *(uint4*)&Bs[row * LDB + lc] = bv;
    }
    __syncthreads();
    #pragma unroll
    for (int h = 0; h < 2; h++) {
      half8 af[4], bf[4];
      #pragma unroll
      for (int i = 0; i < 4; i++)
        af[i] = *(const half8*)&As[(wm + i * 16 + mrow) * LDB + h * 32 + q8];
      #pragma unroll
      for (int j = 0; j < 4; j++)
        bf[j] = *(const half8*)&Bs[(wn + j * 16 + mrow) * LDB + h * 32 + q8];
      #pragma unroll
      for (int i = 0; i < 4; i++)
        #pragma unroll
        for (int j = 0; j < 4; j++)
          acc[i][j] = __builtin_amdgcn_mfma_f32_16x16x32_f16(af[i], bf[j], acc[i][j], 0, 0, 0);
    }
  }

  __syncthreads();
  u16* stage = smem;
  int ccol = lane & 15;
  int crow4 = (lane >> 4) * 4;
  #pragma unroll
  for (int j = 0; j < 4; j++) {
    float bv = bias[n0 + wn + j * 16 + ccol];
    #pragma unroll
    for (int i = 0; i < 4; i++) {
      #pragma unroll
      for (int r = 0; r < 4; r++) {
        int row = wm + i * 16 + crow4 + r;
        stage[row * SSTR + wn + j * 16 + ccol] = f2h(acc[i][j][r] + bv);
      }
    }
  }
  __syncthreads();
  int rr = tid >> 1;
  int c0 = (tid & 1) * 64;
  int grow = bm + rr;
  if (grow < M) {
    const ushort4* sp = (const ushort4*)&stage[rr * SSTR + c0];
    ushort4* gp = (ushort4*)&outh[(size_t)grow * H + n0 + c0];
    #pragma unroll
    for (int q = 0; q < 16; q++) gp[q] = sp[q];
  }
}

// ---------------- dual GEMM v5: one n-tile per block, 64-row m-tiles, 27.6 KB LDS ----------------
#define DTM 64
#define SSTR2 132

__global__ __launch_bounds__(256) void gemm_dual3_kernel(
    const u16* __restrict__ A, const u16* __restrict__ Wlb, const u16* __restrict__ Wrb,
    const float* __restrict__ biasL, const float* __restrict__ biasR,
    u16* __restrict__ outL, u16* __restrict__ outR, int M)
{
  __shared__ u16 As[DTM * LDB];    // 64 x 72 (9.2 KB)
  __shared__ u16 Bs[128 * LDB];    // 128 x 72 (18.4 KB; reused as epilogue stage)
  int tid = threadIdx.x;
  int lane = tid & 63;
  int wave = tid >> 6;
  int wn = wave * 32;
  int nt = blockIdx.x;             // 0..3
  int bm = blockIdx.y * DTM;
  const u16* W = (nt < 2) ? Wlb : Wrb;
  const float* bias = (nt < 2) ? biasL : biasR;
  u16* outp = (nt < 2) ? outL : outR;
  int n0 = (nt & 1) * 128;
  int mrow = lane & 15;
  int q8 = (lane >> 4) * 8;
  int ccol = lane & 15;
  int crow4 = (lane >> 4) * 4;
  int lr = tid >> 3;               // 0..31
  int lc = (tid & 7) * 8;          // 0..56

  floatx4 zero4 = {0.f, 0.f, 0.f, 0.f};
  floatx4 acc[4][2];
  #pragma unroll
  for (int i = 0; i < 4; i++) {
    acc[i][0] = zero4;
    acc[i][1] = zero4;
  }

  for (int k0 = 0; k0 < H; k0 += 64) {
    __syncthreads();
    // stage A chunk: 64 rows x 64 cols (2 passes)
    #pragma unroll
    for (int p = 0; p < 2; p++) {
      int row = lr + p * 32;
      int gr = bm + row;
      uint4 av = {0, 0, 0, 0};
      if (gr < M) av = *(const uint4*)&A[(size_t)gr * H + k0 + lc];
      *(uint4*)&As[row * LDB + lc] = av;
    }
    // stage B chunk: 128 rows x 64 cols (4 passes)
    #pragma unroll
    for (int p = 0; p < 4; p++) {
      int row = lr + p * 32;
      uint4 bv = *(const uint4*)&W[(size_t)(n0 + row) * H + k0 + lc];
      *(uint4*)&Bs[row * LDB + lc] = bv;
    }
    __syncthreads();
    #pragma unroll
    for (int h = 0; h < 2; h++) {
      half8 af[4], bf[2];
      #pragma unroll
      for (int i = 0; i < 4; i++)
        af[i] = *(const half8*)&As[(i * 16 + mrow) * LDB + h * 32 + q8];
      #pragma unroll
      for (int j = 0; j < 2; j++)
        bf[j] = *(const half8*)&Bs[(wn + j * 16 + mrow) * LDB + h * 32 + q8];
      #pragma unroll
      for (int i = 0; i < 4; i++)
        #pragma unroll
        for (int j = 0; j < 2; j++)
          acc[i][j] = __builtin_amdgcn_mfma_f32_16x16x32_f16(af[i], bf[j], acc[i][j], 0, 0, 0);
    }
  }

  // staged coalesced epilogue (reuse Bs)
  __syncthreads();
  u16* stage = Bs;
  #pragma unroll
  for (int j = 0; j < 2; j++) {
    float bv = bias[n0 + wn + j * 16 + ccol];
    #pragma unroll
    for (int i = 0; i < 4; i++) {
      #pragma unroll
      for (int r = 0; r < 4; r++) {
        int row = i * 16 + crow4 + r;
        stage[row * SSTR2 + wn + j * 16 + ccol] = f2h(acc[i][j][r] + bv);
      }
    }
  }
  __syncthreads();
  #pragma unroll
  for (int pass = 0; pass < 4; pass++) {
    int row = pass * 16 + (tid >> 4);
    int cu = (tid & 15) * 8;
    int grow = bm + row;
    if (grow < M) {
      *(uint4*)&outp[(size_t)grow * H + n0 + cu] =
          *(const uint4*)&stage[row * SSTR2 + cu];
    }
  }
}

// gate GEMM: gate[row] += sum_col relu(x@Wg1 + bg1)[col] * Wg2[col]; gate pre-init to bg2
__global__ __launch_bounds__(256) void gemm_gate_kernel(
    const u16* __restrict__ A, const u16* __restrict__ W,
    const float* __restrict__ bias, const float* __restrict__ Wg2,
    float* __restrict__ gate, int M)
{
  __shared__ u16 smem[2 * GTM * LDB];
  u16* As = smem;
  u16* Bs = smem + GTM * LDB;
  int tid = threadIdx.x;
  int lane = tid & 63;
  int wave = tid >> 6;
  int wm = (wave >> 1) * 64;
  int wn = (wave & 1) * 64;
  int bm = blockIdx.y * GTM;
  int bn = blockIdx.x * 128;
  int lr = tid >> 3;
  int lc = (tid & 7) * 8;

  floatx4 zero4 = {0.f, 0.f, 0.f, 0.f};
  floatx4 acc[4][4];
  #pragma unroll
  for (int i = 0; i < 4; i++)
    #pragma unroll
    for (int j = 0; j < 4; j++) acc[i][j] = zero4;

  int q8 = (lane >> 4) * 8;
  int mrow = lane & 15;

  for (int k0 = 0; k0 < H; k0 += GTK) {
    __syncthreads();
    #pragma unroll
    for (int p = 0; p < 4; p++) {
      int row = lr + p * 32;
      int gr = bm + row;
      uint4 av = {0, 0, 0, 0};
      if (gr < M) av = *(const uint4*)&A[(size_t)gr * H + k0 + lc];
      *(uint4*)&As[row * LDB + lc] = av;
      uint4 bv = *(const uint4*)&W[(size_t)(bn + row) * H + k0 + lc];
      *(uint4*)&Bs[row * LDB + lc] = bv;
    }
    __syncthreads();
    #pragma unroll
    for (int h = 0; h < 2; h++) {
      half8 af[4], bf[4];
      #pragma unroll
      for (int i = 0; i < 4; i++)
        af[i] = *(const half8*)&As[(wm + i * 16 + mrow) * LDB + h * 32 + q8];
      #pragma unroll
      for (int j = 0; j < 4; j++)
        bf[j] = *(const half8*)&Bs[(wn + j * 16 + mrow) * LDB + h * 32 + q8];
      #pragma unroll
      for (int i = 0; i < 4; i++)
        #pragma unroll
        for (int j = 0; j < 4; j++)
          acc[i][j] = __builtin_amdgcn_mfma_f32_16x16x32_f16(af[i], bf[j], acc[i][j], 0, 0, 0);
    }
  }

  int ccol = lane & 15;
  float bv[4], wv[4];
  #pragma unroll
  for (int j = 0; j < 4; j++) {
    int col = bn + wn + j * 16 + ccol;
    bv[j] = bias[col];
    wv[j] = Wg2[col];
  }
  #pragma unroll
  for (int i = 0; i < 4; i++) {
    #pragma unroll
    for (int r = 0; r < 4; r++) {
      float p = 0.f;
      #pragma unroll
      for (int j = 0; j < 4; j++) {
        float hcol = fmaxf(acc[i][j][r] + bv[j], 0.f);
        p += hcol * wv[j];
      }
      p += __shfl_xor(p, 1, 64);
      p += __shfl_xor(p, 2, 64);
      p += __shfl_xor(p, 4, 64);
      p += __shfl_xor(p, 8, 64);
      int row = bm + wm + i * 16 + (lane >> 4) * 4 + r;
      if ((lane & 15) == 0 && row < M) atomicAdd(&gate[row], p);
    }
  }
}

// ---------------- fused edge softmax + aggregate + LN + residual (R11 unroll-2) ----------------
__global__ __launch_bounds__(256) void layer_fused_kernel(
    const u16* __restrict__ xl, const u16* __restrict__ xr,
    u16* __restrict__ xst,
    const int* __restrict__ rowp, const int* __restrict__ col,
    const float* __restrict__ att, const float* __restrict__ bias_c,
    const float* __restrict__ ln_g, const float* __restrict__ ln_b)
{
  int lane = threadIdx.x & 63;
  int v = blockIdx.x * 4 + (threadIdx.x >> 6);
  if (v >= N_NODES) return;
  int f4 = lane << 2;
  size_t rowbase = (size_t)v * H;
  ushort4 xr4 = *(const ushort4*)&xr[rowbase + f4];
  float xrx = h2f(xr4.x), xry = h2f(xr4.y), xrz = h2f(xr4.z), xrw = h2f(xr4.w);
  float4 attv = *(const float4*)&att[f4];
  int beg = rowp[v], end = rowp[v + 1];
  float m = -INFINITY, d = 0.f;
  float ox = 0.f, oy = 0.f, oz = 0.f, ow = 0.f;
  int p = beg;
  for (; p + 2 <= end; p += 2) {
    int u0 = col[p];
    int u1 = col[p + 1];
    ushort4 a04 = *(const ushort4*)&xl[(size_t)u0 * H + f4];
    ushort4 a14 = *(const ushort4*)&xl[(size_t)u1 * H + f4];
    float a0x = h2f(a04.x), a0y = h2f(a04.y), a0z = h2f(a04.z), a0w = h2f(a04.w);
    float a1x = h2f(a14.x), a1y = h2f(a14.y), a1z = h2f(a14.z), a1w = h2f(a14.w);
    float t0x = a0x + xrx; t0x = t0x > 0.f ? t0x : NEG_SLOPE * t0x;
    float t0y = a0y + xry; t0y = t0y > 0.f ? t0y : NEG_SLOPE * t0y;
    float t0z = a0z + xrz; t0z = t0z > 0.f ? t0z : NEG_SLOPE * t0z;
    float t0w = a0w + xrw; t0w = t0w > 0.f ? t0w : NEG_SLOPE * t0w;
    float t1x = a1x + xrx; t1x = t1x > 0.f ? t1x : NEG_SLOPE * t1x;
    float t1y = a1y + xry; t1y = t1y > 0.f ? t1y : NEG_SLOPE * t1y;
    float t1z = a1z + xrz; t1z = t1z > 0.f ? t1z : NEG_SLOPE * t1z;
    float t1w = a1w + xrw; t1w = t1w > 0.f ? t1w : NEG_SLOPE * t1w;
    float pe0 = t0x * attv.x + t0y * attv.y + t0z * attv.z + t0w * attv.w;
    float pe1 = t1x * attv.x + t1y * attv.y + t1z * attv.z + t1w * attv.w;
    #pragma unroll
    for (int off = 32; off > 0; off >>= 1) {
      pe0 += __shfl_xor(pe0, off, 64);
      pe1 += __shfl_xor(pe1, off, 64);
    }
    float mn = fmaxf(m, fmaxf(pe0, pe1));
    float sc = __expf(m - mn);
    float w0 = __expf(pe0 - mn);
    float w1 = __expf(pe1 - mn);
    d = fmaf(d, sc, w0 + w1);
    ox = fmaf(ox, sc, fmaf(w0, a0x, w1 * a1x));
    oy = fmaf(oy, sc, fmaf(w0, a0y, w1 * a1y));
    oz = fmaf(oz, sc, fmaf(w0, a0z, w1 * a1z));
    ow = fmaf(ow, sc, fmaf(w0, a0w, w1 * a1w));
    m = mn;
  }
  if (p < end) {
    int u0 = col[p];
    ushort4 a04 = *(const ushort4*)&xl[(size_t)u0 * H + f4];
    float a0x = h2f(a04.x), a0y = h2f(a04.y), a0z = h2f(a04.z), a0w = h2f(a04.w);
    float t0x = a0x + xrx; t0x = t0x > 0.f ? t0x : NEG_SLOPE * t0x;
    float t0y = a0y + xry; t0y = t0y > 0.f ? t0y : NEG_SLOPE * t0y;
    float t0z = a0z + xrz; t0z = t0z > 0.f ? t0z : NEG_SLOPE * t0z;
    float t0w = a0w + xrw; t0w = t0w > 0.f ? t0w : NEG_SLOPE * t0w;
    float pe0 = t0x * attv.x + t0y * attv.y + t0z * attv.z + t0w * attv.w;
    pe0 = wave_reduce_sum(pe0);
    float mn = fmaxf(m, pe0);
    float sc = __expf(m - mn);
    float w0 = __expf(pe0 - mn);
    d = fmaf(d, sc, w0);
    ox = fmaf(ox, sc, w0 * a0x);
    oy = fmaf(oy, sc, w0 * a0y);
    oz = fmaf(oz, sc, w0 * a0z);
    ow = fmaf(ow, sc, w0 * a0w);
    m = mn;
  }
  float invd = 1.0f / d;
  float4 bc4 = *(const float4*)&bias_c[f4];
  ox = ox * invd + bc4.x;
  oy = oy * invd + bc4.y;
  oz = oz * invd + bc4.z;
  ow = ow * invd + bc4.w;
  float s = wave_reduce_sum(ox + oy + oz + ow);
  float mean = s * (1.0f / H);
  float cx = ox - mean, cy = oy - mean, cz = oz - mean, cw = ow - mean;
  float sq = wave_reduce_sum(cx * cx + cy * cy + cz * cz + cw * cw);
  float rstd = rsqrtf(sq * (1.0f / H) + LN_EPS);
  float4 g4 = *(const float4*)&ln_g[f4];
  float4 b4 = *(const float4*)&ln_b[f4];
  ushort4 xres4 = *(const ushort4*)&xst[rowbase + f4];
  float yx = fmaxf(fmaf(cx * rstd, g4.x, b4.x), 0.f) + h2f(xres4.x);
  float yy = fmaxf(fmaf(cy * rstd, g4.y, b4.y), 0.f) + h2f(xres4.y);
  float yz = fmaxf(fmaf(cz * rstd, g4.z, b4.z), 0.f) + h2f(xres4.z);
  float yw = fmaxf(fmaf(cw * rstd, g4.w, b4.w), 0.f) + h2f(xres4.w);
  ushort4 yb;
  yb.x = f2h(yx); yb.y = f2h(yy); yb.z = f2h(yz); yb.w = f2h(yw);
  *(ushort4*)&xst[rowbase + f4] = yb;
}

// ---------------- gate init + graph bounds (merged; batch sorted) ----------------
__global__ void gate_init_kernel(float* __restrict__ gate, const float* __restrict__ bg2,
                                 const int* __restrict__ batch,
                                 int* __restrict__ gstart, int* __restrict__ gend) {
  int i = blockIdx.x * 256 + threadIdx.x;
  if (i < N_NODES) {
    gate[i] = bg2[0];
    int b = batch[i];
    if (i == 0 || batch[i - 1] != b) gstart[b] = i;
    if (i == N_NODES - 1 || batch[i + 1] != b) gend[b] = i + 1;
  }
}

// ---------------- pooling: per-graph softmax stats (+ pooled zero) ----------------
__global__ __launch_bounds__(256) void pool_prep_kernel(
    const float* __restrict__ gate, const int* __restrict__ gstart,
    const int* __restrict__ gend, float* __restrict__ gmax, float* __restrict__ gdinv,
    float* __restrict__ pooled)
{
  __shared__ float red[256];
  int g = blockIdx.x, tid = threadIdx.x;
  pooled[(size_t)g * H + tid] = 0.f;
  int s = gstart[g], e = gend[g];
  float lm = -INFINITY;
  for (int i = s + tid; i < e; i += 256) lm = fmaxf(lm, gate[i]);
  red[tid] = lm;
  __syncthreads();
  for (int off = 128; off; off >>= 1) {
    if (tid < off) red[tid] = fmaxf(red[tid], red[tid + off]);
    __syncthreads();
  }
  float m = red[0];
  __syncthreads();
  float lsum = 0.0f;
  for (int i = s + tid; i < e; i += 256) lsum += __expf(gate[i] - m);
  red[tid] = lsum;
  __syncthreads();
  for (int off = 128; off; off >>= 1) {
    if (tid < off) red[tid] += red[tid + off];
    __syncthreads();
  }
  if (tid == 0) {
    gmax[g] = m;
    gdinv[g] = (s < e) ? 1.0f / red[0] : 0.0f;
  }
}

// ---------------- pooling: weighted accumulate (128 nodes per block, fp16 x) ----------------
__global__ __launch_bounds__(256) void pool_accum_kernel(
    const float* __restrict__ gate, const u16* __restrict__ xh,
    const int* __restrict__ batch, const float* __restrict__ gmax,
    const float* __restrict__ gdinv, float* __restrict__ pooled)
{
  __shared__ float wl[128];
  __shared__ int gl[128];
  int b0 = blockIdx.x * 128;
  int tid = threadIdx.x;
  if (tid < 128) {
    int v = b0 + tid;
    if (v < N_NODES) {
      int g = batch[v];
      gl[tid] = g;
      wl[tid] = __expf(gate[v] - gmax[g]) * gdinv[g];
    } else {
      gl[tid] = -1;
      wl[tid] = 0.f;
    }
  }
  __syncthreads();
  int cnt = min(128, N_NODES - b0);
  float acc = 0.f;
  int cur = gl[0];
  for (int j = 0; j < cnt; j++) {
    int g = gl[j];
    if (g != cur) {
      atomicAdd(&pooled[(size_t)cur * H + tid], acc);
      acc = 0.f;
      cur = g;
    }
    acc += wl[j] * h2f(xh[(size_t)(b0 + j) * H + tid]);
  }
  if (cur >= 0) atomicAdd(&pooled[(size_t)cur * H + tid], acc);
}

// ---------------- fused head: pooled -> z -> {cls, r1} -> residual ----------------
__global__ __launch_bounds__(256) void head_kernel(
    const float* __restrict__ pooled,
    const float* __restrict__ Ws, const float* __restrict__ bs,
    const float* __restrict__ Wc, const float* __restrict__ bc,
    const float* __restrict__ Wr1, const float* __restrict__ br1,
    const float* __restrict__ Wr2, const float* __restrict__ br2,
    float* __restrict__ out)
{
  __shared__ float psh[256];
  __shared__ float zsh[256];
  __shared__ float r1sh[128];
  int g = blockIdx.x, tid = threadIdx.x;
  psh[tid] = pooled[(size_t)g * H + tid];
  __syncthreads();
  {
    float acc = bs[tid];
    const float4* wr = (const float4*)&Ws[(size_t)tid * H];
    for (int k4 = 0; k4 < H / 4; k4++) {
      float4 wv = wr[k4];
      float4 av = *(const float4*)&psh[k4 * 4];
      acc += av.x * wv.x + av.y * wv.y + av.z * wv.z + av.w * wv.w;
    }
    zsh[tid] = fmaxf(acc, 0.f);
  }
  __syncthreads();
  if (tid < NB) {
    float acc = bc[tid];
    const float4* wr = (const float4*)&Wc[(size_t)tid * H];
    for (int k4 = 0; k4 < H / 4; k4++) {
      float4 wv = wr[k4];
      float4 av = *(const float4*)&zsh[k4 * 4];
      acc += av.x * wv.x + av.y * wv.y + av.z * wv.z + av.w * wv.w;
    }
    out[(size_t)g * NB + tid] = acc;
  }
  if (tid < 128) {
    float acc = br1[tid];
    const float4* wr = (const float4*)&Wr1[(size_t)tid * H];
    for (int k4 = 0; k4 < H / 4; k4++) {
      float4 wv = wr[k4];
      float4 av = *(const float4*)&zsh[k4 * 4];
      acc += av.x * wv.x + av.y * wv.y + av.z * wv.z + av.w * wv.w;
    }
    r1sh[tid] = fmaxf(acc, 0.f);
  }
  __syncthreads();
  if (tid < 64) {
    float s2 = r1sh[tid] * Wr2[tid] + r1sh[tid + 64] * Wr2[tid + 64];
    s2 = wave_reduce_sum(s2);
    if (tid == 0) out[(size_t)NGRAPH * NB + g] = tanhf(s2 + br2[0]);
  }
}

// ---------------- launcher ----------------
extern "C" void kernel_launch(void* const* d_in, const int* in_sizes, int n_in,
                              void* d_out, int out_size, void* d_ws, size_t ws_size,
                              hipStream_t stream) {
  const float* x_in   = (const float*)d_in[0];
  const int*   eidx   = (const int*)d_in[1];
  const int*   batch  = (const int*)d_in[2];
  const float* W_in   = (const float*)d_in[3];
  const float* b_in   = (const float*)d_in[4];
  const float* Wl     = (const float*)d_in[5];
  const float* bl     = (const float*)d_in[6];
  const float* Wr     = (const float*)d_in[7];
  const float* br     = (const float*)d_in[8];
  const float* att    = (const float*)d_in[9];
  const float* bias_c = (const float*)d_in[10];
  const float* ln_g   = (const float*)d_in[11];
  const float* ln_b   = (const float*)d_in[12];
  const float* Wg1    = (const float*)d_in[13];
  const float* bg1    = (const float*)d_in[14];
  const float* Wg2    = (const float*)d_in[15];
  const float* bg2    = (const float*)d_in[16];
  const float* Ws     = (const float*)d_in[17];
  const float* bs     = (const float*)d_in[18];
  const float* Wc     = (const float*)d_in[19];
  const float* bc     = (const float*)d_in[20];
  const float* Wr1    = (const float*)d_in[21];
  const float* br1    = (const float*)d_in[22];
  const float* Wr2    = (const float*)d_in[23];
  const float* br2    = (const float*)d_in[24];
  float* out = (float*)d_out;

  char* w = (char*)d_ws;
  u16* x_h    = (u16*)w;    w += sizeof(u16) * (size_t)N_NODES * H;
  u16* xl_h   = (u16*)w;    w += sizeof(u16) * (size_t)N_NODES * H;
  u16* xr_h   = (u16*)w;    w += sizeof(u16) * (size_t)N_NODES * H;
  u16* xin_h  = (u16*)w;    w += sizeof(u16) * (size_t)N_NODES * IN_DIM;
  u16* win_h  = (u16*)w;    w += sizeof(u16) * (size_t)H * IN_DIM;
  u16* wl_h   = (u16*)w;    w += sizeof(u16) * (size_t)LAYERS * H * H;
  u16* wr_h   = (u16*)w;    w += sizeof(u16) * (size_t)LAYERS * H * H;
  u16* wg1_h  = (u16*)w;    w += sizeof(u16) * (size_t)H * H;
  float* pooled = (float*)w; w += sizeof(float) * NGRAPH * H;
  float* gate = (float*)w;  w += sizeof(float) * N_NODES;
  float* gmax = (float*)w;  w += sizeof(float) * NGRAPH;
  float* gdinv= (float*)w;  w += sizeof(float) * NGRAPH;
  int* cnt    = (int*)w;    w += sizeof(int) * N_NODES;
  int* rowp   = (int*)w;    w += sizeof(int) * (N_NODES + 1);
  int* col    = (int*)w;    w += sizeof(int) * EE;
  int* partial= (int*)w;    w += sizeof(int) * N_NODES;
  int* bsums  = (int*)w;    w += sizeof(int) * 256;
  int* gstart = (int*)w;    w += sizeof(int) * NGRAPH;
  int* gend   = (int*)w;    w += sizeof(int) * NGRAPH;
  (void)ws_size; (void)n_in; (void)in_sizes; (void)out_size;

  const int* src = eidx;
  const int* dst = eidx + N_EDGES;
  int nblkN = (N_NODES + 255) / 256;
  int nblkE = (N_EDGES + 255) / 256;
  int mtiles = (N_NODES + GTM - 1) / GTM;
  int mtiles2 = (N_NODES + DTM - 1) / DTM;

  // CSR build (by dst, self-loops included)
  init_counts_kernel<<<nblkN, 256, 0, stream>>>(cnt);
  count_edges_kernel<<<nblkE, 256, 0, stream>>>(dst, cnt);
  scan_blocks_kernel<<<nblkN, 256, 0, stream>>>(cnt, partial, bsums, N_NODES);
  scan_sums_kernel<<<1, 256, 0, stream>>>(bsums, nblkN);
  scan_write_kernel<<<nblkN, 256, 0, stream>>>(partial, bsums, rowp, N_NODES);
  fill_self_kernel<<<nblkN, 256, 0, stream>>>(rowp, col, cnt);
  fill_edges_kernel<<<nblkE, 256, 0, stream>>>(src, dst, cnt, col);

  // casts
  {
    int maxn4 = LAYERS * H * H / 4;
    dim3 gcast((maxn4 + 255) / 256, 4);
    cast_weights_kernel<<<gcast, 256, 0, stream>>>(W_in, Wg1, Wl, Wr,
                                                   win_h, wg1_h, wl_h, wr_h);
    int n4 = N_NODES * IN_DIM / 4;
    cast_f16_kernel<<<(n4 + 255) / 256, 256, 0, stream>>>(x_in, xin_h, n4);
  }

  // input projection -> x_h
  dim3 gproj(2, mtiles);
  gemm_proj_kernel<<<gproj, 256, 0, stream>>>(xin_h, win_h, b_in, x_h, N_NODES, IN_DIM);

  int nblkV = N_NODES / 4;
  dim3 gdual(4, mtiles2);
  for (int l = 0; l < LAYERS; l++) {
    gemm_dual3_kernel<<<gdual, 256, 0, stream>>>(x_h,
        wl_h + (size_t)l * H * H, wr_h + (size_t)l * H * H,
        bl + l * H, br + l * H, xl_h, xr_h, N_NODES);
    layer_fused_kernel<<<nblkV, 256, 0, stream>>>(xl_h, xr_h, x_h, rowp, col,
        att + l * H, bias_c + l * H, ln_g + l * H, ln_b + l * H);
  }

  // gate (fused GEMM + row-dot); gate_init also computes graph bounds
  gate_init_kernel<<<nblkN, 256, 0, stream>>>(gate, bg2, batch, gstart, gend);
  dim3 ggate(2, mtiles);
  gemm_gate_kernel<<<ggate, 256, 0, stream>>>(x_h, wg1_h, bg1, Wg2, gate, N_NODES);

  // pooling
  pool_prep_kernel<<<NGRAPH, 256, 0, stream>>>(gate, gstart, gend, gmax, gdinv, pooled);
  pool_accum_kernel<<<(N_NODES + 127) / 128, 256, 0, stream>>>(gate, x_h, batch, gmax, gdinv, pooled);

  // fused heads
  head_kernel<<<NGRAPH, 256, 0, stream>>>(pooled, Ws, bs, Wc, bc, Wr1, br1, Wr2, br2, out);
}

// Round 15
// 587.699 us; speedup vs baseline: 1.3978x; 1.0215x over previous
//
#include <hip/hip_runtime.h>
#include <math.h>

#define N_NODES 50000
#define N_EDGES 300000
#define IN_DIM 64
#define H 256
#define LAYERS 4
#define NB 181
#define NGRAPH 64
#define EE (N_EDGES + N_NODES)
#define NEG_SLOPE 0.2f
#define LN_EPS 1e-5f

typedef unsigned short u16;
typedef __attribute__((ext_vector_type(8))) _Float16 half8;
typedef __attribute__((ext_vector_type(4))) float floatx4;

__device__ __forceinline__ u16 f2h(float f) {
  _Float16 h = (_Float16)f;
  return __builtin_bit_cast(u16, h);
}
__device__ __forceinline__ float h2f(u16 b) {
  return (float)__builtin_bit_cast(_Float16, b);
}

__device__ __forceinline__ float wave_reduce_sum(float v) {
  #pragma unroll
  for (int off = 32; off > 0; off >>= 1) v += __shfl_xor(v, off, 64);
  return v;
}

// ---------------- casts ----------------
__global__ void cast_f16_kernel(const float* __restrict__ in, u16* __restrict__ out, int n4) {
  int i = blockIdx.x * 256 + threadIdx.x;
  if (i < n4) {
    float4 f = ((const float4*)in)[i];
    ushort4 o;
    o.x = f2h(f.x); o.y = f2h(f.y); o.z = f2h(f.z); o.w = f2h(f.w);
    ((ushort4*)out)[i] = o;
  }
}

__global__ void cast_weights_kernel(
    const float* __restrict__ W_in, const float* __restrict__ Wg1,
    const float* __restrict__ Wl, const float* __restrict__ Wr,
    u16* __restrict__ win_h, u16* __restrict__ wg1_h,
    u16* __restrict__ wl_h, u16* __restrict__ wr_h)
{
  int i = blockIdx.x * 256 + threadIdx.x;
  int which = blockIdx.y;
  const float* s; u16* dd; int n4;
  if (which == 0)      { s = W_in; dd = win_h; n4 = H * IN_DIM / 4; }
  else if (which == 1) { s = Wg1;  dd = wg1_h; n4 = H * H / 4; }
  else if (which == 2) { s = Wl;   dd = wl_h;  n4 = LAYERS * H * H / 4; }
  else                 { s = Wr;   dd = wr_h;  n4 = LAYERS * H * H / 4; }
  if (i < n4) {
    float4 f = ((const float4*)s)[i];
    ushort4 o;
    o.x = f2h(f.x); o.y = f2h(f.y); o.z = f2h(f.z); o.w = f2h(f.w);
    ((ushort4*)dd)[i] = o;
  }
}

// ---------------- CSR build ----------------
__global__ void init_counts_kernel(int* __restrict__ cnt) {
  int i = blockIdx.x * 256 + threadIdx.x;
  if (i < N_NODES) cnt[i] = 1;  // self loop
}

__global__ void count_edges_kernel(const int* __restrict__ dst, int* __restrict__ cnt) {
  int e = blockIdx.x * 256 + threadIdx.x;
  if (e < N_EDGES) atomicAdd(&cnt[dst[e]], 1);
}

__global__ void scan_blocks_kernel(const int* __restrict__ cnt, int* __restrict__ partial,
                                   int* __restrict__ bsums, int n) {
  __shared__ int buf[256];
  int tid = threadIdx.x;
  int i = blockIdx.x * 256 + tid;
  buf[tid] = (i < n) ? cnt[i] : 0;
  __syncthreads();
  #pragma unroll
  for (int off = 1; off < 256; off <<= 1) {
    int t = (tid >= off) ? buf[tid - off] : 0;
    __syncthreads();
    buf[tid] += t;
    __syncthreads();
  }
  if (i < n) partial[i] = buf[tid];
  if (tid == 255) bsums[blockIdx.x] = buf[255];
}

__global__ void scan_sums_kernel(int* __restrict__ bsums, int nblk) {
  __shared__ int buf[256];
  int tid = threadIdx.x;
  buf[tid] = (tid < nblk) ? bsums[tid] : 0;
  __syncthreads();
  #pragma unroll
  for (int off = 1; off < 256; off <<= 1) {
    int t = (tid >= off) ? buf[tid - off] : 0;
    __syncthreads();
    buf[tid] += t;
    __syncthreads();
  }
  if (tid < nblk) bsums[tid] = buf[tid];
}

__global__ void scan_write_kernel(const int* __restrict__ partial, const int* __restrict__ bsums,
                                  int* __restrict__ rowp, int n) {
  int i = blockIdx.x * 256 + threadIdx.x;
  if (i < n) {
    int b = blockIdx.x;
    int off = (b > 0) ? bsums[b - 1] : 0;
    rowp[i + 1] = partial[i] + off;
    if (i == 0) rowp[0] = 0;
  }
}

__global__ void fill_self_kernel(const int* __restrict__ rowp, int* __restrict__ col,
                                 int* __restrict__ fillpos) {
  int i = blockIdx.x * 256 + threadIdx.x;
  if (i < N_NODES) {
    int p = rowp[i];
    col[p] = i;       // self loop FIRST in each row (layer_fused relies on this)
    fillpos[i] = p + 1;
  }
}

__global__ void fill_edges_kernel(const int* __restrict__ src, const int* __restrict__ dst,
                                  int* __restrict__ fillpos, int* __restrict__ col) {
  int e = blockIdx.x * 256 + threadIdx.x;
  if (e < N_EDGES) {
    int d = dst[e];
    int p = atomicAdd(&fillpos[d], 1);
    col[p] = src[e];
  }
}

// ---------------- MFMA GEMM tiles ----------------
#define GTM 128
#define GTK 64
#define LDB 72
#define SSTR 132

__global__ __launch_bounds__(256) void gemm_proj_kernel(
    const u16* __restrict__ A, const u16* __restrict__ W,
    const float* __restrict__ bias, u16* __restrict__ outh, int M, int K)
{
  __shared__ u16 smem[2 * GTM * LDB];
  u16* As = smem;
  u16* Bs = smem + GTM * LDB;
  int tid = threadIdx.x;
  int lane = tid & 63;
  int wave = tid >> 6;
  int wm = (wave >> 1) * 64;
  int wn = (wave & 1) * 64;
  int bm = blockIdx.y * GTM;
  int n0 = blockIdx.x * 128;
  int lr = tid >> 3;
  int lc = (tid & 7) * 8;

  floatx4 zero4 = {0.f, 0.f, 0.f, 0.f};
  floatx4 acc[4][4];
  #pragma unroll
  for (int i = 0; i < 4; i++)
    #pragma unroll
    for (int j = 0; j < 4; j++) acc[i][j] = zero4;

  int q8 = (lane >> 4) * 8;
  int mrow = lane & 15;

  for (int k0 = 0; k0 < K; k0 += GTK) {
    __syncthreads();
    #pragma unroll
    for (int p = 0; p < 4; p++) {
      int row = lr + p * 32;
      int gr = bm + row;
      uint4 av = {0, 0, 0, 0};
      if (gr < M) av = *(const uint4*)&A[(size_t)gr * K + k0 + lc];
      *(uint4*)&As[row * LDB + lc] = av;
      uint4 bv = *(const uint4*)&W[(size_t)(n0 + row) * K + k0 + lc];
      *(uint4*)&Bs[row * LDB + lc] = bv;
    }
    __syncthreads();
    #pragma unroll
    for (int h = 0; h < 2; h++) {
      half8 af[4], bf[4];
      #pragma unroll
      for (int i = 0; i < 4; i++)
        af[i] = *(const half8*)&As[(wm + i * 16 + mrow) * LDB + h * 32 + q8];
      #pragma unroll
      for (int j = 0; j < 4; j++)
        bf[j] = *(const half8*)&Bs[(wn + j * 16 + mrow) * LDB + h * 32 + q8];
      #pragma unroll
      for (int i = 0; i < 4; i++)
        #pragma unroll
        for (int j = 0; j < 4; j++)
          acc[i][j] = __builtin_amdgcn_mfma_f32_16x16x32_f16(af[i], bf[j], acc[i][j], 0, 0, 0);
    }
  }

  __syncthreads();
  u16* stage = smem;
  int ccol = lane & 15;
  int crow4 = (lane >> 4) * 4;
  #pragma unroll
  for (int j = 0; j < 4; j++) {
    float bv = bias[n0 + wn + j * 16 + ccol];
    #pragma unroll
    for (int i = 0; i < 4; i++) {
      #pragma unroll
      for (int r = 0; r < 4; r++) {
        int row = wm + i * 16 + crow4 + r;
        stage[row * SSTR + wn + j * 16 + ccol] = f2h(acc[i][j][r] + bv);
      }
    }
  }
  __syncthreads();
  int rr = tid >> 1;
  int c0 = (tid & 1) * 64;
  int grow = bm + rr;
  if (grow < M) {
    const ushort4* sp = (const ushort4*)&stage[rr * SSTR + c0];
    ushort4* gp = (ushort4*)&outh[(size_t)grow * H + n0 + c0];
    #pragma unroll
    for (int q = 0; q < 16; q++) gp[q] = sp[q];
  }
}

// ---------------- dual GEMM v5: one n-tile per block, 64-row m-tiles, 27.6 KB LDS ----------------
#define DTM 64
#define SSTR2 132

__global__ __launch_bounds__(256) void gemm_dual3_kernel(
    const u16* __restrict__ A, const u16* __restrict__ Wlb, const u16* __restrict__ Wrb,
    const float* __restrict__ biasL, const float* __restrict__ biasR,
    u16* __restrict__ outL, u16* __restrict__ outR, int M)
{
  __shared__ u16 As[DTM * LDB];
  __shared__ u16 Bs[128 * LDB];
  int tid = threadIdx.x;
  int lane = tid & 63;
  int wave = tid >> 6;
  int wn = wave * 32;
  int nt = blockIdx.x;
  int bm = blockIdx.y * DTM;
  const u16* W = (nt < 2) ? Wlb : Wrb;
  const float* bias = (nt < 2) ? biasL : biasR;
  u16* outp = (nt < 2) ? outL : outR;
  int n0 = (nt & 1) * 128;
  int mrow = lane & 15;
  int q8 = (lane >> 4) * 8;
  int ccol = lane & 15;
  int crow4 = (lane >> 4) * 4;
  int lr = tid >> 3;
  int lc = (tid & 7) * 8;

  floatx4 zero4 = {0.f, 0.f, 0.f, 0.f};
  floatx4 acc[4][2];
  #pragma unroll
  for (int i = 0; i < 4; i++) {
    acc[i][0] = zero4;
    acc[i][1] = zero4;
  }

  for (int k0 = 0; k0 < H; k0 += 64) {
    __syncthreads();
    #pragma unroll
    for (int p = 0; p < 2; p++) {
      int row = lr + p * 32;
      int gr = bm + row;
      uint4 av = {0, 0, 0, 0};
      if (gr < M) av = *(const uint4*)&A[(size_t)gr * H + k0 + lc];
      *(uint4*)&As[row * LDB + lc] = av;
    }
    #pragma unroll
    for (int p = 0; p < 4; p++) {
      int row = lr + p * 32;
      uint4 bv = *(const uint4*)&W[(size_t)(n0 + row) * H + k0 + lc];
      *(uint4*)&Bs[row * LDB + lc] = bv;
    }
    __syncthreads();
    #pragma unroll
    for (int h = 0; h < 2; h++) {
      half8 af[4], bf[2];
      #pragma unroll
      for (int i = 0; i < 4; i++)
        af[i] = *(const half8*)&As[(i * 16 + mrow) * LDB + h * 32 + q8];
      #pragma unroll
      for (int j = 0; j < 2; j++)
        bf[j] = *(const half8*)&Bs[(wn + j * 16 + mrow) * LDB + h * 32 + q8];
      #pragma unroll
      for (int i = 0; i < 4; i++)
        #pragma unroll
        for (int j = 0; j < 2; j++)
          acc[i][j] = __builtin_amdgcn_mfma_f32_16x16x32_f16(af[i], bf[j], acc[i][j], 0, 0, 0);
    }
  }

  __syncthreads();
  u16* stage = Bs;
  #pragma unroll
  for (int j = 0; j < 2; j++) {
    float bv = bias[n0 + wn + j * 16 + ccol];
    #pragma unroll
    for (int i = 0; i < 4; i++) {
      #pragma unroll
      for (int r = 0; r < 4; r++) {
        int row = i * 16 + crow4 + r;
        stage[row * SSTR2 + wn + j * 16 + ccol] = f2h(acc[i][j][r] + bv);
      }
    }
  }
  __syncthreads();
  #pragma unroll
  for (int pass = 0; pass < 4; pass++) {
    int row = pass * 16 + (tid >> 4);
    int cu = (tid & 15) * 8;
    int grow = bm + row;
    if (grow < M) {
      *(uint4*)&outp[(size_t)grow * H + n0 + cu] =
          *(const uint4*)&stage[row * SSTR2 + cu];
    }
  }
}

// gate GEMM: gate[row] += sum_col relu(x@Wg1 + bg1)[col] * Wg2[col]; gate pre-init to bg2
__global__ __launch_bounds__(256) void gemm_gate_kernel(
    const u16* __restrict__ A, const u16* __restrict__ W,
    const float* __restrict__ bias, const float* __restrict__ Wg2,
    float* __restrict__ gate, int M)
{
  __shared__ u16 smem[2 * GTM * LDB];
  u16* As = smem;
  u16* Bs = smem + GTM * LDB;
  int tid = threadIdx.x;
  int lane = tid & 63;
  int wave = tid >> 6;
  int wm = (wave >> 1) * 64;
  int wn = (wave & 1) * 64;
  int bm = blockIdx.y * GTM;
  int bn = blockIdx.x * 128;
  int lr = tid >> 3;
  int lc = (tid & 7) * 8;

  floatx4 zero4 = {0.f, 0.f, 0.f, 0.f};
  floatx4 acc[4][4];
  #pragma unroll
  for (int i = 0; i < 4; i++)
    #pragma unroll
    for (int j = 0; j < 4; j++) acc[i][j] = zero4;

  int q8 = (lane >> 4) * 8;
  int mrow = lane & 15;

  for (int k0 = 0; k0 < H; k0 += GTK) {
    __syncthreads();
    #pragma unroll
    for (int p = 0; p < 4; p++) {
      int row = lr + p * 32;
      int gr = bm + row;
      uint4 av = {0, 0, 0, 0};
      if (gr < M) av = *(const uint4*)&A[(size_t)gr * H + k0 + lc];
      *(uint4*)&As[row * LDB + lc] = av;
      uint4 bv = *(const uint4*)&W[(size_t)(bn + row) * H + k0 + lc];
      *(uint4*)&Bs[row * LDB + lc] = bv;
    }
    __syncthreads();
    #pragma unroll
    for (int h = 0; h < 2; h++) {
      half8 af[4], bf[4];
      #pragma unroll
      for (int i = 0; i < 4; i++)
        af[i] = *(const half8*)&As[(wm + i * 16 + mrow) * LDB + h * 32 + q8];
      #pragma unroll
      for (int j = 0; j < 4; j++)
        bf[j] = *(const half8*)&Bs[(wn + j * 16 + mrow) * LDB + h * 32 + q8];
      #pragma unroll
      for (int i = 0; i < 4; i++)
        #pragma unroll
        for (int j = 0; j < 4; j++)
          acc[i][j] = __builtin_amdgcn_mfma_f32_16x16x32_f16(af[i], bf[j], acc[i][j], 0, 0, 0);
    }
  }

  int ccol = lane & 15;
  float bv[4], wv[4];
  #pragma unroll
  for (int j = 0; j < 4; j++) {
    int col = bn + wn + j * 16 + ccol;
    bv[j] = bias[col];
    wv[j] = Wg2[col];
  }
  #pragma unroll
  for (int i = 0; i < 4; i++) {
    #pragma unroll
    for (int r = 0; r < 4; r++) {
      float p = 0.f;
      #pragma unroll
      for (int j = 0; j < 4; j++) {
        float hcol = fmaxf(acc[i][j][r] + bv[j], 0.f);
        p += hcol * wv[j];
      }
      p += __shfl_xor(p, 1, 64);
      p += __shfl_xor(p, 2, 64);
      p += __shfl_xor(p, 4, 64);
      p += __shfl_xor(p, 8, 64);
      int row = bm + wm + i * 16 + (lane >> 4) * 4 + r;
      if ((lane & 15) == 0 && row < M) atomicAdd(&gate[row], p);
    }
  }
}

// ---------------- fused edge softmax + aggregate + LN + residual ----------------
// Self-edge-anchored softmax: col[rowp[v]]==v, so pe_self provides a fixed
// stabilization offset -> the edge loop has NO running-max/rescale chain.
__global__ __launch_bounds__(256) void layer_fused_kernel(
    const u16* __restrict__ xl, const u16* __restrict__ xr,
    u16* __restrict__ xst,
    const int* __restrict__ rowp, const int* __restrict__ col,
    const float* __restrict__ att, const float* __restrict__ bias_c,
    const float* __restrict__ ln_g, const float* __restrict__ ln_b)
{
  int lane = threadIdx.x & 63;
  int v = blockIdx.x * 4 + (threadIdx.x >> 6);
  if (v >= N_NODES) return;
  int f4 = lane << 2;
  size_t rowbase = (size_t)v * H;
  ushort4 xr4 = *(const ushort4*)&xr[rowbase + f4];
  float xrx = h2f(xr4.x), xry = h2f(xr4.y), xrz = h2f(xr4.z), xrw = h2f(xr4.w);
  float4 attv = *(const float4*)&att[f4];
  int beg = rowp[v], end = rowp[v + 1];

  // self edge (always first): anchor offset
  float sx, sy, sz, sw, m;
  {
    ushort4 a04 = *(const ushort4*)&xl[rowbase + f4];
    sx = h2f(a04.x); sy = h2f(a04.y); sz = h2f(a04.z); sw = h2f(a04.w);
    float t0x = sx + xrx; t0x = t0x > 0.f ? t0x : NEG_SLOPE * t0x;
    float t0y = sy + xry; t0y = t0y > 0.f ? t0y : NEG_SLOPE * t0y;
    float t0z = sz + xrz; t0z = t0z > 0.f ? t0z : NEG_SLOPE * t0z;
    float t0w = sw + xrw; t0w = t0w > 0.f ? t0w : NEG_SLOPE * t0w;
    float pe = t0x * attv.x + t0y * attv.y + t0z * attv.z + t0w * attv.w;
    m = wave_reduce_sum(pe);
  }
  float d = 1.0f;
  float ox = sx, oy = sy, oz = sz, ow = sw;

  int p = beg + 1;
  for (; p + 2 <= end; p += 2) {
    int u0 = col[p];
    int u1 = col[p + 1];
    ushort4 a04 = *(const ushort4*)&xl[(size_t)u0 * H + f4];
    ushort4 a14 = *(const ushort4*)&xl[(size_t)u1 * H + f4];
    float a0x = h2f(a04.x), a0y = h2f(a04.y), a0z = h2f(a04.z), a0w = h2f(a04.w);
    float a1x = h2f(a14.x), a1y = h2f(a14.y), a1z = h2f(a14.z), a1w = h2f(a14.w);
    float t0x = a0x + xrx; t0x = t0x > 0.f ? t0x : NEG_SLOPE * t0x;
    float t0y = a0y + xry; t0y = t0y > 0.f ? t0y : NEG_SLOPE * t0y;
    float t0z = a0z + xrz; t0z = t0z > 0.f ? t0z : NEG_SLOPE * t0z;
    float t0w = a0w + xrw; t0w = t0w > 0.f ? t0w : NEG_SLOPE * t0w;
    float t1x = a1x + xrx; t1x = t1x > 0.f ? t1x : NEG_SLOPE * t1x;
    float t1y = a1y + xry; t1y = t1y > 0.f ? t1y : NEG_SLOPE * t1y;
    float t1z = a1z + xrz; t1z = t1z > 0.f ? t1z : NEG_SLOPE * t1z;
    float t1w = a1w + xrw; t1w = t1w > 0.f ? t1w : NEG_SLOPE * t1w;
    float pe0 = t0x * attv.x + t0y * attv.y + t0z * attv.z + t0w * attv.w;
    float pe1 = t1x * attv.x + t1y * attv.y + t1z * attv.z + t1w * attv.w;
    #pragma unroll
    for (int off = 32; off > 0; off >>= 1) {
      pe0 += __shfl_xor(pe0, off, 64);
      pe1 += __shfl_xor(pe1, off, 64);
    }
    float w0 = __expf(pe0 - m);
    float w1 = __expf(pe1 - m);
    d += w0 + w1;
    ox = fmaf(w0, a0x, fmaf(w1, a1x, ox));
    oy = fmaf(w0, a0y, fmaf(w1, a1y, oy));
    oz = fmaf(w0, a0z, fmaf(w1, a1z, oz));
    ow = fmaf(w0, a0w, fmaf(w1, a1w, ow));
  }
  if (p < end) {
    int u0 = col[p];
    ushort4 a04 = *(const ushort4*)&xl[(size_t)u0 * H + f4];
    float a0x = h2f(a04.x), a0y = h2f(a04.y), a0z = h2f(a04.z), a0w = h2f(a04.w);
    float t0x = a0x + xrx; t0x = t0x > 0.f ? t0x : NEG_SLOPE * t0x;
    float t0y = a0y + xry; t0y = t0y > 0.f ? t0y : NEG_SLOPE * t0y;
    float t0z = a0z + xrz; t0z = t0z > 0.f ? t0z : NEG_SLOPE * t0z;
    float t0w = a0w + xrw; t0w = t0w > 0.f ? t0w : NEG_SLOPE * t0w;
    float pe0 = t0x * attv.x + t0y * attv.y + t0z * attv.z + t0w * attv.w;
    pe0 = wave_reduce_sum(pe0);
    float w0 = __expf(pe0 - m);
    d += w0;
    ox = fmaf(w0, a0x, ox);
    oy = fmaf(w0, a0y, oy);
    oz = fmaf(w0, a0z, oz);
    ow = fmaf(w0, a0w, ow);
  }
  float invd = 1.0f / d;
  float4 bc4 = *(const float4*)&bias_c[f4];
  ox = ox * invd + bc4.x;
  oy = oy * invd + bc4.y;
  oz = oz * invd + bc4.z;
  ow = ow * invd + bc4.w;
  float s = wave_reduce_sum(ox + oy + oz + ow);
  float mean = s * (1.0f / H);
  float cx = ox - mean, cy = oy - mean, cz = oz - mean, cw = ow - mean;
  float sq = wave_reduce_sum(cx * cx + cy * cy + cz * cz + cw * cw);
  float rstd = rsqrtf(sq * (1.0f / H) + LN_EPS);
  float4 g4 = *(const float4*)&ln_g[f4];
  float4 b4 = *(const float4*)&ln_b[f4];
  ushort4 xres4 = *(const ushort4*)&xst[rowbase + f4];
  float yx = fmaxf(fmaf(cx * rstd, g4.x, b4.x), 0.f) + h2f(xres4.x);
  float yy = fmaxf(fmaf(cy * rstd, g4.y, b4.y), 0.f) + h2f(xres4.y);
  float yz = fmaxf(fmaf(cz * rstd, g4.z, b4.z), 0.f) + h2f(xres4.z);
  float yw = fmaxf(fmaf(cw * rstd, g4.w, b4.w), 0.f) + h2f(xres4.w);
  ushort4 yb;
  yb.x = f2h(yx); yb.y = f2h(yy); yb.z = f2h(yz); yb.w = f2h(yw);
  *(ushort4*)&xst[rowbase + f4] = yb;
}

// ---------------- gate init + graph bounds (merged; batch sorted) ----------------
__global__ void gate_init_kernel(float* __restrict__ gate, const float* __restrict__ bg2,
                                 const int* __restrict__ batch,
                                 int* __restrict__ gstart, int* __restrict__ gend) {
  int i = blockIdx.x * 256 + threadIdx.x;
  if (i < N_NODES) {
    gate[i] = bg2[0];
    int b = batch[i];
    if (i == 0 || batch[i - 1] != b) gstart[b] = i;
    if (i == N_NODES - 1 || batch[i + 1] != b) gend[b] = i + 1;
  }
}

// ---------------- pooling: per-graph softmax stats (+ pooled zero) ----------------
__global__ __launch_bounds__(256) void pool_prep_kernel(
    const float* __restrict__ gate, const int* __restrict__ gstart,
    const int* __restrict__ gend, float* __restrict__ gmax, float* __restrict__ gdinv,
    float* __restrict__ pooled)
{
  __shared__ float red[256];
  int g = blockIdx.x, tid = threadIdx.x;
  pooled[(size_t)g * H + tid] = 0.f;
  int s = gstart[g], e = gend[g];
  float lm = -INFINITY;
  for (int i = s + tid; i < e; i += 256) lm = fmaxf(lm, gate[i]);
  red[tid] = lm;
  __syncthreads();
  for (int off = 128; off; off >>= 1) {
    if (tid < off) red[tid] = fmaxf(red[tid], red[tid + off]);
    __syncthreads();
  }
  float m = red[0];
  __syncthreads();
  float lsum = 0.0f;
  for (int i = s + tid; i < e; i += 256) lsum += __expf(gate[i] - m);
  red[tid] = lsum;
  __syncthreads();
  for (int off = 128; off; off >>= 1) {
    if (tid < off) red[tid] += red[tid + off];
    __syncthreads();
  }
  if (tid == 0) {
    gmax[g] = m;
    gdinv[g] = (s < e) ? 1.0f / red[0] : 0.0f;
  }
}

// ---------------- pooling: weighted accumulate (128 nodes per block, fp16 x) ----------------
__global__ __launch_bounds__(256) void pool_accum_kernel(
    const float* __restrict__ gate, const u16* __restrict__ xh,
    const int* __restrict__ batch, const float* __restrict__ gmax,
    const float* __restrict__ gdinv, float* __restrict__ pooled)
{
  __shared__ float wl[128];
  __shared__ int gl[128];
  int b0 = blockIdx.x * 128;
  int tid = threadIdx.x;
  if (tid < 128) {
    int v = b0 + tid;
    if (v < N_NODES) {
      int g = batch[v];
      gl[tid] = g;
      wl[tid] = __expf(gate[v] - gmax[g]) * gdinv[g];
    } else {
      gl[tid] = -1;
      wl[tid] = 0.f;
    }
  }
  __syncthreads();
  int cnt = min(128, N_NODES - b0);
  float acc = 0.f;
  int cur = gl[0];
  for (int j = 0; j < cnt; j++) {
    int g = gl[j];
    if (g != cur) {
      atomicAdd(&pooled[(size_t)cur * H + tid], acc);
      acc = 0.f;
      cur = g;
    }
    acc += wl[j] * h2f(xh[(size_t)(b0 + j) * H + tid]);
  }
  if (cur >= 0) atomicAdd(&pooled[(size_t)cur * H + tid], acc);
}

// ---------------- fused head: pooled -> z -> {cls, r1} -> residual ----------------
__global__ __launch_bounds__(256) void head_kernel(
    const float* __restrict__ pooled,
    const float* __restrict__ Ws, const float* __restrict__ bs,
    const float* __restrict__ Wc, const float* __restrict__ bc,
    const float* __restrict__ Wr1, const float* __restrict__ br1,
    const float* __restrict__ Wr2, const float* __restrict__ br2,
    float* __restrict__ out)
{
  __shared__ float psh[256];
  __shared__ float zsh[256];
  __shared__ float r1sh[128];
  int g = blockIdx.x, tid = threadIdx.x;
  psh[tid] = pooled[(size_t)g * H + tid];
  __syncthreads();
  {
    float acc = bs[tid];
    const float4* wr = (const float4*)&Ws[(size_t)tid * H];
    for (int k4 = 0; k4 < H / 4; k4++) {
      float4 wv = wr[k4];
      float4 av = *(const float4*)&psh[k4 * 4];
      acc += av.x * wv.x + av.y * wv.y + av.z * wv.z + av.w * wv.w;
    }
    zsh[tid] = fmaxf(acc, 0.f);
  }
  __syncthreads();
  if (tid < NB) {
    float acc = bc[tid];
    const float4* wr = (const float4*)&Wc[(size_t)tid * H];
    for (int k4 = 0; k4 < H / 4; k4++) {
      float4 wv = wr[k4];
      float4 av = *(const float4*)&zsh[k4 * 4];
      acc += av.x * wv.x + av.y * wv.y + av.z * wv.z + av.w * wv.w;
    }
    out[(size_t)g * NB + tid] = acc;
  }
  if (tid < 128) {
    float acc = br1[tid];
    const float4* wr = (const float4*)&Wr1[(size_t)tid * H];
    for (int k4 = 0; k4 < H / 4; k4++) {
      float4 wv = wr[k4];
      float4 av = *(const float4*)&zsh[k4 * 4];
      acc += av.x * wv.x + av.y * wv.y + av.z * wv.z + av.w * wv.w;
    }
    r1sh[tid] = fmaxf(acc, 0.f);
  }
  __syncthreads();
  if (tid < 64) {
    float s2 = r1sh[tid] * Wr2[tid] + r1sh[tid + 64] * Wr2[tid + 64];
    s2 = wave_reduce_sum(s2);
    if (tid == 0) out[(size_t)NGRAPH * NB + g] = tanhf(s2 + br2[0]);
  }
}

// ---------------- launcher ----------------
extern "C" void kernel_launch(void* const* d_in, const int* in_sizes, int n_in,
                              void* d_out, int out_size, void* d_ws, size_t ws_size,
                              hipStream_t stream) {
  const float* x_in   = (const float*)d_in[0];
  const int*   eidx   = (const int*)d_in[1];
  const int*   batch  = (const int*)d_in[2];
  const float* W_in   = (const float*)d_in[3];
  const float* b_in   = (const float*)d_in[4];
  const float* Wl     = (const float*)d_in[5];
  const float* bl     = (const float*)d_in[6];
  const float* Wr     = (const float*)d_in[7];
  const float* br     = (const float*)d_in[8];
  const float* att    = (const float*)d_in[9];
  const float* bias_c = (const float*)d_in[10];
  const float* ln_g   = (const float*)d_in[11];
  const float* ln_b   = (const float*)d_in[12];
  const float* Wg1    = (const float*)d_in[13];
  const float* bg1    = (const float*)d_in[14];
  const float* Wg2    = (const float*)d_in[15];
  const float* bg2    = (const float*)d_in[16];
  const float* Ws     = (const float*)d_in[17];
  const float* bs     = (const float*)d_in[18];
  const float* Wc     = (const float*)d_in[19];
  const float* bc     = (const float*)d_in[20];
  const float* Wr1    = (const float*)d_in[21];
  const float* br1    = (const float*)d_in[22];
  const float* Wr2    = (const float*)d_in[23];
  const float* br2    = (const float*)d_in[24];
  float* out = (float*)d_out;

  char* w = (char*)d_ws;
  u16* x_h    = (u16*)w;    w += sizeof(u16) * (size_t)N_NODES * H;
  u16* xl_h   = (u16*)w;    w += sizeof(u16) * (size_t)N_NODES * H;
  u16* xr_h   = (u16*)w;    w += sizeof(u16) * (size_t)N_NODES * H;
  u16* xin_h  = (u16*)w;    w += sizeof(u16) * (size_t)N_NODES * IN_DIM;
  u16* win_h  = (u16*)w;    w += sizeof(u16) * (size_t)H * IN_DIM;
  u16* wl_h   = (u16*)w;    w += sizeof(u16) * (size_t)LAYERS * H * H;
  u16* wr_h   = (u16*)w;    w += sizeof(u16) * (size_t)LAYERS * H * H;
  u16* wg1_h  = (u16*)w;    w += sizeof(u16) * (size_t)H * H;
  float* pooled = (float*)w; w += sizeof(float) * NGRAPH * H;
  float* gate = (float*)w;  w += sizeof(float) * N_NODES;
  float* gmax = (float*)w;  w += sizeof(float) * NGRAPH;
  float* gdinv= (float*)w;  w += sizeof(float) * NGRAPH;
  int* cnt    = (int*)w;    w += sizeof(int) * N_NODES;
  int* rowp   = (int*)w;    w += sizeof(int) * (N_NODES + 1);
  int* col    = (int*)w;    w += sizeof(int) * EE;
  int* partial= (int*)w;    w += sizeof(int) * N_NODES;
  int* bsums  = (int*)w;    w += sizeof(int) * 256;
  int* gstart = (int*)w;    w += sizeof(int) * NGRAPH;
  int* gend   = (int*)w;    w += sizeof(int) * NGRAPH;
  (void)ws_size; (void)n_in; (void)in_sizes; (void)out_size;

  const int* src = eidx;
  const int* dst = eidx + N_EDGES;
  int nblkN = (N_NODES + 255) / 256;
  int nblkE = (N_EDGES + 255) / 256;
  int mtiles = (N_NODES + GTM - 1) / GTM;
  int mtiles2 = (N_NODES + DTM - 1) / DTM;

  // CSR build (by dst, self-loops first in each row)
  init_counts_kernel<<<nblkN, 256, 0, stream>>>(cnt);
  count_edges_kernel<<<nblkE, 256, 0, stream>>>(dst, cnt);
  scan_blocks_kernel<<<nblkN, 256, 0, stream>>>(cnt, partial, bsums, N_NODES);
  scan_sums_kernel<<<1, 256, 0, stream>>>(bsums, nblkN);
  scan_write_kernel<<<nblkN, 256, 0, stream>>>(partial, bsums, rowp, N_NODES);
  fill_self_kernel<<<nblkN, 256, 0, stream>>>(rowp, col, cnt);
  fill_edges_kernel<<<nblkE, 256, 0, stream>>>(src, dst, cnt, col);

  // casts
  {
    int maxn4 = LAYERS * H * H / 4;
    dim3 gcast((maxn4 + 255) / 256, 4);
    cast_weights_kernel<<<gcast, 256, 0, stream>>>(W_in, Wg1, Wl, Wr,
                                                   win_h, wg1_h, wl_h, wr_h);
    int n4 = N_NODES * IN_DIM / 4;
    cast_f16_kernel<<<(n4 + 255) / 256, 256, 0, stream>>>(x_in, xin_h, n4);
  }

  // input projection -> x_h
  dim3 gproj(2, mtiles);
  gemm_proj_kernel<<<gproj, 256, 0, stream>>>(xin_h, win_h, b_in, x_h, N_NODES, IN_DIM);

  int nblkV = N_NODES / 4;
  dim3 gdual(4, mtiles2);
  for (int l = 0; l < LAYERS; l++) {
    gemm_dual3_kernel<<<gdual, 256, 0, stream>>>(x_h,
        wl_h + (size_t)l * H * H, wr_h + (size_t)l * H * H,
        bl + l * H, br + l * H, xl_h, xr_h, N_NODES);
    layer_fused_kernel<<<nblkV, 256, 0, stream>>>(xl_h, xr_h, x_h, rowp, col,
        att + l * H, bias_c + l * H, ln_g + l * H, ln_b + l * H);
  }

  // gate (fused GEMM + row-dot); gate_init also computes graph bounds
  gate_init_kernel<<<nblkN, 256, 0, stream>>>(gate, bg2, batch, gstart, gend);
  dim3 ggate(2, mtiles);
  gemm_gate_kernel<<<ggate, 256, 0, stream>>>(x_h, wg1_h, bg1, Wg2, gate, N_NODES);

  // pooling
  pool_prep_kernel<<<NGRAPH, 256, 0, stream>>>(gate, gstart, gend, gmax, gdinv, pooled);
  pool_accum_kernel<<<(N_NODES + 127) / 128, 256, 0, stream>>>(gate, x_h, batch, gmax, gdinv, pooled);

  // fused heads
  head_kernel<<<NGRAPH, 256, 0, stream>>>(pooled, Ws, bs, Wc, bc, Wr1, br1, Wr2, br2, out);
}

// Round 16
// 584.311 us; speedup vs baseline: 1.4059x; 1.0058x over previous
//
#include <hip/hip_runtime.h>
#include <math.h>

#define N_NODES 50000
#define N_EDGES 300000
#define IN_DIM 64
#define H 256
#define LAYERS 4
#define NB 181
#define NGRAPH 64
#define EE (N_EDGES + N_NODES)
#define NEG_SLOPE 0.2f
#define LN_EPS 1e-5f

typedef unsigned short u16;
typedef __attribute__((ext_vector_type(8))) _Float16 half8;
typedef __attribute__((ext_vector_type(4))) float floatx4;

__device__ __forceinline__ u16 f2h(float f) {
  _Float16 h = (_Float16)f;
  return __builtin_bit_cast(u16, h);
}
__device__ __forceinline__ float h2f(u16 b) {
  return (float)__builtin_bit_cast(_Float16, b);
}

__device__ __forceinline__ float wave_reduce_sum(float v) {
  #pragma unroll
  for (int off = 32; off > 0; off >>= 1) v += __shfl_xor(v, off, 64);
  return v;
}

// ---------------- casts ----------------
__global__ void cast_f16_kernel(const float* __restrict__ in, u16* __restrict__ out, int n4) {
  int i = blockIdx.x * 256 + threadIdx.x;
  if (i < n4) {
    float4 f = ((const float4*)in)[i];
    ushort4 o;
    o.x = f2h(f.x); o.y = f2h(f.y); o.z = f2h(f.z); o.w = f2h(f.w);
    ((ushort4*)out)[i] = o;
  }
}

__global__ void cast_weights_kernel(
    const float* __restrict__ W_in, const float* __restrict__ Wg1,
    const float* __restrict__ Wl, const float* __restrict__ Wr,
    u16* __restrict__ win_h, u16* __restrict__ wg1_h,
    u16* __restrict__ wl_h, u16* __restrict__ wr_h)
{
  int i = blockIdx.x * 256 + threadIdx.x;
  int which = blockIdx.y;
  const float* s; u16* dd; int n4;
  if (which == 0)      { s = W_in; dd = win_h; n4 = H * IN_DIM / 4; }
  else if (which == 1) { s = Wg1;  dd = wg1_h; n4 = H * H / 4; }
  else if (which == 2) { s = Wl;   dd = wl_h;  n4 = LAYERS * H * H / 4; }
  else                 { s = Wr;   dd = wr_h;  n4 = LAYERS * H * H / 4; }
  if (i < n4) {
    float4 f = ((const float4*)s)[i];
    ushort4 o;
    o.x = f2h(f.x); o.y = f2h(f.y); o.z = f2h(f.z); o.w = f2h(f.w);
    ((ushort4*)dd)[i] = o;
  }
}

// ---------------- CSR build ----------------
__global__ void init_counts_kernel(int* __restrict__ cnt) {
  int i = blockIdx.x * 256 + threadIdx.x;
  if (i < N_NODES) cnt[i] = 1;  // self loop
}

__global__ void count_edges_kernel(const int* __restrict__ dst, int* __restrict__ cnt) {
  int e = blockIdx.x * 256 + threadIdx.x;
  if (e < N_EDGES) atomicAdd(&cnt[dst[e]], 1);
}

__global__ void scan_blocks_kernel(const int* __restrict__ cnt, int* __restrict__ partial,
                                   int* __restrict__ bsums, int n) {
  __shared__ int buf[256];
  int tid = threadIdx.x;
  int i = blockIdx.x * 256 + tid;
  buf[tid] = (i < n) ? cnt[i] : 0;
  __syncthreads();
  #pragma unroll
  for (int off = 1; off < 256; off <<= 1) {
    int t = (tid >= off) ? buf[tid - off] : 0;
    __syncthreads();
    buf[tid] += t;
    __syncthreads();
  }
  if (i < n) partial[i] = buf[tid];
  if (tid == 255) bsums[blockIdx.x] = buf[255];
}

__global__ void scan_sums_kernel(int* __restrict__ bsums, int nblk) {
  __shared__ int buf[256];
  int tid = threadIdx.x;
  buf[tid] = (tid < nblk) ? bsums[tid] : 0;
  __syncthreads();
  #pragma unroll
  for (int off = 1; off < 256; off <<= 1) {
    int t = (tid >= off) ? buf[tid - off] : 0;
    __syncthreads();
    buf[tid] += t;
    __syncthreads();
  }
  if (tid < nblk) bsums[tid] = buf[tid];
}

__global__ void scan_write_kernel(const int* __restrict__ partial, const int* __restrict__ bsums,
                                  int* __restrict__ rowp, int n) {
  int i = blockIdx.x * 256 + threadIdx.x;
  if (i < n) {
    int b = blockIdx.x;
    int off = (b > 0) ? bsums[b - 1] : 0;
    rowp[i + 1] = partial[i] + off;
    if (i == 0) rowp[0] = 0;
  }
}

__global__ void fill_self_kernel(const int* __restrict__ rowp, int* __restrict__ col,
                                 int* __restrict__ fillpos) {
  int i = blockIdx.x * 256 + threadIdx.x;
  if (i < N_NODES) {
    int p = rowp[i];
    col[p] = i;       // self loop FIRST in each row (layer_fused relies on this)
    fillpos[i] = p + 1;
  }
}

__global__ void fill_edges_kernel(const int* __restrict__ src, const int* __restrict__ dst,
                                  int* __restrict__ fillpos, int* __restrict__ col) {
  int e = blockIdx.x * 256 + threadIdx.x;
  if (e < N_EDGES) {
    int d = dst[e];
    int p = atomicAdd(&fillpos[d], 1);
    col[p] = src[e];
  }
}

// ---------------- MFMA GEMM tiles ----------------
#define GTM 128
#define GTK 64
#define LDB 72
#define SSTR 132

__global__ __launch_bounds__(256) void gemm_proj_kernel(
    const u16* __restrict__ A, const u16* __restrict__ W,
    const float* __restrict__ bias, u16* __restrict__ outh, int M, int K)
{
  __shared__ u16 smem[2 * GTM * LDB];
  u16* As = smem;
  u16* Bs = smem + GTM * LDB;
  int tid = threadIdx.x;
  int lane = tid & 63;
  int wave = tid >> 6;
  int wm = (wave >> 1) * 64;
  int wn = (wave & 1) * 64;
  int bm = blockIdx.y * GTM;
  int n0 = blockIdx.x * 128;
  int lr = tid >> 3;
  int lc = (tid & 7) * 8;

  floatx4 zero4 = {0.f, 0.f, 0.f, 0.f};
  floatx4 acc[4][4];
  #pragma unroll
  for (int i = 0; i < 4; i++)
    #pragma unroll
    for (int j = 0; j < 4; j++) acc[i][j] = zero4;

  int q8 = (lane >> 4) * 8;
  int mrow = lane & 15;

  for (int k0 = 0; k0 < K; k0 += GTK) {
    __syncthreads();
    #pragma unroll
    for (int p = 0; p < 4; p++) {
      int row = lr + p * 32;
      int gr = bm + row;
      uint4 av = {0, 0, 0, 0};
      if (gr < M) av = *(const uint4*)&A[(size_t)gr * K + k0 + lc];
      *(uint4*)&As[row * LDB + lc] = av;
      uint4 bv = *(const uint4*)&W[(size_t)(n0 + row) * K + k0 + lc];
      *(uint4*)&Bs[row * LDB + lc] = bv;
    }
    __syncthreads();
    #pragma unroll
    for (int h = 0; h < 2; h++) {
      half8 af[4], bf[4];
      #pragma unroll
      for (int i = 0; i < 4; i++)
        af[i] = *(const half8*)&As[(wm + i * 16 + mrow) * LDB + h * 32 + q8];
      #pragma unroll
      for (int j = 0; j < 4; j++)
        bf[j] = *(const half8*)&Bs[(wn + j * 16 + mrow) * LDB + h * 32 + q8];
      #pragma unroll
      for (int i = 0; i < 4; i++)
        #pragma unroll
        for (int j = 0; j < 4; j++)
          acc[i][j] = __builtin_amdgcn_mfma_f32_16x16x32_f16(af[i], bf[j], acc[i][j], 0, 0, 0);
    }
  }

  __syncthreads();
  u16* stage = smem;
  int ccol = lane & 15;
  int crow4 = (lane >> 4) * 4;
  #pragma unroll
  for (int j = 0; j < 4; j++) {
    float bv = bias[n0 + wn + j * 16 + ccol];
    #pragma unroll
    for (int i = 0; i < 4; i++) {
      #pragma unroll
      for (int r = 0; r < 4; r++) {
        int row = wm + i * 16 + crow4 + r;
        stage[row * SSTR + wn + j * 16 + ccol] = f2h(acc[i][j][r] + bv);
      }
    }
  }
  __syncthreads();
  int rr = tid >> 1;
  int c0 = (tid & 1) * 64;
  int grow = bm + rr;
  if (grow < M) {
    const ushort4* sp = (const ushort4*)&stage[rr * SSTR + c0];
    ushort4* gp = (ushort4*)&outh[(size_t)grow * H + n0 + c0];
    #pragma unroll
    for (int q = 0; q < 16; q++) gp[q] = sp[q];
  }
}

// ---------------- dual GEMM v5: one n-tile per block, 64-row m-tiles, 27.6 KB LDS ----------------
#define DTM 64
#define SSTR2 132

__global__ __launch_bounds__(256) void gemm_dual3_kernel(
    const u16* __restrict__ A, const u16* __restrict__ Wlb, const u16* __restrict__ Wrb,
    const float* __restrict__ biasL, const float* __restrict__ biasR,
    u16* __restrict__ outL, u16* __restrict__ outR, int M)
{
  __shared__ u16 As[DTM * LDB];
  __shared__ u16 Bs[128 * LDB];
  int tid = threadIdx.x;
  int lane = tid & 63;
  int wave = tid >> 6;
  int wn = wave * 32;
  int nt = blockIdx.x;
  int bm = blockIdx.y * DTM;
  const u16* W = (nt < 2) ? Wlb : Wrb;
  const float* bias = (nt < 2) ? biasL : biasR;
  u16* outp = (nt < 2) ? outL : outR;
  int n0 = (nt & 1) * 128;
  int mrow = lane & 15;
  int q8 = (lane >> 4) * 8;
  int ccol = lane & 15;
  int crow4 = (lane >> 4) * 4;
  int lr = tid >> 3;
  int lc = (tid & 7) * 8;

  floatx4 zero4 = {0.f, 0.f, 0.f, 0.f};
  floatx4 acc[4][2];
  #pragma unroll
  for (int i = 0; i < 4; i++) {
    acc[i][0] = zero4;
    acc[i][1] = zero4;
  }

  for (int k0 = 0; k0 < H; k0 += 64) {
    __syncthreads();
    #pragma unroll
    for (int p = 0; p < 2; p++) {
      int row = lr + p * 32;
      int gr = bm + row;
      uint4 av = {0, 0, 0, 0};
      if (gr < M) av = *(const uint4*)&A[(size_t)gr * H + k0 + lc];
      *(uint4*)&As[row * LDB + lc] = av;
    }
    #pragma unroll
    for (int p = 0; p < 4; p++) {
      int row = lr + p * 32;
      uint4 bv = *(const uint4*)&W[(size_t)(n0 + row) * H + k0 + lc];
      *(uint4*)&Bs[row * LDB + lc] = bv;
    }
    __syncthreads();
    #pragma unroll
    for (int h = 0; h < 2; h++) {
      half8 af[4], bf[2];
      #pragma unroll
      for (int i = 0; i < 4; i++)
        af[i] = *(const half8*)&As[(i * 16 + mrow) * LDB + h * 32 + q8];
      #pragma unroll
      for (int j = 0; j < 2; j++)
        bf[j] = *(const half8*)&Bs[(wn + j * 16 + mrow) * LDB + h * 32 + q8];
      #pragma unroll
      for (int i = 0; i < 4; i++)
        #pragma unroll
        for (int j = 0; j < 2; j++)
          acc[i][j] = __builtin_amdgcn_mfma_f32_16x16x32_f16(af[i], bf[j], acc[i][j], 0, 0, 0);
    }
  }

  __syncthreads();
  u16* stage = Bs;
  #pragma unroll
  for (int j = 0; j < 2; j++) {
    float bv = bias[n0 + wn + j * 16 + ccol];
    #pragma unroll
    for (int i = 0; i < 4; i++) {
      #pragma unroll
      for (int r = 0; r < 4; r++) {
        int row = i * 16 + crow4 + r;
        stage[row * SSTR2 + wn + j * 16 + ccol] = f2h(acc[i][j][r] + bv);
      }
    }
  }
  __syncthreads();
  #pragma unroll
  for (int pass = 0; pass < 4; pass++) {
    int row = pass * 16 + (tid >> 4);
    int cu = (tid & 15) * 8;
    int grow = bm + row;
    if (grow < M) {
      *(uint4*)&outp[(size_t)grow * H + n0 + cu] =
          *(const uint4*)&stage[row * SSTR2 + cu];
    }
  }
}

// gate GEMM: gate[row] += sum_col relu(x@Wg1 + bg1)[col] * Wg2[col]; gate pre-init to bg2
__global__ __launch_bounds__(256) void gemm_gate_kernel(
    const u16* __restrict__ A, const u16* __restrict__ W,
    const float* __restrict__ bias, const float* __restrict__ Wg2,
    float* __restrict__ gate, int M)
{
  __shared__ u16 smem[2 * GTM * LDB];
  u16* As = smem;
  u16* Bs = smem + GTM * LDB;
  int tid = threadIdx.x;
  int lane = tid & 63;
  int wave = tid >> 6;
  int wm = (wave >> 1) * 64;
  int wn = (wave & 1) * 64;
  int bm = blockIdx.y * GTM;
  int bn = blockIdx.x * 128;
  int lr = tid >> 3;
  int lc = (tid & 7) * 8;

  floatx4 zero4 = {0.f, 0.f, 0.f, 0.f};
  floatx4 acc[4][4];
  #pragma unroll
  for (int i = 0; i < 4; i++)
    #pragma unroll
    for (int j = 0; j < 4; j++) acc[i][j] = zero4;

  int q8 = (lane >> 4) * 8;
  int mrow = lane & 15;

  for (int k0 = 0; k0 < H; k0 += GTK) {
    __syncthreads();
    #pragma unroll
    for (int p = 0; p < 4; p++) {
      int row = lr + p * 32;
      int gr = bm + row;
      uint4 av = {0, 0, 0, 0};
      if (gr < M) av = *(const uint4*)&A[(size_t)gr * H + k0 + lc];
      *(uint4*)&As[row * LDB + lc] = av;
      uint4 bv = *(const uint4*)&W[(size_t)(bn + row) * H + k0 + lc];
      *(uint4*)&Bs[row * LDB + lc] = bv;
    }
    __syncthreads();
    #pragma unroll
    for (int h = 0; h < 2; h++) {
      half8 af[4], bf[4];
      #pragma unroll
      for (int i = 0; i < 4; i++)
        af[i] = *(const half8*)&As[(wm + i * 16 + mrow) * LDB + h * 32 + q8];
      #pragma unroll
      for (int j = 0; j < 4; j++)
        bf[j] = *(const half8*)&Bs[(wn + j * 16 + mrow) * LDB + h * 32 + q8];
      #pragma unroll
      for (int i = 0; i < 4; i++)
        #pragma unroll
        for (int j = 0; j < 4; j++)
          acc[i][j] = __builtin_amdgcn_mfma_f32_16x16x32_f16(af[i], bf[j], acc[i][j], 0, 0, 0);
    }
  }

  int ccol = lane & 15;
  float bv[4], wv[4];
  #pragma unroll
  for (int j = 0; j < 4; j++) {
    int col = bn + wn + j * 16 + ccol;
    bv[j] = bias[col];
    wv[j] = Wg2[col];
  }
  #pragma unroll
  for (int i = 0; i < 4; i++) {
    #pragma unroll
    for (int r = 0; r < 4; r++) {
      float p = 0.f;
      #pragma unroll
      for (int j = 0; j < 4; j++) {
        float hcol = fmaxf(acc[i][j][r] + bv[j], 0.f);
        p += hcol * wv[j];
      }
      p += __shfl_xor(p, 1, 64);
      p += __shfl_xor(p, 2, 64);
      p += __shfl_xor(p, 4, 64);
      p += __shfl_xor(p, 8, 64);
      int row = bm + wm + i * 16 + (lane >> 4) * 4 + r;
      if ((lane & 15) == 0 && row < M) atomicAdd(&gate[row], p);
    }
  }
}

// ---------------- fused edge softmax + aggregate + LN + residual ----------------
// Self-edge-anchored softmax + mask-free unroll-4 main loop (commutative body).
__global__ __launch_bounds__(256) void layer_fused_kernel(
    const u16* __restrict__ xl, const u16* __restrict__ xr,
    u16* __restrict__ xst,
    const int* __restrict__ rowp, const int* __restrict__ col,
    const float* __restrict__ att, const float* __restrict__ bias_c,
    const float* __restrict__ ln_g, const float* __restrict__ ln_b)
{
  int lane = threadIdx.x & 63;
  int v = blockIdx.x * 4 + (threadIdx.x >> 6);
  if (v >= N_NODES) return;
  int f4 = lane << 2;
  size_t rowbase = (size_t)v * H;
  ushort4 xr4 = *(const ushort4*)&xr[rowbase + f4];
  float xrx = h2f(xr4.x), xry = h2f(xr4.y), xrz = h2f(xr4.z), xrw = h2f(xr4.w);
  float4 attv = *(const float4*)&att[f4];
  int beg = rowp[v], end = rowp[v + 1];

  // self edge (always first): anchor offset
  float sx, sy, sz, sw, m;
  {
    ushort4 a04 = *(const ushort4*)&xl[rowbase + f4];
    sx = h2f(a04.x); sy = h2f(a04.y); sz = h2f(a04.z); sw = h2f(a04.w);
    float t0x = sx + xrx; t0x = t0x > 0.f ? t0x : NEG_SLOPE * t0x;
    float t0y = sy + xry; t0y = t0y > 0.f ? t0y : NEG_SLOPE * t0y;
    float t0z = sz + xrz; t0z = t0z > 0.f ? t0z : NEG_SLOPE * t0z;
    float t0w = sw + xrw; t0w = t0w > 0.f ? t0w : NEG_SLOPE * t0w;
    float pe = t0x * attv.x + t0y * attv.y + t0z * attv.z + t0w * attv.w;
    m = wave_reduce_sum(pe);
  }
  float d = 1.0f;
  float ox = sx, oy = sy, oz = sz, ow = sw;

  int p = beg + 1;
  for (; p + 4 <= end; p += 4) {
    int u0 = col[p];
    int u1 = col[p + 1];
    int u2 = col[p + 2];
    int u3 = col[p + 3];
    ushort4 A0 = *(const ushort4*)&xl[(size_t)u0 * H + f4];
    ushort4 A1 = *(const ushort4*)&xl[(size_t)u1 * H + f4];
    ushort4 A2 = *(const ushort4*)&xl[(size_t)u2 * H + f4];
    ushort4 A3 = *(const ushort4*)&xl[(size_t)u3 * H + f4];
    float a0x = h2f(A0.x), a0y = h2f(A0.y), a0z = h2f(A0.z), a0w = h2f(A0.w);
    float a1x = h2f(A1.x), a1y = h2f(A1.y), a1z = h2f(A1.z), a1w = h2f(A1.w);
    float a2x = h2f(A2.x), a2y = h2f(A2.y), a2z = h2f(A2.z), a2w = h2f(A2.w);
    float a3x = h2f(A3.x), a3y = h2f(A3.y), a3z = h2f(A3.z), a3w = h2f(A3.w);
    float t, pe0, pe1, pe2, pe3;
    t = a0x + xrx; t = t > 0.f ? t : NEG_SLOPE * t; pe0 = t * attv.x;
    t = a0y + xry; t = t > 0.f ? t : NEG_SLOPE * t; pe0 = fmaf(t, attv.y, pe0);
    t = a0z + xrz; t = t > 0.f ? t : NEG_SLOPE * t; pe0 = fmaf(t, attv.z, pe0);
    t = a0w + xrw; t = t > 0.f ? t : NEG_SLOPE * t; pe0 = fmaf(t, attv.w, pe0);
    t = a1x + xrx; t = t > 0.f ? t : NEG_SLOPE * t; pe1 = t * attv.x;
    t = a1y + xry; t = t > 0.f ? t : NEG_SLOPE * t; pe1 = fmaf(t, attv.y, pe1);
    t = a1z + xrz; t = t > 0.f ? t : NEG_SLOPE * t; pe1 = fmaf(t, attv.z, pe1);
    t = a1w + xrw; t = t > 0.f ? t : NEG_SLOPE * t; pe1 = fmaf(t, attv.w, pe1);
    t = a2x + xrx; t = t > 0.f ? t : NEG_SLOPE * t; pe2 = t * attv.x;
    t = a2y + xry; t = t > 0.f ? t : NEG_SLOPE * t; pe2 = fmaf(t, attv.y, pe2);
    t = a2z + xrz; t = t > 0.f ? t : NEG_SLOPE * t; pe2 = fmaf(t, attv.z, pe2);
    t = a2w + xrw; t = t > 0.f ? t : NEG_SLOPE * t; pe2 = fmaf(t, attv.w, pe2);
    t = a3x + xrx; t = t > 0.f ? t : NEG_SLOPE * t; pe3 = t * attv.x;
    t = a3y + xry; t = t > 0.f ? t : NEG_SLOPE * t; pe3 = fmaf(t, attv.y, pe3);
    t = a3z + xrz; t = t > 0.f ? t : NEG_SLOPE * t; pe3 = fmaf(t, attv.z, pe3);
    t = a3w + xrw; t = t > 0.f ? t : NEG_SLOPE * t; pe3 = fmaf(t, attv.w, pe3);
    #pragma unroll
    for (int off = 32; off > 0; off >>= 1) {
      pe0 += __shfl_xor(pe0, off, 64);
      pe1 += __shfl_xor(pe1, off, 64);
      pe2 += __shfl_xor(pe2, off, 64);
      pe3 += __shfl_xor(pe3, off, 64);
    }
    float w0 = __expf(pe0 - m);
    float w1 = __expf(pe1 - m);
    float w2 = __expf(pe2 - m);
    float w3 = __expf(pe3 - m);
    d += (w0 + w1) + (w2 + w3);
    ox = fmaf(w0, a0x, fmaf(w1, a1x, fmaf(w2, a2x, fmaf(w3, a3x, ox))));
    oy = fmaf(w0, a0y, fmaf(w1, a1y, fmaf(w2, a2y, fmaf(w3, a3y, oy))));
    oz = fmaf(w0, a0z, fmaf(w1, a1z, fmaf(w2, a2z, fmaf(w3, a3z, oz))));
    ow = fmaf(w0, a0w, fmaf(w1, a1w, fmaf(w2, a2w, fmaf(w3, a3w, ow))));
  }
  for (; p < end; p++) {
    int u0 = col[p];
    ushort4 a04 = *(const ushort4*)&xl[(size_t)u0 * H + f4];
    float a0x = h2f(a04.x), a0y = h2f(a04.y), a0z = h2f(a04.z), a0w = h2f(a04.w);
    float t0x = a0x + xrx; t0x = t0x > 0.f ? t0x : NEG_SLOPE * t0x;
    float t0y = a0y + xry; t0y = t0y > 0.f ? t0y : NEG_SLOPE * t0y;
    float t0z = a0z + xrz; t0z = t0z > 0.f ? t0z : NEG_SLOPE * t0z;
    float t0w = a0w + xrw; t0w = t0w > 0.f ? t0w : NEG_SLOPE * t0w;
    float pe0 = t0x * attv.x + t0y * attv.y + t0z * attv.z + t0w * attv.w;
    pe0 = wave_reduce_sum(pe0);
    float w0 = __expf(pe0 - m);
    d += w0;
    ox = fmaf(w0, a0x, ox);
    oy = fmaf(w0, a0y, oy);
    oz = fmaf(w0, a0z, oz);
    ow = fmaf(w0, a0w, ow);
  }
  float invd = 1.0f / d;
  float4 bc4 = *(const float4*)&bias_c[f4];
  ox = ox * invd + bc4.x;
  oy = oy * invd + bc4.y;
  oz = oz * invd + bc4.z;
  ow = ow * invd + bc4.w;
  float s = wave_reduce_sum(ox + oy + oz + ow);
  float mean = s * (1.0f / H);
  float cx = ox - mean, cy = oy - mean, cz = oz - mean, cw = ow - mean;
  float sq = wave_reduce_sum(cx * cx + cy * cy + cz * cz + cw * cw);
  float rstd = rsqrtf(sq * (1.0f / H) + LN_EPS);
  float4 g4 = *(const float4*)&ln_g[f4];
  float4 b4 = *(const float4*)&ln_b[f4];
  ushort4 xres4 = *(const ushort4*)&xst[rowbase + f4];
  float yx = fmaxf(fmaf(cx * rstd, g4.x, b4.x), 0.f) + h2f(xres4.x);
  float yy = fmaxf(fmaf(cy * rstd, g4.y, b4.y), 0.f) + h2f(xres4.y);
  float yz = fmaxf(fmaf(cz * rstd, g4.z, b4.z), 0.f) + h2f(xres4.z);
  float yw = fmaxf(fmaf(cw * rstd, g4.w, b4.w), 0.f) + h2f(xres4.w);
  ushort4 yb;
  yb.x = f2h(yx); yb.y = f2h(yy); yb.z = f2h(yz); yb.w = f2h(yw);
  *(ushort4*)&xst[rowbase + f4] = yb;
}

// ---------------- gate init + graph bounds (merged; batch sorted) ----------------
__global__ void gate_init_kernel(float* __restrict__ gate, const float* __restrict__ bg2,
                                 const int* __restrict__ batch,
                                 int* __restrict__ gstart, int* __restrict__ gend) {
  int i = blockIdx.x * 256 + threadIdx.x;
  if (i < N_NODES) {
    gate[i] = bg2[0];
    int b = batch[i];
    if (i == 0 || batch[i - 1] != b) gstart[b] = i;
    if (i == N_NODES - 1 || batch[i + 1] != b) gend[b] = i + 1;
  }
}

// ---------------- pooling: per-graph softmax stats (+ pooled zero) ----------------
__global__ __launch_bounds__(256) void pool_prep_kernel(
    const float* __restrict__ gate, const int* __restrict__ gstart,
    const int* __restrict__ gend, float* __restrict__ gmax, float* __restrict__ gdinv,
    float* __restrict__ pooled)
{
  __shared__ float red[256];
  int g = blockIdx.x, tid = threadIdx.x;
  pooled[(size_t)g * H + tid] = 0.f;
  int s = gstart[g], e = gend[g];
  float lm = -INFINITY;
  for (int i = s + tid; i < e; i += 256) lm = fmaxf(lm, gate[i]);
  red[tid] = lm;
  __syncthreads();
  for (int off = 128; off; off >>= 1) {
    if (tid < off) red[tid] = fmaxf(red[tid], red[tid + off]);
    __syncthreads();
  }
  float m = red[0];
  __syncthreads();
  float lsum = 0.0f;
  for (int i = s + tid; i < e; i += 256) lsum += __expf(gate[i] - m);
  red[tid] = lsum;
  __syncthreads();
  for (int off = 128; off; off >>= 1) {
    if (tid < off) red[tid] += red[tid + off];
    __syncthreads();
  }
  if (tid == 0) {
    gmax[g] = m;
    gdinv[g] = (s < e) ? 1.0f / red[0] : 0.0f;
  }
}

// ---------------- pooling: weighted accumulate (128 nodes per block, fp16 x) ----------------
__global__ __launch_bounds__(256) void pool_accum_kernel(
    const float* __restrict__ gate, const u16* __restrict__ xh,
    const int* __restrict__ batch, const float* __restrict__ gmax,
    const float* __restrict__ gdinv, float* __restrict__ pooled)
{
  __shared__ float wl[128];
  __shared__ int gl[128];
  int b0 = blockIdx.x * 128;
  int tid = threadIdx.x;
  if (tid < 128) {
    int v = b0 + tid;
    if (v < N_NODES) {
      int g = batch[v];
      gl[tid] = g;
      wl[tid] = __expf(gate[v] - gmax[g]) * gdinv[g];
    } else {
      gl[tid] = -1;
      wl[tid] = 0.f;
    }
  }
  __syncthreads();
  int cnt = min(128, N_NODES - b0);
  float acc = 0.f;
  int cur = gl[0];
  for (int j = 0; j < cnt; j++) {
    int g = gl[j];
    if (g != cur) {
      atomicAdd(&pooled[(size_t)cur * H + tid], acc);
      acc = 0.f;
      cur = g;
    }
    acc += wl[j] * h2f(xh[(size_t)(b0 + j) * H + tid]);
  }
  if (cur >= 0) atomicAdd(&pooled[(size_t)cur * H + tid], acc);
}

// ---------------- fused head: pooled -> z -> {cls, r1} -> residual ----------------
__global__ __launch_bounds__(256) void head_kernel(
    const float* __restrict__ pooled,
    const float* __restrict__ Ws, const float* __restrict__ bs,
    const float* __restrict__ Wc, const float* __restrict__ bc,
    const float* __restrict__ Wr1, const float* __restrict__ br1,
    const float* __restrict__ Wr2, const float* __restrict__ br2,
    float* __restrict__ out)
{
  __shared__ float psh[256];
  __shared__ float zsh[256];
  __shared__ float r1sh[128];
  int g = blockIdx.x, tid = threadIdx.x;
  psh[tid] = pooled[(size_t)g * H + tid];
  __syncthreads();
  {
    float acc = bs[tid];
    const float4* wr = (const float4*)&Ws[(size_t)tid * H];
    for (int k4 = 0; k4 < H / 4; k4++) {
      float4 wv = wr[k4];
      float4 av = *(const float4*)&psh[k4 * 4];
      acc += av.x * wv.x + av.y * wv.y + av.z * wv.z + av.w * wv.w;
    }
    zsh[tid] = fmaxf(acc, 0.f);
  }
  __syncthreads();
  if (tid < NB) {
    float acc = bc[tid];
    const float4* wr = (const float4*)&Wc[(size_t)tid * H];
    for (int k4 = 0; k4 < H / 4; k4++) {
      float4 wv = wr[k4];
      float4 av = *(const float4*)&zsh[k4 * 4];
      acc += av.x * wv.x + av.y * wv.y + av.z * wv.z + av.w * wv.w;
    }
    out[(size_t)g * NB + tid] = acc;
  }
  if (tid < 128) {
    float acc = br1[tid];
    const float4* wr = (const float4*)&Wr1[(size_t)tid * H];
    for (int k4 = 0; k4 < H / 4; k4++) {
      float4 wv = wr[k4];
      float4 av = *(const float4*)&zsh[k4 * 4];
      acc += av.x * wv.x + av.y * wv.y + av.z * wv.z + av.w * wv.w;
    }
    r1sh[tid] = fmaxf(acc, 0.f);
  }
  __syncthreads();
  if (tid < 64) {
    float s2 = r1sh[tid] * Wr2[tid] + r1sh[tid + 64] * Wr2[tid + 64];
    s2 = wave_reduce_sum(s2);
    if (tid == 0) out[(size_t)NGRAPH * NB + g] = tanhf(s2 + br2[0]);
  }
}

// ---------------- launcher ----------------
extern "C" void kernel_launch(void* const* d_in, const int* in_sizes, int n_in,
                              void* d_out, int out_size, void* d_ws, size_t ws_size,
                              hipStream_t stream) {
  const float* x_in   = (const float*)d_in[0];
  const int*   eidx   = (const int*)d_in[1];
  const int*   batch  = (const int*)d_in[2];
  const float* W_in   = (const float*)d_in[3];
  const float* b_in   = (const float*)d_in[4];
  const float* Wl     = (const float*)d_in[5];
  const float* bl     = (const float*)d_in[6];
  const float* Wr     = (const float*)d_in[7];
  const float* br     = (const float*)d_in[8];
  const float* att    = (const float*)d_in[9];
  const float* bias_c = (const float*)d_in[10];
  const float* ln_g   = (const float*)d_in[11];
  const float* ln_b   = (const float*)d_in[12];
  const float* Wg1    = (const float*)d_in[13];
  const float* bg1    = (const float*)d_in[14];
  const float* Wg2    = (const float*)d_in[15];
  const float* bg2    = (const float*)d_in[16];
  const float* Ws     = (const float*)d_in[17];
  const float* bs     = (const float*)d_in[18];
  const float* Wc     = (const float*)d_in[19];
  const float* bc     = (const float*)d_in[20];
  const float* Wr1    = (const float*)d_in[21];
  const float* br1    = (const float*)d_in[22];
  const float* Wr2    = (const float*)d_in[23];
  const float* br2    = (const float*)d_in[24];
  float* out = (float*)d_out;

  char* w = (char*)d_ws;
  u16* x_h    = (u16*)w;    w += sizeof(u16) * (size_t)N_NODES * H;
  u16* xl_h   = (u16*)w;    w += sizeof(u16) * (size_t)N_NODES * H;
  u16* xr_h   = (u16*)w;    w += sizeof(u16) * (size_t)N_NODES * H;
  u16* xin_h  = (u16*)w;    w += sizeof(u16) * (size_t)N_NODES * IN_DIM;
  u16* win_h  = (u16*)w;    w += sizeof(u16) * (size_t)H * IN_DIM;
  u16* wl_h   = (u16*)w;    w += sizeof(u16) * (size_t)LAYERS * H * H;
  u16* wr_h   = (u16*)w;    w += sizeof(u16) * (size_t)LAYERS * H * H;
  u16* wg1_h  = (u16*)w;    w += sizeof(u16) * (size_t)H * H;
  float* pooled = (float*)w; w += sizeof(float) * NGRAPH * H;
  float* gate = (float*)w;  w += sizeof(float) * N_NODES;
  float* gmax = (float*)w;  w += sizeof(float) * NGRAPH;
  float* gdinv= (float*)w;  w += sizeof(float) * NGRAPH;
  int* cnt    = (int*)w;    w += sizeof(int) * N_NODES;
  int* rowp   = (int*)w;    w += sizeof(int) * (N_NODES + 1);
  int* col    = (int*)w;    w += sizeof(int) * EE;
  int* partial= (int*)w;    w += sizeof(int) * N_NODES;
  int* bsums  = (int*)w;    w += sizeof(int) * 256;
  int* gstart = (int*)w;    w += sizeof(int) * NGRAPH;
  int* gend   = (int*)w;    w += sizeof(int) * NGRAPH;
  (void)ws_size; (void)n_in; (void)in_sizes; (void)out_size;

  const int* src = eidx;
  const int* dst = eidx + N_EDGES;
  int nblkN = (N_NODES + 255) / 256;
  int nblkE = (N_EDGES + 255) / 256;
  int mtiles = (N_NODES + GTM - 1) / GTM;
  int mtiles2 = (N_NODES + DTM - 1) / DTM;

  // CSR build (by dst, self-loops first in each row)
  init_counts_kernel<<<nblkN, 256, 0, stream>>>(cnt);
  count_edges_kernel<<<nblkE, 256, 0, stream>>>(dst, cnt);
  scan_blocks_kernel<<<nblkN, 256, 0, stream>>>(cnt, partial, bsums, N_NODES);
  scan_sums_kernel<<<1, 256, 0, stream>>>(bsums, nblkN);
  scan_write_kernel<<<nblkN, 256, 0, stream>>>(partial, bsums, rowp, N_NODES);
  fill_self_kernel<<<nblkN, 256, 0, stream>>>(rowp, col, cnt);
  fill_edges_kernel<<<nblkE, 256, 0, stream>>>(src, dst, cnt, col);

  // casts
  {
    int maxn4 = LAYERS * H * H / 4;
    dim3 gcast((maxn4 + 255) / 256, 4);
    cast_weights_kernel<<<gcast, 256, 0, stream>>>(W_in, Wg1, Wl, Wr,
                                                   win_h, wg1_h, wl_h, wr_h);
    int n4 = N_NODES * IN_DIM / 4;
    cast_f16_kernel<<<(n4 + 255) / 256, 256, 0, stream>>>(x_in, xin_h, n4);
  }

  // input projection -> x_h
  dim3 gproj(2, mtiles);
  gemm_proj_kernel<<<gproj, 256, 0, stream>>>(xin_h, win_h, b_in, x_h, N_NODES, IN_DIM);

  int nblkV = N_NODES / 4;
  dim3 gdual(4, mtiles2);
  for (int l = 0; l < LAYERS; l++) {
    gemm_dual3_kernel<<<gdual, 256, 0, stream>>>(x_h,
        wl_h + (size_t)l * H * H, wr_h + (size_t)l * H * H,
        bl + l * H, br + l * H, xl_h, xr_h, N_NODES);
    layer_fused_kernel<<<nblkV, 256, 0, stream>>>(xl_h, xr_h, x_h, rowp, col,
        att + l * H, bias_c + l * H, ln_g + l * H, ln_b + l * H);
  }

  // gate (fused GEMM + row-dot); gate_init also computes graph bounds
  gate_init_kernel<<<nblkN, 256, 0, stream>>>(gate, bg2, batch, gstart, gend);
  dim3 ggate(2, mtiles);
  gemm_gate_kernel<<<ggate, 256, 0, stream>>>(x_h, wg1_h, bg1, Wg2, gate, N_NODES);

  // pooling
  pool_prep_kernel<<<NGRAPH, 256, 0, stream>>>(gate, gstart, gend, gmax, gdinv, pooled);
  pool_accum_kernel<<<(N_NODES + 127) / 128, 256, 0, stream>>>(gate, x_h, batch, gmax, gdinv, pooled);

  // fused heads
  head_kernel<<<NGRAPH, 256, 0, stream>>>(pooled, Ws, bs, Wc, bc, Wr1, br1, Wr2, br2, out);
}

// Round 17
// 565.380 us; speedup vs baseline: 1.4530x; 1.0335x over previous
//
#include <hip/hip_runtime.h>
#include <math.h>

#define N_NODES 50000
#define N_EDGES 300000
#define IN_DIM 64
#define H 256
#define LAYERS 4
#define NB 181
#define NGRAPH 64
#define EE (N_EDGES + N_NODES)
#define NEG_SLOPE 0.2f
#define LN_EPS 1e-5f

typedef unsigned short u16;
typedef __attribute__((ext_vector_type(8))) _Float16 half8;
typedef __attribute__((ext_vector_type(4))) float floatx4;

__device__ __forceinline__ u16 f2h(float f) {
  _Float16 h = (_Float16)f;
  return __builtin_bit_cast(u16, h);
}
__device__ __forceinline__ float h2f(u16 b) {
  return (float)__builtin_bit_cast(_Float16, b);
}

__device__ __forceinline__ float wave_reduce_sum(float v) {
  #pragma unroll
  for (int off = 32; off > 0; off >>= 1) v += __shfl_xor(v, off, 64);
  return v;
}

// ---------------- casts ----------------
__global__ void cast_f16_kernel(const float* __restrict__ in, u16* __restrict__ out, int n4) {
  int i = blockIdx.x * 256 + threadIdx.x;
  if (i < n4) {
    float4 f = ((const float4*)in)[i];
    ushort4 o;
    o.x = f2h(f.x); o.y = f2h(f.y); o.z = f2h(f.z); o.w = f2h(f.w);
    ((ushort4*)out)[i] = o;
  }
}

__global__ void cast_weights_kernel(
    const float* __restrict__ W_in, const float* __restrict__ Wg1,
    const float* __restrict__ Wl, const float* __restrict__ Wr,
    u16* __restrict__ win_h, u16* __restrict__ wg1_h,
    u16* __restrict__ wl_h, u16* __restrict__ wr_h)
{
  int i = blockIdx.x * 256 + threadIdx.x;
  int which = blockIdx.y;
  const float* s; u16* dd; int n4;
  if (which == 0)      { s = W_in; dd = win_h; n4 = H * IN_DIM / 4; }
  else if (which == 1) { s = Wg1;  dd = wg1_h; n4 = H * H / 4; }
  else if (which == 2) { s = Wl;   dd = wl_h;  n4 = LAYERS * H * H / 4; }
  else                 { s = Wr;   dd = wr_h;  n4 = LAYERS * H * H / 4; }
  if (i < n4) {
    float4 f = ((const float4*)s)[i];
    ushort4 o;
    o.x = f2h(f.x); o.y = f2h(f.y); o.z = f2h(f.z); o.w = f2h(f.w);
    ((ushort4*)dd)[i] = o;
  }
}

// ---------------- CSR build ----------------
__global__ void init_counts_kernel(int* __restrict__ cnt) {
  int i = blockIdx.x * 256 + threadIdx.x;
  if (i < N_NODES) cnt[i] = 1;  // self loop
}

__global__ void count_edges_kernel(const int* __restrict__ dst, int* __restrict__ cnt) {
  int e = blockIdx.x * 256 + threadIdx.x;
  if (e < N_EDGES) atomicAdd(&cnt[dst[e]], 1);
}

__global__ void scan_blocks_kernel(const int* __restrict__ cnt, int* __restrict__ partial,
                                   int* __restrict__ bsums, int n) {
  __shared__ int buf[256];
  int tid = threadIdx.x;
  int i = blockIdx.x * 256 + tid;
  buf[tid] = (i < n) ? cnt[i] : 0;
  __syncthreads();
  #pragma unroll
  for (int off = 1; off < 256; off <<= 1) {
    int t = (tid >= off) ? buf[tid - off] : 0;
    __syncthreads();
    buf[tid] += t;
    __syncthreads();
  }
  if (i < n) partial[i] = buf[tid];
  if (tid == 255) bsums[blockIdx.x] = buf[255];
}

__global__ void scan_sums_kernel(int* __restrict__ bsums, int nblk) {
  __shared__ int buf[256];
  int tid = threadIdx.x;
  buf[tid] = (tid < nblk) ? bsums[tid] : 0;
  __syncthreads();
  #pragma unroll
  for (int off = 1; off < 256; off <<= 1) {
    int t = (tid >= off) ? buf[tid - off] : 0;
    __syncthreads();
    buf[tid] += t;
    __syncthreads();
  }
  if (tid < nblk) bsums[tid] = buf[tid];
}

__global__ void scan_write_kernel(const int* __restrict__ partial, const int* __restrict__ bsums,
                                  int* __restrict__ rowp, int n) {
  int i = blockIdx.x * 256 + threadIdx.x;
  if (i < n) {
    int b = blockIdx.x;
    int off = (b > 0) ? bsums[b - 1] : 0;
    rowp[i + 1] = partial[i] + off;
    if (i == 0) rowp[0] = 0;
  }
}

__global__ void fill_self_kernel(const int* __restrict__ rowp, int* __restrict__ col,
                                 int* __restrict__ fillpos) {
  int i = blockIdx.x * 256 + threadIdx.x;
  if (i < N_NODES) {
    int p = rowp[i];
    col[p] = i;       // self loop FIRST in each row (layer_fused relies on this)
    fillpos[i] = p + 1;
  }
}

__global__ void fill_edges_kernel(const int* __restrict__ src, const int* __restrict__ dst,
                                  int* __restrict__ fillpos, int* __restrict__ col) {
  int e = blockIdx.x * 256 + threadIdx.x;
  if (e < N_EDGES) {
    int d = dst[e];
    int p = atomicAdd(&fillpos[d], 1);
    col[p] = src[e];
  }
}

// ---------------- MFMA GEMM tiles ----------------
#define GTM 128
#define GTK 64
#define LDB 72
#define SSTR 132

__global__ __launch_bounds__(256) void gemm_proj_kernel(
    const u16* __restrict__ A, const u16* __restrict__ W,
    const float* __restrict__ bias, u16* __restrict__ outh, int M, int K)
{
  __shared__ u16 smem[2 * GTM * LDB];
  u16* As = smem;
  u16* Bs = smem + GTM * LDB;
  int tid = threadIdx.x;
  int lane = tid & 63;
  int wave = tid >> 6;
  int wm = (wave >> 1) * 64;
  int wn = (wave & 1) * 64;
  int bm = blockIdx.y * GTM;
  int n0 = blockIdx.x * 128;
  int lr = tid >> 3;
  int lc = (tid & 7) * 8;

  floatx4 zero4 = {0.f, 0.f, 0.f, 0.f};
  floatx4 acc[4][4];
  #pragma unroll
  for (int i = 0; i < 4; i++)
    #pragma unroll
    for (int j = 0; j < 4; j++) acc[i][j] = zero4;

  int q8 = (lane >> 4) * 8;
  int mrow = lane & 15;

  for (int k0 = 0; k0 < K; k0 += GTK) {
    __syncthreads();
    #pragma unroll
    for (int p = 0; p < 4; p++) {
      int row = lr + p * 32;
      int gr = bm + row;
      uint4 av = {0, 0, 0, 0};
      if (gr < M) av = *(const uint4*)&A[(size_t)gr * K + k0 + lc];
      *(uint4*)&As[row * LDB + lc] = av;
      uint4 bv = *(const uint4*)&W[(size_t)(n0 + row) * K + k0 + lc];
      *(uint4*)&Bs[row * LDB + lc] = bv;
    }
    __syncthreads();
    #pragma unroll
    for (int h = 0; h < 2; h++) {
      half8 af[4], bf[4];
      #pragma unroll
      for (int i = 0; i < 4; i++)
        af[i] = *(const half8*)&As[(wm + i * 16 + mrow) * LDB + h * 32 + q8];
      #pragma unroll
      for (int j = 0; j < 4; j++)
        bf[j] = *(const half8*)&Bs[(wn + j * 16 + mrow) * LDB + h * 32 + q8];
      #pragma unroll
      for (int i = 0; i < 4; i++)
        #pragma unroll
        for (int j = 0; j < 4; j++)
          acc[i][j] = __builtin_amdgcn_mfma_f32_16x16x32_f16(af[i], bf[j], acc[i][j], 0, 0, 0);
    }
  }

  __syncthreads();
  u16* stage = smem;
  int ccol = lane & 15;
  int crow4 = (lane >> 4) * 4;
  #pragma unroll
  for (int j = 0; j < 4; j++) {
    float bv = bias[n0 + wn + j * 16 + ccol];
    #pragma unroll
    for (int i = 0; i < 4; i++) {
      #pragma unroll
      for (int r = 0; r < 4; r++) {
        int row = wm + i * 16 + crow4 + r;
        stage[row * SSTR + wn + j * 16 + ccol] = f2h(acc[i][j][r] + bv);
      }
    }
  }
  __syncthreads();
  int rr = tid >> 1;
  int c0 = (tid & 1) * 64;
  int grow = bm + rr;
  if (grow < M) {
    const ushort4* sp = (const ushort4*)&stage[rr * SSTR + c0];
    ushort4* gp = (ushort4*)&outh[(size_t)grow * H + n0 + c0];
    #pragma unroll
    for (int q = 0; q < 16; q++) gp[q] = sp[q];
  }
}

// ---------------- dual GEMM v5: one n-tile per block, 64-row m-tiles, 27.6 KB LDS ----------------
#define DTM 64
#define SSTR2 132

__global__ __launch_bounds__(256) void gemm_dual3_kernel(
    const u16* __restrict__ A, const u16* __restrict__ Wlb, const u16* __restrict__ Wrb,
    const float* __restrict__ biasL, const float* __restrict__ biasR,
    u16* __restrict__ outL, u16* __restrict__ outR, int M)
{
  __shared__ u16 As[DTM * LDB];
  __shared__ u16 Bs[128 * LDB];
  int tid = threadIdx.x;
  int lane = tid & 63;
  int wave = tid >> 6;
  int wn = wave * 32;
  int nt = blockIdx.x;
  int bm = blockIdx.y * DTM;
  const u16* W = (nt < 2) ? Wlb : Wrb;
  const float* bias = (nt < 2) ? biasL : biasR;
  u16* outp = (nt < 2) ? outL : outR;
  int n0 = (nt & 1) * 128;
  int mrow = lane & 15;
  int q8 = (lane >> 4) * 8;
  int ccol = lane & 15;
  int crow4 = (lane >> 4) * 4;
  int lr = tid >> 3;
  int lc = (tid & 7) * 8;

  floatx4 zero4 = {0.f, 0.f, 0.f, 0.f};
  floatx4 acc[4][2];
  #pragma unroll
  for (int i = 0; i < 4; i++) {
    acc[i][0] = zero4;
    acc[i][1] = zero4;
  }

  for (int k0 = 0; k0 < H; k0 += 64) {
    __syncthreads();
    #pragma unroll
    for (int p = 0; p < 2; p++) {
      int row = lr + p * 32;
      int gr = bm + row;
      uint4 av = {0, 0, 0, 0};
      if (gr < M) av = *(const uint4*)&A[(size_t)gr * H + k0 + lc];
      *(uint4*)&As[row * LDB + lc] = av;
    }
    #pragma unroll
    for (int p = 0; p < 4; p++) {
      int row = lr + p * 32;
      uint4 bv = *(const uint4*)&W[(size_t)(n0 + row) * H + k0 + lc];
      *(uint4*)&Bs[row * LDB + lc] = bv;
    }
    __syncthreads();
    #pragma unroll
    for (int h = 0; h < 2; h++) {
      half8 af[4], bf[2];
      #pragma unroll
      for (int i = 0; i < 4; i++)
        af[i] = *(const half8*)&As[(i * 16 + mrow) * LDB + h * 32 + q8];
      #pragma unroll
      for (int j = 0; j < 2; j++)
        bf[j] = *(const half8*)&Bs[(wn + j * 16 + mrow) * LDB + h * 32 + q8];
      #pragma unroll
      for (int i = 0; i < 4; i++)
        #pragma unroll
        for (int j = 0; j < 2; j++)
          acc[i][j] = __builtin_amdgcn_mfma_f32_16x16x32_f16(af[i], bf[j], acc[i][j], 0, 0, 0);
    }
  }

  __syncthreads();
  u16* stage = Bs;
  #pragma unroll
  for (int j = 0; j < 2; j++) {
    float bv = bias[n0 + wn + j * 16 + ccol];
    #pragma unroll
    for (int i = 0; i < 4; i++) {
      #pragma unroll
      for (int r = 0; r < 4; r++) {
        int row = i * 16 + crow4 + r;
        stage[row * SSTR2 + wn + j * 16 + ccol] = f2h(acc[i][j][r] + bv);
      }
    }
  }
  __syncthreads();
  #pragma unroll
  for (int pass = 0; pass < 4; pass++) {
    int row = pass * 16 + (tid >> 4);
    int cu = (tid & 15) * 8;
    int grow = bm + row;
    if (grow < M) {
      *(uint4*)&outp[(size_t)grow * H + n0 + cu] =
          *(const uint4*)&stage[row * SSTR2 + cu];
    }
  }
}

// ---------------- gate GEMM v2: dual3-style 64-row m-tiles, 128-col n-tile per block ----------------
__global__ __launch_bounds__(256) void gemm_gate2_kernel(
    const u16* __restrict__ A, const u16* __restrict__ W,
    const float* __restrict__ bias, const float* __restrict__ Wg2,
    float* __restrict__ gate, int M)
{
  __shared__ u16 As[DTM * LDB];
  __shared__ u16 Bs[128 * LDB];
  int tid = threadIdx.x;
  int lane = tid & 63;
  int wave = tid >> 6;
  int wn = wave * 32;
  int n0 = blockIdx.x * 128;
  int bm = blockIdx.y * DTM;
  int mrow = lane & 15;
  int q8 = (lane >> 4) * 8;
  int ccol = lane & 15;
  int crow4 = (lane >> 4) * 4;
  int lr = tid >> 3;
  int lc = (tid & 7) * 8;

  floatx4 zero4 = {0.f, 0.f, 0.f, 0.f};
  floatx4 acc[4][2];
  #pragma unroll
  for (int i = 0; i < 4; i++) {
    acc[i][0] = zero4;
    acc[i][1] = zero4;
  }

  for (int k0 = 0; k0 < H; k0 += 64) {
    __syncthreads();
    #pragma unroll
    for (int p = 0; p < 2; p++) {
      int row = lr + p * 32;
      int gr = bm + row;
      uint4 av = {0, 0, 0, 0};
      if (gr < M) av = *(const uint4*)&A[(size_t)gr * H + k0 + lc];
      *(uint4*)&As[row * LDB + lc] = av;
    }
    #pragma unroll
    for (int p = 0; p < 4; p++) {
      int row = lr + p * 32;
      uint4 bv = *(const uint4*)&W[(size_t)(n0 + row) * H + k0 + lc];
      *(uint4*)&Bs[row * LDB + lc] = bv;
    }
    __syncthreads();
    #pragma unroll
    for (int h = 0; h < 2; h++) {
      half8 af[4], bf[2];
      #pragma unroll
      for (int i = 0; i < 4; i++)
        af[i] = *(const half8*)&As[(i * 16 + mrow) * LDB + h * 32 + q8];
      #pragma unroll
      for (int j = 0; j < 2; j++)
        bf[j] = *(const half8*)&Bs[(wn + j * 16 + mrow) * LDB + h * 32 + q8];
      #pragma unroll
      for (int i = 0; i < 4; i++)
        #pragma unroll
        for (int j = 0; j < 2; j++)
          acc[i][j] = __builtin_amdgcn_mfma_f32_16x16x32_f16(af[i], bf[j], acc[i][j], 0, 0, 0);
    }
  }

  float bv[2], wv[2];
  #pragma unroll
  for (int j = 0; j < 2; j++) {
    int c = n0 + wn + j * 16 + ccol;
    bv[j] = bias[c];
    wv[j] = Wg2[c];
  }
  #pragma unroll
  for (int i = 0; i < 4; i++) {
    #pragma unroll
    for (int r = 0; r < 4; r++) {
      float p = fmaxf(acc[i][0][r] + bv[0], 0.f) * wv[0]
              + fmaxf(acc[i][1][r] + bv[1], 0.f) * wv[1];
      p += __shfl_xor(p, 1, 64);
      p += __shfl_xor(p, 2, 64);
      p += __shfl_xor(p, 4, 64);
      p += __shfl_xor(p, 8, 64);
      int row = bm + i * 16 + crow4 + r;
      if ((lane & 15) == 0 && row < M) atomicAdd(&gate[row], p);
    }
  }
}

// ---------------- fused edge softmax + aggregate + LN + residual ----------------
// Self-edge-anchored softmax + mask-free unroll-4 main loop (commutative body).
__global__ __launch_bounds__(256) void layer_fused_kernel(
    const u16* __restrict__ xl, const u16* __restrict__ xr,
    u16* __restrict__ xst,
    const int* __restrict__ rowp, const int* __restrict__ col,
    const float* __restrict__ att, const float* __restrict__ bias_c,
    const float* __restrict__ ln_g, const float* __restrict__ ln_b)
{
  int lane = threadIdx.x & 63;
  int v = blockIdx.x * 4 + (threadIdx.x >> 6);
  if (v >= N_NODES) return;
  int f4 = lane << 2;
  size_t rowbase = (size_t)v * H;
  ushort4 xr4 = *(const ushort4*)&xr[rowbase + f4];
  float xrx = h2f(xr4.x), xry = h2f(xr4.y), xrz = h2f(xr4.z), xrw = h2f(xr4.w);
  float4 attv = *(const float4*)&att[f4];
  int beg = rowp[v], end = rowp[v + 1];

  float sx, sy, sz, sw, m;
  {
    ushort4 a04 = *(const ushort4*)&xl[rowbase + f4];
    sx = h2f(a04.x); sy = h2f(a04.y); sz = h2f(a04.z); sw = h2f(a04.w);
    float t0x = sx + xrx; t0x = t0x > 0.f ? t0x : NEG_SLOPE * t0x;
    float t0y = sy + xry; t0y = t0y > 0.f ? t0y : NEG_SLOPE * t0y;
    float t0z = sz + xrz; t0z = t0z > 0.f ? t0z : NEG_SLOPE * t0z;
    float t0w = sw + xrw; t0w = t0w > 0.f ? t0w : NEG_SLOPE * t0w;
    float pe = t0x * attv.x + t0y * attv.y + t0z * attv.z + t0w * attv.w;
    m = wave_reduce_sum(pe);
  }
  float d = 1.0f;
  float ox = sx, oy = sy, oz = sz, ow = sw;

  int p = beg + 1;
  for (; p + 4 <= end; p += 4) {
    int u0 = col[p];
    int u1 = col[p + 1];
    int u2 = col[p + 2];
    int u3 = col[p + 3];
    ushort4 A0 = *(const ushort4*)&xl[(size_t)u0 * H + f4];
    ushort4 A1 = *(const ushort4*)&xl[(size_t)u1 * H + f4];
    ushort4 A2 = *(const ushort4*)&xl[(size_t)u2 * H + f4];
    ushort4 A3 = *(const ushort4*)&xl[(size_t)u3 * H + f4];
    float a0x = h2f(A0.x), a0y = h2f(A0.y), a0z = h2f(A0.z), a0w = h2f(A0.w);
    float a1x = h2f(A1.x), a1y = h2f(A1.y), a1z = h2f(A1.z), a1w = h2f(A1.w);
    float a2x = h2f(A2.x), a2y = h2f(A2.y), a2z = h2f(A2.z), a2w = h2f(A2.w);
    float a3x = h2f(A3.x), a3y = h2f(A3.y), a3z = h2f(A3.z), a3w = h2f(A3.w);
    float t, pe0, pe1, pe2, pe3;
    t = a0x + xrx; t = t > 0.f ? t : NEG_SLOPE * t; pe0 = t * attv.x;
    t = a0y + xry; t = t > 0.f ? t : NEG_SLOPE * t; pe0 = fmaf(t, attv.y, pe0);
    t = a0z + xrz; t = t > 0.f ? t : NEG_SLOPE * t; pe0 = fmaf(t, attv.z, pe0);
    t = a0w + xrw; t = t > 0.f ? t : NEG_SLOPE * t; pe0 = fmaf(t, attv.w, pe0);
    t = a1x + xrx; t = t > 0.f ? t : NEG_SLOPE * t; pe1 = t * attv.x;
    t = a1y + xry; t = t > 0.f ? t : NEG_SLOPE * t; pe1 = fmaf(t, attv.y, pe1);
    t = a1z + xrz; t = t > 0.f ? t : NEG_SLOPE * t; pe1 = fmaf(t, attv.z, pe1);
    t = a1w + xrw; t = t > 0.f ? t : NEG_SLOPE * t; pe1 = fmaf(t, attv.w, pe1);
    t = a2x + xrx; t = t > 0.f ? t : NEG_SLOPE * t; pe2 = t * attv.x;
    t = a2y + xry; t = t > 0.f ? t : NEG_SLOPE * t; pe2 = fmaf(t, attv.y, pe2);
    t = a2z + xrz; t = t > 0.f ? t : NEG_SLOPE * t; pe2 = fmaf(t, attv.z, pe2);
    t = a2w + xrw; t = t > 0.f ? t : NEG_SLOPE * t; pe2 = fmaf(t, attv.w, pe2);
    t = a3x + xrx; t = t > 0.f ? t : NEG_SLOPE * t; pe3 = t * attv.x;
    t = a3y + xry; t = t > 0.f ? t : NEG_SLOPE * t; pe3 = fmaf(t, attv.y, pe3);
    t = a3z + xrz; t = t > 0.f ? t : NEG_SLOPE * t; pe3 = fmaf(t, attv.z, pe3);
    t = a3w + xrw; t = t > 0.f ? t : NEG_SLOPE * t; pe3 = fmaf(t, attv.w, pe3);
    #pragma unroll
    for (int off = 32; off > 0; off >>= 1) {
      pe0 += __shfl_xor(pe0, off, 64);
      pe1 += __shfl_xor(pe1, off, 64);
      pe2 += __shfl_xor(pe2, off, 64);
      pe3 += __shfl_xor(pe3, off, 64);
    }
    float w0 = __expf(pe0 - m);
    float w1 = __expf(pe1 - m);
    float w2 = __expf(pe2 - m);
    float w3 = __expf(pe3 - m);
    d += (w0 + w1) + (w2 + w3);
    ox = fmaf(w0, a0x, fmaf(w1, a1x, fmaf(w2, a2x, fmaf(w3, a3x, ox))));
    oy = fmaf(w0, a0y, fmaf(w1, a1y, fmaf(w2, a2y, fmaf(w3, a3y, oy))));
    oz = fmaf(w0, a0z, fmaf(w1, a1z, fmaf(w2, a2z, fmaf(w3, a3z, oz))));
    ow = fmaf(w0, a0w, fmaf(w1, a1w, fmaf(w2, a2w, fmaf(w3, a3w, ow))));
  }
  for (; p < end; p++) {
    int u0 = col[p];
    ushort4 a04 = *(const ushort4*)&xl[(size_t)u0 * H + f4];
    float a0x = h2f(a04.x), a0y = h2f(a04.y), a0z = h2f(a04.z), a0w = h2f(a04.w);
    float t0x = a0x + xrx; t0x = t0x > 0.f ? t0x : NEG_SLOPE * t0x;
    float t0y = a0y + xry; t0y = t0y > 0.f ? t0y : NEG_SLOPE * t0y;
    float t0z = a0z + xrz; t0z = t0z > 0.f ? t0z : NEG_SLOPE * t0z;
    float t0w = a0w + xrw; t0w = t0w > 0.f ? t0w : NEG_SLOPE * t0w;
    float pe0 = t0x * attv.x + t0y * attv.y + t0z * attv.z + t0w * attv.w;
    pe0 = wave_reduce_sum(pe0);
    float w0 = __expf(pe0 - m);
    d += w0;
    ox = fmaf(w0, a0x, ox);
    oy = fmaf(w0, a0y, oy);
    oz = fmaf(w0, a0z, oz);
    ow = fmaf(w0, a0w, ow);
  }
  float invd = 1.0f / d;
  float4 bc4 = *(const float4*)&bias_c[f4];
  ox = ox * invd + bc4.x;
  oy = oy * invd + bc4.y;
  oz = oz * invd + bc4.z;
  ow = ow * invd + bc4.w;
  float s = wave_reduce_sum(ox + oy + oz + ow);
  float mean = s * (1.0f / H);
  float cx = ox - mean, cy = oy - mean, cz = oz - mean, cw = ow - mean;
  float sq = wave_reduce_sum(cx * cx + cy * cy + cz * cz + cw * cw);
  float rstd = rsqrtf(sq * (1.0f / H) + LN_EPS);
  float4 g4 = *(const float4*)&ln_g[f4];
  float4 b4 = *(const float4*)&ln_b[f4];
  ushort4 xres4 = *(const ushort4*)&xst[rowbase + f4];
  float yx = fmaxf(fmaf(cx * rstd, g4.x, b4.x), 0.f) + h2f(xres4.x);
  float yy = fmaxf(fmaf(cy * rstd, g4.y, b4.y), 0.f) + h2f(xres4.y);
  float yz = fmaxf(fmaf(cz * rstd, g4.z, b4.z), 0.f) + h2f(xres4.z);
  float yw = fmaxf(fmaf(cw * rstd, g4.w, b4.w), 0.f) + h2f(xres4.w);
  ushort4 yb;
  yb.x = f2h(yx); yb.y = f2h(yy); yb.z = f2h(yz); yb.w = f2h(yw);
  *(ushort4*)&xst[rowbase + f4] = yb;
}

// ---------------- gate init + graph bounds (merged; batch sorted) ----------------
__global__ void gate_init_kernel(float* __restrict__ gate, const float* __restrict__ bg2,
                                 const int* __restrict__ batch,
                                 int* __restrict__ gstart, int* __restrict__ gend) {
  int i = blockIdx.x * 256 + threadIdx.x;
  if (i < N_NODES) {
    gate[i] = bg2[0];
    int b = batch[i];
    if (i == 0 || batch[i - 1] != b) gstart[b] = i;
    if (i == N_NODES - 1 || batch[i + 1] != b) gend[b] = i + 1;
  }
}

// ---------------- pooling: per-graph softmax stats (+ pooled zero) ----------------
__global__ __launch_bounds__(256) void pool_prep_kernel(
    const float* __restrict__ gate, const int* __restrict__ gstart,
    const int* __restrict__ gend, float* __restrict__ gmax, float* __restrict__ gdinv,
    float* __restrict__ pooled)
{
  __shared__ float red[256];
  int g = blockIdx.x, tid = threadIdx.x;
  pooled[(size_t)g * H + tid] = 0.f;
  int s = gstart[g], e = gend[g];
  float lm = -INFINITY;
  for (int i = s + tid; i < e; i += 256) lm = fmaxf(lm, gate[i]);
  red[tid] = lm;
  __syncthreads();
  for (int off = 128; off; off >>= 1) {
    if (tid < off) red[tid] = fmaxf(red[tid], red[tid + off]);
    __syncthreads();
  }
  float m = red[0];
  __syncthreads();
  float lsum = 0.0f;
  for (int i = s + tid; i < e; i += 256) lsum += __expf(gate[i] - m);
  red[tid] = lsum;
  __syncthreads();
  for (int off = 128; off; off >>= 1) {
    if (tid < off) red[tid] += red[tid + off];
    __syncthreads();
  }
  if (tid == 0) {
    gmax[g] = m;
    gdinv[g] = (s < e) ? 1.0f / red[0] : 0.0f;
  }
}

// ---------------- pooling: weighted accumulate (64 nodes per block, fp16 x) ----------------
__global__ __launch_bounds__(256) void pool_accum_kernel(
    const float* __restrict__ gate, const u16* __restrict__ xh,
    const int* __restrict__ batch, const float* __restrict__ gmax,
    const float* __restrict__ gdinv, float* __restrict__ pooled)
{
  __shared__ float wl[64];
  __shared__ int gl[64];
  int b0 = blockIdx.x * 64;
  int tid = threadIdx.x;
  if (tid < 64) {
    int v = b0 + tid;
    if (v < N_NODES) {
      int g = batch[v];
      gl[tid] = g;
      wl[tid] = __expf(gate[v] - gmax[g]) * gdinv[g];
    } else {
      gl[tid] = -1;
      wl[tid] = 0.f;
    }
  }
  __syncthreads();
  int cnt = min(64, N_NODES - b0);
  float acc = 0.f;
  int cur = gl[0];
  for (int j = 0; j < cnt; j++) {
    int g = gl[j];
    if (g != cur) {
      atomicAdd(&pooled[(size_t)cur * H + tid], acc);
      acc = 0.f;
      cur = g;
    }
    acc += wl[j] * h2f(xh[(size_t)(b0 + j) * H + tid]);
  }
  if (cur >= 0) atomicAdd(&pooled[(size_t)cur * H + tid], acc);
}

// ---------------- fused head: pooled -> z -> {cls, r1} -> residual ----------------
__global__ __launch_bounds__(256) void head_kernel(
    const float* __restrict__ pooled,
    const float* __restrict__ Ws, const float* __restrict__ bs,
    const float* __restrict__ Wc, const float* __restrict__ bc,
    const float* __restrict__ Wr1, const float* __restrict__ br1,
    const float* __restrict__ Wr2, const float* __restrict__ br2,
    float* __restrict__ out)
{
  __shared__ float psh[256];
  __shared__ float zsh[256];
  __shared__ float r1sh[128];
  int g = blockIdx.x, tid = threadIdx.x;
  psh[tid] = pooled[(size_t)g * H + tid];
  __syncthreads();
  {
    float acc = bs[tid];
    const float4* wr = (const float4*)&Ws[(size_t)tid * H];
    for (int k4 = 0; k4 < H / 4; k4++) {
      float4 wv = wr[k4];
      float4 av = *(const float4*)&psh[k4 * 4];
      acc += av.x * wv.x + av.y * wv.y + av.z * wv.z + av.w * wv.w;
    }
    zsh[tid] = fmaxf(acc, 0.f);
  }
  __syncthreads();
  if (tid < NB) {
    float acc = bc[tid];
    const float4* wr = (const float4*)&Wc[(size_t)tid * H];
    for (int k4 = 0; k4 < H / 4; k4++) {
      float4 wv = wr[k4];
      float4 av = *(const float4*)&zsh[k4 * 4];
      acc += av.x * wv.x + av.y * wv.y + av.z * wv.z + av.w * wv.w;
    }
    out[(size_t)g * NB + tid] = acc;
  }
  if (tid < 128) {
    float acc = br1[tid];
    const float4* wr = (const float4*)&Wr1[(size_t)tid * H];
    for (int k4 = 0; k4 < H / 4; k4++) {
      float4 wv = wr[k4];
      float4 av = *(const float4*)&zsh[k4 * 4];
      acc += av.x * wv.x + av.y * wv.y + av.z * wv.z + av.w * wv.w;
    }
    r1sh[tid] = fmaxf(acc, 0.f);
  }
  __syncthreads();
  if (tid < 64) {
    float s2 = r1sh[tid] * Wr2[tid] + r1sh[tid + 64] * Wr2[tid + 64];
    s2 = wave_reduce_sum(s2);
    if (tid == 0) out[(size_t)NGRAPH * NB + g] = tanhf(s2 + br2[0]);
  }
}

// ---------------- launcher ----------------
extern "C" void kernel_launch(void* const* d_in, const int* in_sizes, int n_in,
                              void* d_out, int out_size, void* d_ws, size_t ws_size,
                              hipStream_t stream) {
  const float* x_in   = (const float*)d_in[0];
  const int*   eidx   = (const int*)d_in[1];
  const int*   batch  = (const int*)d_in[2];
  const float* W_in   = (const float*)d_in[3];
  const float* b_in   = (const float*)d_in[4];
  const float* Wl     = (const float*)d_in[5];
  const float* bl     = (const float*)d_in[6];
  const float* Wr     = (const float*)d_in[7];
  const float* br     = (const float*)d_in[8];
  const float* att    = (const float*)d_in[9];
  const float* bias_c = (const float*)d_in[10];
  const float* ln_g   = (const float*)d_in[11];
  const float* ln_b   = (const float*)d_in[12];
  const float* Wg1    = (const float*)d_in[13];
  const float* bg1    = (const float*)d_in[14];
  const float* Wg2    = (const float*)d_in[15];
  const float* bg2    = (const float*)d_in[16];
  const float* Ws     = (const float*)d_in[17];
  const float* bs     = (const float*)d_in[18];
  const float* Wc     = (const float*)d_in[19];
  const float* bc     = (const float*)d_in[20];
  const float* Wr1    = (const float*)d_in[21];
  const float* br1    = (const float*)d_in[22];
  const float* Wr2    = (const float*)d_in[23];
  const float* br2    = (const float*)d_in[24];
  float* out = (float*)d_out;

  char* w = (char*)d_ws;
  u16* x_h    = (u16*)w;    w += sizeof(u16) * (size_t)N_NODES * H;
  u16* xl_h   = (u16*)w;    w += sizeof(u16) * (size_t)N_NODES * H;
  u16* xr_h   = (u16*)w;    w += sizeof(u16) * (size_t)N_NODES * H;
  u16* xin_h  = (u16*)w;    w += sizeof(u16) * (size_t)N_NODES * IN_DIM;
  u16* win_h  = (u16*)w;    w += sizeof(u16) * (size_t)H * IN_DIM;
  u16* wl_h   = (u16*)w;    w += sizeof(u16) * (size_t)LAYERS * H * H;
  u16* wr_h   = (u16*)w;    w += sizeof(u16) * (size_t)LAYERS * H * H;
  u16* wg1_h  = (u16*)w;    w += sizeof(u16) * (size_t)H * H;
  float* pooled = (float*)w; w += sizeof(float) * NGRAPH * H;
  float* gate = (float*)w;  w += sizeof(float) * N_NODES;
  float* gmax = (float*)w;  w += sizeof(float) * NGRAPH;
  float* gdinv= (float*)w;  w += sizeof(float) * NGRAPH;
  int* cnt    = (int*)w;    w += sizeof(int) * N_NODES;
  int* rowp   = (int*)w;    w += sizeof(int) * (N_NODES + 1);
  int* col    = (int*)w;    w += sizeof(int) * EE;
  int* partial= (int*)w;    w += sizeof(int) * N_NODES;
  int* bsums  = (int*)w;    w += sizeof(int) * 256;
  int* gstart = (int*)w;    w += sizeof(int) * NGRAPH;
  int* gend   = (int*)w;    w += sizeof(int) * NGRAPH;
  (void)ws_size; (void)n_in; (void)in_sizes; (void)out_size;

  const int* src = eidx;
  const int* dst = eidx + N_EDGES;
  int nblkN = (N_NODES + 255) / 256;
  int nblkE = (N_EDGES + 255) / 256;
  int mtiles = (N_NODES + GTM - 1) / GTM;
  int mtiles2 = (N_NODES + DTM - 1) / DTM;

  // CSR build (by dst, self-loops first in each row)
  init_counts_kernel<<<nblkN, 256, 0, stream>>>(cnt);
  count_edges_kernel<<<nblkE, 256, 0, stream>>>(dst, cnt);
  scan_blocks_kernel<<<nblkN, 256, 0, stream>>>(cnt, partial, bsums, N_NODES);
  scan_sums_kernel<<<1, 256, 0, stream>>>(bsums, nblkN);
  scan_write_kernel<<<nblkN, 256, 0, stream>>>(partial, bsums, rowp, N_NODES);
  fill_self_kernel<<<nblkN, 256, 0, stream>>>(rowp, col, cnt);
  fill_edges_kernel<<<nblkE, 256, 0, stream>>>(src, dst, cnt, col);

  // casts
  {
    int maxn4 = LAYERS * H * H / 4;
    dim3 gcast((maxn4 + 255) / 256, 4);
    cast_weights_kernel<<<gcast, 256, 0, stream>>>(W_in, Wg1, Wl, Wr,
                                                   win_h, wg1_h, wl_h, wr_h);
    int n4 = N_NODES * IN_DIM / 4;
    cast_f16_kernel<<<(n4 + 255) / 256, 256, 0, stream>>>(x_in, xin_h, n4);
  }

  // input projection -> x_h
  dim3 gproj(2, mtiles);
  gemm_proj_kernel<<<gproj, 256, 0, stream>>>(xin_h, win_h, b_in, x_h, N_NODES, IN_DIM);

  int nblkV = N_NODES / 4;
  dim3 gdual(4, mtiles2);
  for (int l = 0; l < LAYERS; l++) {
    gemm_dual3_kernel<<<gdual, 256, 0, stream>>>(x_h,
        wl_h + (size_t)l * H * H, wr_h + (size_t)l * H * H,
        bl + l * H, br + l * H, xl_h, xr_h, N_NODES);
    layer_fused_kernel<<<nblkV, 256, 0, stream>>>(xl_h, xr_h, x_h, rowp, col,
        att + l * H, bias_c + l * H, ln_g + l * H, ln_b + l * H);
  }

  // gate (fused GEMM + row-dot); gate_init also computes graph bounds
  gate_init_kernel<<<nblkN, 256, 0, stream>>>(gate, bg2, batch, gstart, gend);
  dim3 ggate(2, mtiles2);
  gemm_gate2_kernel<<<ggate, 256, 0, stream>>>(x_h, wg1_h, bg1, Wg2, gate, N_NODES);

  // pooling
  pool_prep_kernel<<<NGRAPH, 256, 0, stream>>>(gate, gstart, gend, gmax, gdinv, pooled);
  pool_accum_kernel<<<(N_NODES + 63) / 64, 256, 0, stream>>>(gate, x_h, batch, gmax, gdinv, pooled);

  // fused heads
  head_kernel<<<NGRAPH, 256, 0, stream>>>(pooled, Ws, bs, Wc, bc, Wr1, br1, Wr2, br2, out);
}

// Round 18
// 561.544 us; speedup vs baseline: 1.4629x; 1.0068x over previous
//
#include <hip/hip_runtime.h>
#include <math.h>

#define N_NODES 50000
#define N_EDGES 300000
#define IN_DIM 64
#define H 256
#define LAYERS 4
#define NB 181
#define NGRAPH 64
#define EE (N_EDGES + N_NODES)
#define NEG_SLOPE 0.2f
#define LN_EPS 1e-5f

typedef unsigned short u16;
typedef __attribute__((ext_vector_type(8))) _Float16 half8;
typedef __attribute__((ext_vector_type(4))) float floatx4;

__device__ __forceinline__ u16 f2h(float f) {
  _Float16 h = (_Float16)f;
  return __builtin_bit_cast(u16, h);
}
__device__ __forceinline__ float h2f(u16 b) {
  return (float)__builtin_bit_cast(_Float16, b);
}

__device__ __forceinline__ float wave_reduce_sum(float v) {
  #pragma unroll
  for (int off = 32; off > 0; off >>= 1) v += __shfl_xor(v, off, 64);
  return v;
}

// ---------------- weight casts (Wg1, Wl, Wr) ----------------
__global__ void cast_weights_kernel(
    const float* __restrict__ Wg1,
    const float* __restrict__ Wl, const float* __restrict__ Wr,
    u16* __restrict__ wg1_h, u16* __restrict__ wl_h, u16* __restrict__ wr_h)
{
  int i = blockIdx.x * 256 + threadIdx.x;
  int which = blockIdx.y;
  const float* s; u16* dd; int n4;
  if (which == 0)      { s = Wg1;  dd = wg1_h; n4 = H * H / 4; }
  else if (which == 1) { s = Wl;   dd = wl_h;  n4 = LAYERS * H * H / 4; }
  else                 { s = Wr;   dd = wr_h;  n4 = LAYERS * H * H / 4; }
  if (i < n4) {
    float4 f = ((const float4*)s)[i];
    ushort4 o;
    o.x = f2h(f.x); o.y = f2h(f.y); o.z = f2h(f.z); o.w = f2h(f.w);
    ((ushort4*)dd)[i] = o;
  }
}

// ---------------- CSR build + gate/graph-bounds init (merged) ----------------
__global__ void init_kernel(int* __restrict__ cnt,
                            float* __restrict__ gate, const float* __restrict__ bg2,
                            const int* __restrict__ batch,
                            int* __restrict__ gstart, int* __restrict__ gend) {
  int i = blockIdx.x * 256 + threadIdx.x;
  if (i < N_NODES) {
    cnt[i] = 1;  // self loop
    gate[i] = bg2[0];
    int b = batch[i];
    if (i == 0 || batch[i - 1] != b) gstart[b] = i;
    if (i == N_NODES - 1 || batch[i + 1] != b) gend[b] = i + 1;
  }
}

__global__ void count_edges_kernel(const int* __restrict__ dst, int* __restrict__ cnt) {
  int e = blockIdx.x * 256 + threadIdx.x;
  if (e < N_EDGES) atomicAdd(&cnt[dst[e]], 1);
}

__global__ void scan_blocks_kernel(const int* __restrict__ cnt, int* __restrict__ partial,
                                   int* __restrict__ bsums, int n) {
  __shared__ int buf[256];
  int tid = threadIdx.x;
  int i = blockIdx.x * 256 + tid;
  buf[tid] = (i < n) ? cnt[i] : 0;
  __syncthreads();
  #pragma unroll
  for (int off = 1; off < 256; off <<= 1) {
    int t = (tid >= off) ? buf[tid - off] : 0;
    __syncthreads();
    buf[tid] += t;
    __syncthreads();
  }
  if (i < n) partial[i] = buf[tid];
  if (tid == 255) bsums[blockIdx.x] = buf[255];
}

__global__ void scan_sums_kernel(int* __restrict__ bsums, int nblk) {
  __shared__ int buf[256];
  int tid = threadIdx.x;
  buf[tid] = (tid < nblk) ? bsums[tid] : 0;
  __syncthreads();
  #pragma unroll
  for (int off = 1; off < 256; off <<= 1) {
    int t = (tid >= off) ? buf[tid - off] : 0;
    __syncthreads();
    buf[tid] += t;
    __syncthreads();
  }
  if (tid < nblk) bsums[tid] = buf[tid];
}

// writes rowp AND the self-loop entry + fillpos (fill_self merged: rowp[i] = rowp[i+1]-cnt[i])
__global__ void scan_write_kernel(const int* __restrict__ partial, const int* __restrict__ bsums,
                                  const int* __restrict__ cnt,
                                  int* __restrict__ rowp, int* __restrict__ col,
                                  int* __restrict__ fillpos, int n) {
  int i = blockIdx.x * 256 + threadIdx.x;
  if (i < n) {
    int b = blockIdx.x;
    int off = (b > 0) ? bsums[b - 1] : 0;
    int r1 = partial[i] + off;
    rowp[i + 1] = r1;
    if (i == 0) rowp[0] = 0;
    int p = r1 - cnt[i];   // == rowp[i]
    col[p] = i;            // self loop FIRST in each row (layer_fused relies on this)
    fillpos[i] = p + 1;
  }
}

__global__ void fill_edges_kernel(const int* __restrict__ src, const int* __restrict__ dst,
                                  int* __restrict__ fillpos, int* __restrict__ col) {
  int e = blockIdx.x * 256 + threadIdx.x;
  if (e < N_EDGES) {
    int d = dst[e];
    int p = atomicAdd(&fillpos[d], 1);
    col[p] = src[e];
  }
}

// ---------------- MFMA GEMM tiles ----------------
#define GTM 128
#define GTK 64
#define LDB 72
#define SSTR 132

// input projection with fused fp32->fp16 cast of A and W (K = 64 = one chunk)
__global__ __launch_bounds__(256) void gemm_proj_kernel(
    const float* __restrict__ A, const float* __restrict__ W,
    const float* __restrict__ bias, u16* __restrict__ outh, int M)
{
  __shared__ u16 smem[2 * GTM * LDB];
  u16* As = smem;
  u16* Bs = smem + GTM * LDB;
  int tid = threadIdx.x;
  int lane = tid & 63;
  int wave = tid >> 6;
  int wm = (wave >> 1) * 64;
  int wn = (wave & 1) * 64;
  int bm = blockIdx.y * GTM;
  int n0 = blockIdx.x * 128;

  floatx4 zero4 = {0.f, 0.f, 0.f, 0.f};
  floatx4 acc[4][4];
  #pragma unroll
  for (int i = 0; i < 4; i++)
    #pragma unroll
    for (int j = 0; j < 4; j++) acc[i][j] = zero4;

  int q8 = (lane >> 4) * 8;
  int mrow = lane & 15;

  // stage (cast in-register): 128 rows x 64 cols, fp32 source
  {
    int r0 = tid >> 4;          // 0..15
    int c4 = (tid & 15) * 4;    // 0..60
    #pragma unroll
    for (int p = 0; p < 8; p++) {
      int row = r0 + p * 16;
      int gr = bm + row;
      float4 av = {0.f, 0.f, 0.f, 0.f};
      if (gr < M) av = *(const float4*)&A[(size_t)gr * IN_DIM + c4];
      ushort4 oa;
      oa.x = f2h(av.x); oa.y = f2h(av.y); oa.z = f2h(av.z); oa.w = f2h(av.w);
      *(ushort4*)&As[row * LDB + c4] = oa;
      float4 bv = *(const float4*)&W[(size_t)(n0 + row) * IN_DIM + c4];
      ushort4 ob;
      ob.x = f2h(bv.x); ob.y = f2h(bv.y); ob.z = f2h(bv.z); ob.w = f2h(bv.w);
      *(ushort4*)&Bs[row * LDB + c4] = ob;
    }
  }
  __syncthreads();
  #pragma unroll
  for (int h = 0; h < 2; h++) {
    half8 af[4], bf[4];
    #pragma unroll
    for (int i = 0; i < 4; i++)
      af[i] = *(const half8*)&As[(wm + i * 16 + mrow) * LDB + h * 32 + q8];
    #pragma unroll
    for (int j = 0; j < 4; j++)
      bf[j] = *(const half8*)&Bs[(wn + j * 16 + mrow) * LDB + h * 32 + q8];
    #pragma unroll
    for (int i = 0; i < 4; i++)
      #pragma unroll
      for (int j = 0; j < 4; j++)
        acc[i][j] = __builtin_amdgcn_mfma_f32_16x16x32_f16(af[i], bf[j], acc[i][j], 0, 0, 0);
  }

  __syncthreads();
  u16* stage = smem;
  int ccol = lane & 15;
  int crow4 = (lane >> 4) * 4;
  #pragma unroll
  for (int j = 0; j < 4; j++) {
    float bv = bias[n0 + wn + j * 16 + ccol];
    #pragma unroll
    for (int i = 0; i < 4; i++) {
      #pragma unroll
      for (int r = 0; r < 4; r++) {
        int row = wm + i * 16 + crow4 + r;
        stage[row * SSTR + wn + j * 16 + ccol] = f2h(acc[i][j][r] + bv);
      }
    }
  }
  __syncthreads();
  int rr = tid >> 1;
  int c0 = (tid & 1) * 64;
  int grow = bm + rr;
  if (grow < M) {
    const ushort4* sp = (const ushort4*)&stage[rr * SSTR + c0];
    ushort4* gp = (ushort4*)&outh[(size_t)grow * H + n0 + c0];
    #pragma unroll
    for (int q = 0; q < 16; q++) gp[q] = sp[q];
  }
}

// ---------------- dual GEMM v5: one n-tile per block, 64-row m-tiles, 27.6 KB LDS ----------------
#define DTM 64
#define SSTR2 132

__global__ __launch_bounds__(256) void gemm_dual3_kernel(
    const u16* __restrict__ A, const u16* __restrict__ Wlb, const u16* __restrict__ Wrb,
    const float* __restrict__ biasL, const float* __restrict__ biasR,
    u16* __restrict__ outL, u16* __restrict__ outR, int M)
{
  __shared__ u16 As[DTM * LDB];
  __shared__ u16 Bs[128 * LDB];
  int tid = threadIdx.x;
  int lane = tid & 63;
  int wave = tid >> 6;
  int wn = wave * 32;
  int nt = blockIdx.x;
  int bm = blockIdx.y * DTM;
  const u16* W = (nt < 2) ? Wlb : Wrb;
  const float* bias = (nt < 2) ? biasL : biasR;
  u16* outp = (nt < 2) ? outL : outR;
  int n0 = (nt & 1) * 128;
  int mrow = lane & 15;
  int q8 = (lane >> 4) * 8;
  int ccol = lane & 15;
  int crow4 = (lane >> 4) * 4;
  int lr = tid >> 3;
  int lc = (tid & 7) * 8;

  floatx4 zero4 = {0.f, 0.f, 0.f, 0.f};
  floatx4 acc[4][2];
  #pragma unroll
  for (int i = 0; i < 4; i++) {
    acc[i][0] = zero4;
    acc[i][1] = zero4;
  }

  for (int k0 = 0; k0 < H; k0 += 64) {
    __syncthreads();
    #pragma unroll
    for (int p = 0; p < 2; p++) {
      int row = lr + p * 32;
      int gr = bm + row;
      uint4 av = {0, 0, 0, 0};
      if (gr < M) av = *(const uint4*)&A[(size_t)gr * H + k0 + lc];
      *(uint4*)&As[row * LDB + lc] = av;
    }
    #pragma unroll
    for (int p = 0; p < 4; p++) {
      int row = lr + p * 32;
      uint4 bv = *(const uint4*)&W[(size_t)(n0 + row) * H + k0 + lc];
      *(uint4*)&Bs[row * LDB + lc] = bv;
    }
    __syncthreads();
    #pragma unroll
    for (int h = 0; h < 2; h++) {
      half8 af[4], bf[2];
      #pragma unroll
      for (int i = 0; i < 4; i++)
        af[i] = *(const half8*)&As[(i * 16 + mrow) * LDB + h * 32 + q8];
      #pragma unroll
      for (int j = 0; j < 2; j++)
        bf[j] = *(const half8*)&Bs[(wn + j * 16 + mrow) * LDB + h * 32 + q8];
      #pragma unroll
      for (int i = 0; i < 4; i++)
        #pragma unroll
        for (int j = 0; j < 2; j++)
          acc[i][j] = __builtin_amdgcn_mfma_f32_16x16x32_f16(af[i], bf[j], acc[i][j], 0, 0, 0);
    }
  }

  __syncthreads();
  u16* stage = Bs;
  #pragma unroll
  for (int j = 0; j < 2; j++) {
    float bv = bias[n0 + wn + j * 16 + ccol];
    #pragma unroll
    for (int i = 0; i < 4; i++) {
      #pragma unroll
      for (int r = 0; r < 4; r++) {
        int row = i * 16 + crow4 + r;
        stage[row * SSTR2 + wn + j * 16 + ccol] = f2h(acc[i][j][r] + bv);
      }
    }
  }
  __syncthreads();
  #pragma unroll
  for (int pass = 0; pass < 4; pass++) {
    int row = pass * 16 + (tid >> 4);
    int cu = (tid & 15) * 8;
    int grow = bm + row;
    if (grow < M) {
      *(uint4*)&outp[(size_t)grow * H + n0 + cu] =
          *(const uint4*)&stage[row * SSTR2 + cu];
    }
  }
}

// ---------------- gate GEMM v2: dual3-style 64-row m-tiles, 128-col n-tile per block ----------------
__global__ __launch_bounds__(256) void gemm_gate2_kernel(
    const u16* __restrict__ A, const u16* __restrict__ W,
    const float* __restrict__ bias, const float* __restrict__ Wg2,
    float* __restrict__ gate, int M)
{
  __shared__ u16 As[DTM * LDB];
  __shared__ u16 Bs[128 * LDB];
  int tid = threadIdx.x;
  int lane = tid & 63;
  int wave = tid >> 6;
  int wn = wave * 32;
  int n0 = blockIdx.x * 128;
  int bm = blockIdx.y * DTM;
  int mrow = lane & 15;
  int q8 = (lane >> 4) * 8;
  int ccol = lane & 15;
  int crow4 = (lane >> 4) * 4;
  int lr = tid >> 3;
  int lc = (tid & 7) * 8;

  floatx4 zero4 = {0.f, 0.f, 0.f, 0.f};
  floatx4 acc[4][2];
  #pragma unroll
  for (int i = 0; i < 4; i++) {
    acc[i][0] = zero4;
    acc[i][1] = zero4;
  }

  for (int k0 = 0; k0 < H; k0 += 64) {
    __syncthreads();
    #pragma unroll
    for (int p = 0; p < 2; p++) {
      int row = lr + p * 32;
      int gr = bm + row;
      uint4 av = {0, 0, 0, 0};
      if (gr < M) av = *(const uint4*)&A[(size_t)gr * H + k0 + lc];
      *(uint4*)&As[row * LDB + lc] = av;
    }
    #pragma unroll
    for (int p = 0; p < 4; p++) {
      int row = lr + p * 32;
      uint4 bv = *(const uint4*)&W[(size_t)(n0 + row) * H + k0 + lc];
      *(uint4*)&Bs[row * LDB + lc] = bv;
    }
    __syncthreads();
    #pragma unroll
    for (int h = 0; h < 2; h++) {
      half8 af[4], bf[2];
      #pragma unroll
      for (int i = 0; i < 4; i++)
        af[i] = *(const half8*)&As[(i * 16 + mrow) * LDB + h * 32 + q8];
      #pragma unroll
      for (int j = 0; j < 2; j++)
        bf[j] = *(const half8*)&Bs[(wn + j * 16 + mrow) * LDB + h * 32 + q8];
      #pragma unroll
      for (int i = 0; i < 4; i++)
        #pragma unroll
        for (int j = 0; j < 2; j++)
          acc[i][j] = __builtin_amdgcn_mfma_f32_16x16x32_f16(af[i], bf[j], acc[i][j], 0, 0, 0);
    }
  }

  float bv[2], wv[2];
  #pragma unroll
  for (int j = 0; j < 2; j++) {
    int c = n0 + wn + j * 16 + ccol;
    bv[j] = bias[c];
    wv[j] = Wg2[c];
  }
  #pragma unroll
  for (int i = 0; i < 4; i++) {
    #pragma unroll
    for (int r = 0; r < 4; r++) {
      float p = fmaxf(acc[i][0][r] + bv[0], 0.f) * wv[0]
              + fmaxf(acc[i][1][r] + bv[1], 0.f) * wv[1];
      p += __shfl_xor(p, 1, 64);
      p += __shfl_xor(p, 2, 64);
      p += __shfl_xor(p, 4, 64);
      p += __shfl_xor(p, 8, 64);
      int row = bm + i * 16 + crow4 + r;
      if ((lane & 15) == 0 && row < M) atomicAdd(&gate[row], p);
    }
  }
}

// ---------------- fused edge softmax + aggregate + LN + residual ----------------
// Self-edge-anchored softmax + mask-free unroll-4 main loop (commutative body).
__global__ __launch_bounds__(256) void layer_fused_kernel(
    const u16* __restrict__ xl, const u16* __restrict__ xr,
    u16* __restrict__ xst,
    const int* __restrict__ rowp, const int* __restrict__ col,
    const float* __restrict__ att, const float* __restrict__ bias_c,
    const float* __restrict__ ln_g, const float* __restrict__ ln_b)
{
  int lane = threadIdx.x & 63;
  int v = blockIdx.x * 4 + (threadIdx.x >> 6);
  if (v >= N_NODES) return;
  int f4 = lane << 2;
  size_t rowbase = (size_t)v * H;
  ushort4 xr4 = *(const ushort4*)&xr[rowbase + f4];
  float xrx = h2f(xr4.x), xry = h2f(xr4.y), xrz = h2f(xr4.z), xrw = h2f(xr4.w);
  float4 attv = *(const float4*)&att[f4];
  int beg = rowp[v], end = rowp[v + 1];

  float sx, sy, sz, sw, m;
  {
    ushort4 a04 = *(const ushort4*)&xl[rowbase + f4];
    sx = h2f(a04.x); sy = h2f(a04.y); sz = h2f(a04.z); sw = h2f(a04.w);
    float t0x = sx + xrx; t0x = t0x > 0.f ? t0x : NEG_SLOPE * t0x;
    float t0y = sy + xry; t0y = t0y > 0.f ? t0y : NEG_SLOPE * t0y;
    float t0z = sz + xrz; t0z = t0z > 0.f ? t0z : NEG_SLOPE * t0z;
    float t0w = sw + xrw; t0w = t0w > 0.f ? t0w : NEG_SLOPE * t0w;
    float pe = t0x * attv.x + t0y * attv.y + t0z * attv.z + t0w * attv.w;
    m = wave_reduce_sum(pe);
  }
  float d = 1.0f;
  float ox = sx, oy = sy, oz = sz, ow = sw;

  int p = beg + 1;
  for (; p + 4 <= end; p += 4) {
    int u0 = col[p];
    int u1 = col[p + 1];
    int u2 = col[p + 2];
    int u3 = col[p + 3];
    ushort4 A0 = *(const ushort4*)&xl[(size_t)u0 * H + f4];
    ushort4 A1 = *(const ushort4*)&xl[(size_t)u1 * H + f4];
    ushort4 A2 = *(const ushort4*)&xl[(size_t)u2 * H + f4];
    ushort4 A3 = *(const ushort4*)&xl[(size_t)u3 * H + f4];
    float a0x = h2f(A0.x), a0y = h2f(A0.y), a0z = h2f(A0.z), a0w = h2f(A0.w);
    float a1x = h2f(A1.x), a1y = h2f(A1.y), a1z = h2f(A1.z), a1w = h2f(A1.w);
    float a2x = h2f(A2.x), a2y = h2f(A2.y), a2z = h2f(A2.z), a2w = h2f(A2.w);
    float a3x = h2f(A3.x), a3y = h2f(A3.y), a3z = h2f(A3.z), a3w = h2f(A3.w);
    float t, pe0, pe1, pe2, pe3;
    t = a0x + xrx; t = t > 0.f ? t : NEG_SLOPE * t; pe0 = t * attv.x;
    t = a0y + xry; t = t > 0.f ? t : NEG_SLOPE * t; pe0 = fmaf(t, attv.y, pe0);
    t = a0z + xrz; t = t > 0.f ? t : NEG_SLOPE * t; pe0 = fmaf(t, attv.z, pe0);
    t = a0w + xrw; t = t > 0.f ? t : NEG_SLOPE * t; pe0 = fmaf(t, attv.w, pe0);
    t = a1x + xrx; t = t > 0.f ? t : NEG_SLOPE * t; pe1 = t * attv.x;
    t = a1y + xry; t = t > 0.f ? t : NEG_SLOPE * t; pe1 = fmaf(t, attv.y, pe1);
    t = a1z + xrz; t = t > 0.f ? t : NEG_SLOPE * t; pe1 = fmaf(t, attv.z, pe1);
    t = a1w + xrw; t = t > 0.f ? t : NEG_SLOPE * t; pe1 = fmaf(t, attv.w, pe1);
    t = a2x + xrx; t = t > 0.f ? t : NEG_SLOPE * t; pe2 = t * attv.x;
    t = a2y + xry; t = t > 0.f ? t : NEG_SLOPE * t; pe2 = fmaf(t, attv.y, pe2);
    t = a2z + xrz; t = t > 0.f ? t : NEG_SLOPE * t; pe2 = fmaf(t, attv.z, pe2);
    t = a2w + xrw; t = t > 0.f ? t : NEG_SLOPE * t; pe2 = fmaf(t, attv.w, pe2);
    t = a3x + xrx; t = t > 0.f ? t : NEG_SLOPE * t; pe3 = t * attv.x;
    t = a3y + xry; t = t > 0.f ? t : NEG_SLOPE * t; pe3 = fmaf(t, attv.y, pe3);
    t = a3z + xrz; t = t > 0.f ? t : NEG_SLOPE * t; pe3 = fmaf(t, attv.z, pe3);
    t = a3w + xrw; t = t > 0.f ? t : NEG_SLOPE * t; pe3 = fmaf(t, attv.w, pe3);
    #pragma unroll
    for (int off = 32; off > 0; off >>= 1) {
      pe0 += __shfl_xor(pe0, off, 64);
      pe1 += __shfl_xor(pe1, off, 64);
      pe2 += __shfl_xor(pe2, off, 64);
      pe3 += __shfl_xor(pe3, off, 64);
    }
    float w0 = __expf(pe0 - m);
    float w1 = __expf(pe1 - m);
    float w2 = __expf(pe2 - m);
    float w3 = __expf(pe3 - m);
    d += (w0 + w1) + (w2 + w3);
    ox = fmaf(w0, a0x, fmaf(w1, a1x, fmaf(w2, a2x, fmaf(w3, a3x, ox))));
    oy = fmaf(w0, a0y, fmaf(w1, a1y, fmaf(w2, a2y, fmaf(w3, a3y, oy))));
    oz = fmaf(w0, a0z, fmaf(w1, a1z, fmaf(w2, a2z, fmaf(w3, a3z, oz))));
    ow = fmaf(w0, a0w, fmaf(w1, a1w, fmaf(w2, a2w, fmaf(w3, a3w, ow))));
  }
  for (; p < end; p++) {
    int u0 = col[p];
    ushort4 a04 = *(const ushort4*)&xl[(size_t)u0 * H + f4];
    float a0x = h2f(a04.x), a0y = h2f(a04.y), a0z = h2f(a04.z), a0w = h2f(a04.w);
    float t0x = a0x + xrx; t0x = t0x > 0.f ? t0x : NEG_SLOPE * t0x;
    float t0y = a0y + xry; t0y = t0y > 0.f ? t0y : NEG_SLOPE * t0y;
    float t0z = a0z + xrz; t0z = t0z > 0.f ? t0z : NEG_SLOPE * t0z;
    float t0w = a0w + xrw; t0w = t0w > 0.f ? t0w : NEG_SLOPE * t0w;
    float pe0 = t0x * attv.x + t0y * attv.y + t0z * attv.z + t0w * attv.w;
    pe0 = wave_reduce_sum(pe0);
    float w0 = __expf(pe0 - m);
    d += w0;
    ox = fmaf(w0, a0x, ox);
    oy = fmaf(w0, a0y, oy);
    oz = fmaf(w0, a0z, oz);
    ow = fmaf(w0, a0w, ow);
  }
  float invd = 1.0f / d;
  float4 bc4 = *(const float4*)&bias_c[f4];
  ox = ox * invd + bc4.x;
  oy = oy * invd + bc4.y;
  oz = oz * invd + bc4.z;
  ow = ow * invd + bc4.w;
  float s = wave_reduce_sum(ox + oy + oz + ow);
  float mean = s * (1.0f / H);
  float cx = ox - mean, cy = oy - mean, cz = oz - mean, cw = ow - mean;
  float sq = wave_reduce_sum(cx * cx + cy * cy + cz * cz + cw * cw);
  float rstd = rsqrtf(sq * (1.0f / H) + LN_EPS);
  float4 g4 = *(const float4*)&ln_g[f4];
  float4 b4 = *(const float4*)&ln_b[f4];
  ushort4 xres4 = *(const ushort4*)&xst[rowbase + f4];
  float yx = fmaxf(fmaf(cx * rstd, g4.x, b4.x), 0.f) + h2f(xres4.x);
  float yy = fmaxf(fmaf(cy * rstd, g4.y, b4.y), 0.f) + h2f(xres4.y);
  float yz = fmaxf(fmaf(cz * rstd, g4.z, b4.z), 0.f) + h2f(xres4.z);
  float yw = fmaxf(fmaf(cw * rstd, g4.w, b4.w), 0.f) + h2f(xres4.w);
  ushort4 yb;
  yb.x = f2h(yx); yb.y = f2h(yy); yb.z = f2h(yz); yb.w = f2h(yw);
  *(ushort4*)&xst[rowbase + f4] = yb;
}

// ---------------- pooling: per-graph softmax stats (+ pooled zero) ----------------
__global__ __launch_bounds__(256) void pool_prep_kernel(
    const float* __restrict__ gate, const int* __restrict__ gstart,
    const int* __restrict__ gend, float* __restrict__ gmax, float* __restrict__ gdinv,
    float* __restrict__ pooled)
{
  __shared__ float red[256];
  int g = blockIdx.x, tid = threadIdx.x;
  pooled[(size_t)g * H + tid] = 0.f;
  int s = gstart[g], e = gend[g];
  float lm = -INFINITY;
  for (int i = s + tid; i < e; i += 256) lm = fmaxf(lm, gate[i]);
  red[tid] = lm;
  __syncthreads();
  for (int off = 128; off; off >>= 1) {
    if (tid < off) red[tid] = fmaxf(red[tid], red[tid + off]);
    __syncthreads();
  }
  float m = red[0];
  __syncthreads();
  float lsum = 0.0f;
  for (int i = s + tid; i < e; i += 256) lsum += __expf(gate[i] - m);
  red[tid] = lsum;
  __syncthreads();
  for (int off = 128; off; off >>= 1) {
    if (tid < off) red[tid] += red[tid + off];
    __syncthreads();
  }
  if (tid == 0) {
    gmax[g] = m;
    gdinv[g] = (s < e) ? 1.0f / red[0] : 0.0f;
  }
}

// ---------------- pooling: weighted accumulate (64 nodes per block, fp16 x) ----------------
__global__ __launch_bounds__(256) void pool_accum_kernel(
    const float* __restrict__ gate, const u16* __restrict__ xh,
    const int* __restrict__ batch, const float* __restrict__ gmax,
    const float* __restrict__ gdinv, float* __restrict__ pooled)
{
  __shared__ float wl[64];
  __shared__ int gl[64];
  int b0 = blockIdx.x * 64;
  int tid = threadIdx.x;
  if (tid < 64) {
    int v = b0 + tid;
    if (v < N_NODES) {
      int g = batch[v];
      gl[tid] = g;
      wl[tid] = __expf(gate[v] - gmax[g]) * gdinv[g];
    } else {
      gl[tid] = -1;
      wl[tid] = 0.f;
    }
  }
  __syncthreads();
  int cnt = min(64, N_NODES - b0);
  float acc = 0.f;
  int cur = gl[0];
  for (int j = 0; j < cnt; j++) {
    int g = gl[j];
    if (g != cur) {
      atomicAdd(&pooled[(size_t)cur * H + tid], acc);
      acc = 0.f;
      cur = g;
    }
    acc += wl[j] * h2f(xh[(size_t)(b0 + j) * H + tid]);
  }
  if (cur >= 0) atomicAdd(&pooled[(size_t)cur * H + tid], acc);
}

// ---------------- fused head: pooled -> z -> {cls, r1} -> residual ----------------
__global__ __launch_bounds__(256) void head_kernel(
    const float* __restrict__ pooled,
    const float* __restrict__ Ws, const float* __restrict__ bs,
    const float* __restrict__ Wc, const float* __restrict__ bc,
    const float* __restrict__ Wr1, const float* __restrict__ br1,
    const float* __restrict__ Wr2, const float* __restrict__ br2,
    float* __restrict__ out)
{
  __shared__ float psh[256];
  __shared__ float zsh[256];
  __shared__ float r1sh[128];
  int g = blockIdx.x, tid = threadIdx.x;
  psh[tid] = pooled[(size_t)g * H + tid];
  __syncthreads();
  {
    float acc = bs[tid];
    const float4* wr = (const float4*)&Ws[(size_t)tid * H];
    for (int k4 = 0; k4 < H / 4; k4++) {
      float4 wv = wr[k4];
      float4 av = *(const float4*)&psh[k4 * 4];
      acc += av.x * wv.x + av.y * wv.y + av.z * wv.z + av.w * wv.w;
    }
    zsh[tid] = fmaxf(acc, 0.f);
  }
  __syncthreads();
  if (tid < NB) {
    float acc = bc[tid];
    const float4* wr = (const float4*)&Wc[(size_t)tid * H];
    for (int k4 = 0; k4 < H / 4; k4++) {
      float4 wv = wr[k4];
      float4 av = *(const float4*)&zsh[k4 * 4];
      acc += av.x * wv.x + av.y * wv.y + av.z * wv.z + av.w * wv.w;
    }
    out[(size_t)g * NB + tid] = acc;
  }
  if (tid < 128) {
    float acc = br1[tid];
    const float4* wr = (const float4*)&Wr1[(size_t)tid * H];
    for (int k4 = 0; k4 < H / 4; k4++) {
      float4 wv = wr[k4];
      float4 av = *(const float4*)&zsh[k4 * 4];
      acc += av.x * wv.x + av.y * wv.y + av.z * wv.z + av.w * wv.w;
    }
    r1sh[tid] = fmaxf(acc, 0.f);
  }
  __syncthreads();
  if (tid < 64) {
    float s2 = r1sh[tid] * Wr2[tid] + r1sh[tid + 64] * Wr2[tid + 64];
    s2 = wave_reduce_sum(s2);
    if (tid == 0) out[(size_t)NGRAPH * NB + g] = tanhf(s2 + br2[0]);
  }
}

// ---------------- launcher ----------------
extern "C" void kernel_launch(void* const* d_in, const int* in_sizes, int n_in,
                              void* d_out, int out_size, void* d_ws, size_t ws_size,
                              hipStream_t stream) {
  const float* x_in   = (const float*)d_in[0];
  const int*   eidx   = (const int*)d_in[1];
  const int*   batch  = (const int*)d_in[2];
  const float* W_in   = (const float*)d_in[3];
  const float* b_in   = (const float*)d_in[4];
  const float* Wl     = (const float*)d_in[5];
  const float* bl     = (const float*)d_in[6];
  const float* Wr     = (const float*)d_in[7];
  const float* br     = (const float*)d_in[8];
  const float* att    = (const float*)d_in[9];
  const float* bias_c = (const float*)d_in[10];
  const float* ln_g   = (const float*)d_in[11];
  const float* ln_b   = (const float*)d_in[12];
  const float* Wg1    = (const float*)d_in[13];
  const float* bg1    = (const float*)d_in[14];
  const float* Wg2    = (const float*)d_in[15];
  const float* bg2    = (const float*)d_in[16];
  const float* Ws     = (const float*)d_in[17];
  const float* bs     = (const float*)d_in[18];
  const float* Wc     = (const float*)d_in[19];
  const float* bc     = (const float*)d_in[20];
  const float* Wr1    = (const float*)d_in[21];
  const float* br1    = (const float*)d_in[22];
  const float* Wr2    = (const float*)d_in[23];
  const float* br2    = (const float*)d_in[24];
  float* out = (float*)d_out;

  char* w = (char*)d_ws;
  u16* x_h    = (u16*)w;    w += sizeof(u16) * (size_t)N_NODES * H;
  u16* xl_h   = (u16*)w;    w += sizeof(u16) * (size_t)N_NODES * H;
  u16* xr_h   = (u16*)w;    w += sizeof(u16) * (size_t)N_NODES * H;
  u16* wl_h   = (u16*)w;    w += sizeof(u16) * (size_t)LAYERS * H * H;
  u16* wr_h   = (u16*)w;    w += sizeof(u16) * (size_t)LAYERS * H * H;
  u16* wg1_h  = (u16*)w;    w += sizeof(u16) * (size_t)H * H;
  float* pooled = (float*)w; w += sizeof(float) * NGRAPH * H;
  float* gate = (float*)w;  w += sizeof(float) * N_NODES;
  float* gmax = (float*)w;  w += sizeof(float) * NGRAPH;
  float* gdinv= (float*)w;  w += sizeof(float) * NGRAPH;
  int* cnt    = (int*)w;    w += sizeof(int) * N_NODES;
  int* rowp   = (int*)w;    w += sizeof(int) * (N_NODES + 1);
  int* col    = (int*)w;    w += sizeof(int) * EE;
  int* partial= (int*)w;    w += sizeof(int) * N_NODES;
  int* bsums  = (int*)w;    w += sizeof(int) * 256;
  int* gstart = (int*)w;    w += sizeof(int) * NGRAPH;
  int* gend   = (int*)w;    w += sizeof(int) * NGRAPH;
  (void)ws_size; (void)n_in; (void)in_sizes; (void)out_size;

  const int* src = eidx;
  const int* dst = eidx + N_EDGES;
  int nblkN = (N_NODES + 255) / 256;
  int nblkE = (N_EDGES + 255) / 256;
  int mtiles = (N_NODES + GTM - 1) / GTM;
  int mtiles2 = (N_NODES + DTM - 1) / DTM;

  // CSR build + gate/bounds init (merged), self-loop entry written during scan_write
  init_kernel<<<nblkN, 256, 0, stream>>>(cnt, gate, bg2, batch, gstart, gend);
  count_edges_kernel<<<nblkE, 256, 0, stream>>>(dst, cnt);
  scan_blocks_kernel<<<nblkN, 256, 0, stream>>>(cnt, partial, bsums, N_NODES);
  scan_sums_kernel<<<1, 256, 0, stream>>>(bsums, nblkN);
  scan_write_kernel<<<nblkN, 256, 0, stream>>>(partial, bsums, cnt, rowp, col, cnt, N_NODES);
  fill_edges_kernel<<<nblkE, 256, 0, stream>>>(src, dst, cnt, col);

  // weight casts (x_in cast fused into proj)
  {
    int maxn4 = LAYERS * H * H / 4;
    dim3 gcast((maxn4 + 255) / 256, 3);
    cast_weights_kernel<<<gcast, 256, 0, stream>>>(Wg1, Wl, Wr, wg1_h, wl_h, wr_h);
  }

  // input projection (fp32 inputs, fused cast) -> x_h
  dim3 gproj(2, mtiles);
  gemm_proj_kernel<<<gproj, 256, 0, stream>>>(x_in, W_in, b_in, x_h, N_NODES);

  int nblkV = N_NODES / 4;
  dim3 gdual(4, mtiles2);
  for (int l = 0; l < LAYERS; l++) {
    gemm_dual3_kernel<<<gdual, 256, 0, stream>>>(x_h,
        wl_h + (size_t)l * H * H, wr_h + (size_t)l * H * H,
        bl + l * H, br + l * H, xl_h, xr_h, N_NODES);
    layer_fused_kernel<<<nblkV, 256, 0, stream>>>(xl_h, xr_h, x_h, rowp, col,
        att + l * H, bias_c + l * H, ln_g + l * H, ln_b + l * H);
  }

  // gate (fused GEMM + row-dot); gate pre-initialized by init_kernel
  dim3 ggate(2, mtiles2);
  gemm_gate2_kernel<<<ggate, 256, 0, stream>>>(x_h, wg1_h, bg1, Wg2, gate, N_NODES);

  // pooling
  pool_prep_kernel<<<NGRAPH, 256, 0, stream>>>(gate, gstart, gend, gmax, gdinv, pooled);
  pool_accum_kernel<<<(N_NODES + 63) / 64, 256, 0, stream>>>(gate, x_h, batch, gmax, gdinv, pooled);

  // fused heads
  head_kernel<<<NGRAPH, 256, 0, stream>>>(pooled, Ws, bs, Wc, bc, Wr1, br1, Wr2, br2, out);
}